// Round 2
// baseline (1685.973 us; speedup 1.0000x reference)
//
#include <hip/hip_runtime.h>
#include <hip/hip_bf16.h>
#include <math.h>

// All tensors are float32 (per the reference dtypes).

// ---------------------------------------------------------------------------
// Generic conv1x1 (GEMM): Y[b, o, s] = act( sum_c W[o,c] * X[b, c, s] + bias[o] )
// W: [O][Cin] f32 row-major.  X: [B][Cin][S].  Y rows have stride S, batch
// stride YbS (allows writing into a channel-offset slice of a concat buffer).
// Tiles: 64(o) x 64(s) x 16(k), 256 threads, 4x4 micro-tile per thread.
// ---------------------------------------------------------------------------
template<int ACT>
__global__ __launch_bounds__(256)
void conv1x1_kernel(const float* __restrict__ W, const float* __restrict__ X,
                    const float* __restrict__ bias, float* __restrict__ Y,
                    int O, int Cin, int S, size_t YbS) {
  __shared__ __align__(16) float Ws[16][68];
  __shared__ __align__(16) float Xs[16][68];
  const int tid = threadIdx.x;
  const int s0 = blockIdx.x * 64, o0 = blockIdx.y * 64, b = blockIdx.z;
  const float* Xb = X + (size_t)b * Cin * S;
  float acc[4][4] = {};
  const int tx = tid & 15, ty = tid >> 4;
  for (int c0 = 0; c0 < Cin; c0 += 16) {
#pragma unroll
    for (int l = 0; l < 4; ++l) {
      int idx = tid + l * 256;
      int o = idx >> 4, k = idx & 15;
      Ws[k][o] = W[(size_t)(o0 + o) * Cin + c0 + k];
    }
#pragma unroll
    for (int l = 0; l < 4; ++l) {
      int idx = tid + l * 256;
      int k = idx >> 6, s = idx & 63;
      int ss = s0 + s;
      Xs[k][s] = (ss < S) ? Xb[(size_t)(c0 + k) * S + ss] : 0.f;
    }
    __syncthreads();
#pragma unroll
    for (int k = 0; k < 16; ++k) {
      float4 wv = *(const float4*)&Ws[k][ty * 4];
      float4 xv = *(const float4*)&Xs[k][tx * 4];
      acc[0][0] += wv.x * xv.x; acc[0][1] += wv.x * xv.y; acc[0][2] += wv.x * xv.z; acc[0][3] += wv.x * xv.w;
      acc[1][0] += wv.y * xv.x; acc[1][1] += wv.y * xv.y; acc[1][2] += wv.y * xv.z; acc[1][3] += wv.y * xv.w;
      acc[2][0] += wv.z * xv.x; acc[2][1] += wv.z * xv.y; acc[2][2] += wv.z * xv.z; acc[2][3] += wv.z * xv.w;
      acc[3][0] += wv.w * xv.x; acc[3][1] += wv.w * xv.y; acc[3][2] += wv.w * xv.z; acc[3][3] += wv.w * xv.w;
    }
    __syncthreads();
  }
#pragma unroll
  for (int i = 0; i < 4; ++i) {
    int o = o0 + ty * 4 + i;
    float bv = bias ? bias[o] : 0.f;
#pragma unroll
    for (int jj = 0; jj < 4; ++jj) {
      int s = s0 + tx * 4 + jj;
      if (s < S) {
        float v = acc[i][jj] + bv;
        if (ACT == 1) v = v * 0.5f * (1.0f + erff(v * 0.70710678118654752f));
        Y[(size_t)b * YbS + (size_t)o * S + s] = v;
      }
    }
  }
}

// ---------------------------------------------------------------------------
// In-place L2 normalization of q and k head-vectors (hd=32, channel-strided).
// qkv layout: [B][3*256][S]; grid.y = 16 -> (qk = y>>3, head = y&7).
// ---------------------------------------------------------------------------
__global__ __launch_bounds__(256)
void l2norm_kernel(float* __restrict__ qkv, int S) {
  const int C = 256;
  int b = blockIdx.z;
  int qk = blockIdx.y >> 3;
  int h = blockIdx.y & 7;
  int s = blockIdx.x * 256 + threadIdx.x;
  if (s >= S) return;
  float* base = qkv + ((size_t)b * 3 * C + qk * C + h * 32) * S + s;
  float v[32];
  float ss = 0.f;
#pragma unroll
  for (int d = 0; d < 32; ++d) { v[d] = base[(size_t)d * S]; ss += v[d] * v[d]; }
  float inv = 1.0f / fmaxf(sqrtf(ss), 1e-12f);
#pragma unroll
  for (int d = 0; d < 32; ++d) base[(size_t)d * S] = v[d] * inv;
}

// ---------------------------------------------------------------------------
// Flash-style attention per (b, head, 32 q-rows). q/k already L2-normalized.
// 8 lanes per q-row; 128-k chunks staged in LDS (k then v reuse same buffer).
// Output written in spatial layout out[b][h*32+d][s].
// ---------------------------------------------------------------------------
#define ATT_KB 128
__global__ __launch_bounds__(256)
void attn_kernel(const float* __restrict__ qkv, float* __restrict__ out, int S) {
  const int C = 256;
  const float scale = 0.17677669529663687f;  // 32^-0.5
  int b = blockIdx.z, h = blockIdx.y, q0 = blockIdx.x * 32;
  const float* qb = qkv + ((size_t)b * 3 * C + h * 32) * S;
  const float* kb = qb + (size_t)C * S;
  const float* vb = qb + (size_t)2 * C * S;
  __shared__ __align__(16) float q_s[32][36];
  __shared__ __align__(16) float kv_s[ATT_KB][36];
  const int tid = threadIdx.x;
#pragma unroll
  for (int l = 0; l < 4; ++l) {
    int idx = tid + l * 256;
    int r = idx & 31, d = idx >> 5;
    int ss = q0 + r;
    q_s[r][d] = (ss < S) ? qb[(size_t)d * S + ss] : 0.f;
  }
  __syncthreads();
  const int r = tid >> 3, j = tid & 7;
  float qreg[32];
#pragma unroll
  for (int d = 0; d < 32; ++d) qreg[d] = q_s[r][d];
  float m = -INFINITY, lsum = 0.f;
  float4 accd[8] = {};
  for (int kbase = 0; kbase < S; kbase += ATT_KB) {
    __syncthreads();  // previous v-chunk fully consumed
#pragma unroll
    for (int l = 0; l < 16; ++l) {
      int idx = tid + l * 256;
      int kk = idx & 127, d = idx >> 7;
      int ks = kbase + kk;
      kv_s[kk][d] = (ks < S) ? kb[(size_t)d * S + ks] : 0.f;
    }
    __syncthreads();
    float lg[16];
    float chmax = -INFINITY;
#pragma unroll
    for (int i = 0; i < 16; ++i) {
      int kk = j + 8 * i;
      const float4* kr = (const float4*)kv_s[kk];
      float a0 = 0, a1 = 0, a2 = 0, a3 = 0;
#pragma unroll
      for (int dd = 0; dd < 8; ++dd) {
        float4 k4 = kr[dd];
        a0 += qreg[dd * 4 + 0] * k4.x; a1 += qreg[dd * 4 + 1] * k4.y;
        a2 += qreg[dd * 4 + 2] * k4.z; a3 += qreg[dd * 4 + 3] * k4.w;
      }
      float dot = (a0 + a1) + (a2 + a3);
      lg[i] = ((kbase + kk) < S) ? dot * scale : -INFINITY;
      chmax = fmaxf(chmax, lg[i]);
    }
#pragma unroll
    for (int off = 1; off < 8; off <<= 1) chmax = fmaxf(chmax, __shfl_xor(chmax, off));
    float mnew = fmaxf(m, chmax);
    float corr = __expf(m - mnew);
    m = mnew;
    lsum *= corr;
#pragma unroll
    for (int dd = 0; dd < 8; ++dd) {
      accd[dd].x *= corr; accd[dd].y *= corr; accd[dd].z *= corr; accd[dd].w *= corr;
    }
    float p[16];
    float psum = 0.f;
#pragma unroll
    for (int i = 0; i < 16; ++i) { p[i] = __expf(lg[i] - m); psum += p[i]; }
    lsum += psum;
    __syncthreads();
#pragma unroll
    for (int l = 0; l < 16; ++l) {
      int idx = tid + l * 256;
      int kk = idx & 127, d = idx >> 7;
      int ks = kbase + kk;
      kv_s[kk][d] = (ks < S) ? vb[(size_t)d * S + ks] : 0.f;
    }
    __syncthreads();
#pragma unroll
    for (int i = 0; i < 16; ++i) {
      int kk = j + 8 * i;
      float pi = p[i];
      const float4* vr = (const float4*)kv_s[kk];
#pragma unroll
      for (int dd = 0; dd < 8; ++dd) {
        float4 v4 = vr[dd];
        accd[dd].x += pi * v4.x; accd[dd].y += pi * v4.y;
        accd[dd].z += pi * v4.z; accd[dd].w += pi * v4.w;
      }
    }
  }
#pragma unroll
  for (int off = 1; off < 8; off <<= 1) {
    lsum += __shfl_xor(lsum, off);
#pragma unroll
    for (int dd = 0; dd < 8; ++dd) {
      accd[dd].x += __shfl_xor(accd[dd].x, off);
      accd[dd].y += __shfl_xor(accd[dd].y, off);
      accd[dd].z += __shfl_xor(accd[dd].z, off);
      accd[dd].w += __shfl_xor(accd[dd].w, off);
    }
  }
  if (q0 + r < S) {
    float inv = 1.0f / lsum;
    float4 myv;
    switch (j) {
      case 0: myv = accd[0]; break; case 1: myv = accd[1]; break;
      case 2: myv = accd[2]; break; case 3: myv = accd[3]; break;
      case 4: myv = accd[4]; break; case 5: myv = accd[5]; break;
      case 6: myv = accd[6]; break; default: myv = accd[7]; break;
    }
    size_t obase = ((size_t)b * C + h * 32 + j * 4) * S + q0 + r;
    out[obase]         = myv.x * inv;
    out[obase + S]     = myv.y * inv;
    out[obase + 2 * S] = myv.z * inv;
    out[obase + 3 * S] = myv.w * inv;
  }
}

// ---------------------------------------------------------------------------
// 4x4 average pool: x[b][c][48][48] -> xg[b][c][12][12]
// ---------------------------------------------------------------------------
__global__ __launch_bounds__(256)
void pool_kernel(const float* __restrict__ x, float* __restrict__ xg) {
  int idx = blockIdx.x * 256 + threadIdx.x;
  if (idx >= 4 * 256 * 144) return;
  int wc = idx % 12;
  int t = idx / 12;
  int hc = t % 12;
  int bc = t / 12;
  const float* p = x + ((size_t)bc * 48 + hc * 4) * 48 + wc * 4;
  float s = 0.f;
#pragma unroll
  for (int dy = 0; dy < 4; ++dy)
#pragma unroll
    for (int dx = 0; dx < 4; ++dx) s += p[dy * 48 + dx];
  xg[idx] = s * (1.0f / 16.0f);
}

// ---------------------------------------------------------------------------
// Bilinear 12->48 upsample (half-pixel, edge clamp == jax renormalized taps),
// writing into the SECOND half (channels 256..511) of the concat buffer.
// ---------------------------------------------------------------------------
__global__ __launch_bounds__(256)
void upsample_kernel(const float* __restrict__ g, float* __restrict__ cat) {
  int idx = blockIdx.x * 256 + threadIdx.x;
  if (idx >= 4 * 256 * 2304) return;
  int xo = idx % 48;
  int t = idx / 48;
  int yo = t % 48;
  int bc = t / 48;
  int b = bc >> 8, c = bc & 255;
  float sy = 0.25f * yo - 0.375f;
  float sx = 0.25f * xo - 0.375f;
  int y0 = (int)floorf(sy); float fy = sy - (float)y0;
  int x0 = (int)floorf(sx); float fx = sx - (float)x0;
  int y0c = min(11, max(0, y0)), y1c = min(11, max(0, y0 + 1));
  int x0c = min(11, max(0, x0)), x1c = min(11, max(0, x0 + 1));
  const float* gb = g + (size_t)bc * 144;
  float v00 = gb[y0c * 12 + x0c], v01 = gb[y0c * 12 + x1c];
  float v10 = gb[y1c * 12 + x0c], v11 = gb[y1c * 12 + x1c];
  float v = (1.f - fy) * ((1.f - fx) * v00 + fx * v01) + fy * ((1.f - fx) * v10 + fx * v11);
  cat[((size_t)b * 512 + 256 + c) * 2304 + yo * 48 + xo] = v;
}

// ---------------------------------------------------------------------------
extern "C" void kernel_launch(void* const* d_in, const int* in_sizes, int n_in,
                              void* d_out, int out_size, void* d_ws, size_t ws_size,
                              hipStream_t stream) {
  const float* x        = (const float*)d_in[0];
  const float* w_qkv_l  = (const float*)d_in[1];
  const float* w_proj_l = (const float*)d_in[2];
  const float* b_proj_l = (const float*)d_in[3];
  const float* w_qkv_g  = (const float*)d_in[4];
  const float* w_proj_g = (const float*)d_in[5];
  const float* b_proj_g = (const float*)d_in[6];
  const float* w_f1     = (const float*)d_in[7];
  const float* b_f1     = (const float*)d_in[8];
  const float* w_f2     = (const float*)d_in[9];
  const float* b_f2     = (const float*)d_in[10];
  float* out = (float*)d_out;

  const int S = 2304, Sg = 144, B = 4;
  float* ws    = (float*)d_ws;
  float* qkv_l = ws;                                // B*768*S
  float* att_l = qkv_l + (size_t)B * 768 * S;       // B*256*S
  float* cat   = att_l + (size_t)B * 256 * S;       // B*512*S
  float* hbuf  = cat + (size_t)B * 512 * S;         // B*256*S
  float* xg    = hbuf + (size_t)B * 256 * S;        // B*256*Sg
  float* qkv_g = xg + (size_t)B * 256 * Sg;         // B*768*Sg
  float* att_g = qkv_g + (size_t)B * 768 * Sg;      // B*256*Sg
  float* gsm   = att_g + (size_t)B * 256 * Sg;      // B*256*Sg

  dim3 blk(256);

  // ----- local branch -----
  conv1x1_kernel<0><<<dim3(36, 12, B), blk, 0, stream>>>(
      w_qkv_l, x, nullptr, qkv_l, 768, 256, S, (size_t)768 * S);
  l2norm_kernel<<<dim3(9, 16, B), blk, 0, stream>>>(qkv_l, S);
  attn_kernel<<<dim3(72, 8, B), blk, 0, stream>>>(qkv_l, att_l, S);
  conv1x1_kernel<0><<<dim3(36, 4, B), blk, 0, stream>>>(
      w_proj_l, att_l, b_proj_l, cat, 256, 256, S, (size_t)512 * S);

  // ----- global branch -----
  pool_kernel<<<dim3(576), blk, 0, stream>>>(x, xg);
  conv1x1_kernel<0><<<dim3(3, 12, B), blk, 0, stream>>>(
      w_qkv_g, xg, nullptr, qkv_g, 768, 256, Sg, (size_t)768 * Sg);
  l2norm_kernel<<<dim3(1, 16, B), blk, 0, stream>>>(qkv_g, Sg);
  attn_kernel<<<dim3(5, 8, B), blk, 0, stream>>>(qkv_g, att_g, Sg);
  conv1x1_kernel<0><<<dim3(3, 4, B), blk, 0, stream>>>(
      w_proj_g, att_g, b_proj_g, gsm, 256, 256, Sg, (size_t)256 * Sg);
  upsample_kernel<<<dim3(9216), blk, 0, stream>>>(gsm, cat);

  // ----- fuse: f1 (GELU) then f2 -----
  conv1x1_kernel<1><<<dim3(36, 4, B), blk, 0, stream>>>(
      w_f1, cat, b_f1, hbuf, 256, 512, S, (size_t)256 * S);
  conv1x1_kernel<0><<<dim3(36, 4, B), blk, 0, stream>>>(
      w_f2, hbuf, b_f2, out, 256, 256, S, (size_t)256 * S);
}

// Round 3
// 380.901 us; speedup vs baseline: 4.4263x; 4.4263x over previous
//
#include <hip/hip_runtime.h>
#include <hip/hip_bf16.h>
#include <math.h>

typedef __attribute__((ext_vector_type(8))) short bf16x8;
typedef __attribute__((ext_vector_type(4))) float f32x4;

__device__ inline unsigned short f2bf(float x) {
  __hip_bfloat16 h = __float2bfloat16(x);
  return __builtin_bit_cast(unsigned short, h);
}
__device__ inline unsigned packbf2(float lo, float hi) {
  return (unsigned)f2bf(lo) | ((unsigned)f2bf(hi) << 16);
}

// ---------------------------------------------------------------------------
// Generic conv1x1 (GEMM): Y[b, o, s] = act( sum_c W[o,c] * X[b, c, s] + bias[o] )
// f32 VALU version (unchanged from round 2; next optimization target).
// ---------------------------------------------------------------------------
template<int ACT>
__global__ __launch_bounds__(256)
void conv1x1_kernel(const float* __restrict__ W, const float* __restrict__ X,
                    const float* __restrict__ bias, float* __restrict__ Y,
                    int O, int Cin, int S, size_t YbS) {
  __shared__ __align__(16) float Ws[16][68];
  __shared__ __align__(16) float Xs[16][68];
  const int tid = threadIdx.x;
  const int s0 = blockIdx.x * 64, o0 = blockIdx.y * 64, b = blockIdx.z;
  const float* Xb = X + (size_t)b * Cin * S;
  float acc[4][4] = {};
  const int tx = tid & 15, ty = tid >> 4;
  for (int c0 = 0; c0 < Cin; c0 += 16) {
#pragma unroll
    for (int l = 0; l < 4; ++l) {
      int idx = tid + l * 256;
      int o = idx >> 4, k = idx & 15;
      Ws[k][o] = W[(size_t)(o0 + o) * Cin + c0 + k];
    }
#pragma unroll
    for (int l = 0; l < 4; ++l) {
      int idx = tid + l * 256;
      int k = idx >> 6, s = idx & 63;
      int ss = s0 + s;
      Xs[k][s] = (ss < S) ? Xb[(size_t)(c0 + k) * S + ss] : 0.f;
    }
    __syncthreads();
#pragma unroll
    for (int k = 0; k < 16; ++k) {
      float4 wv = *(const float4*)&Ws[k][ty * 4];
      float4 xv = *(const float4*)&Xs[k][tx * 4];
      acc[0][0] += wv.x * xv.x; acc[0][1] += wv.x * xv.y; acc[0][2] += wv.x * xv.z; acc[0][3] += wv.x * xv.w;
      acc[1][0] += wv.y * xv.x; acc[1][1] += wv.y * xv.y; acc[1][2] += wv.y * xv.z; acc[1][3] += wv.y * xv.w;
      acc[2][0] += wv.z * xv.x; acc[2][1] += wv.z * xv.y; acc[2][2] += wv.z * xv.z; acc[2][3] += wv.z * xv.w;
      acc[3][0] += wv.w * xv.x; acc[3][1] += wv.w * xv.y; acc[3][2] += wv.w * xv.z; acc[3][3] += wv.w * xv.w;
    }
    __syncthreads();
  }
#pragma unroll
  for (int i = 0; i < 4; ++i) {
    int o = o0 + ty * 4 + i;
    float bv = bias ? bias[o] : 0.f;
#pragma unroll
    for (int jj = 0; jj < 4; ++jj) {
      int s = s0 + tx * 4 + jj;
      if (s < S) {
        float v = acc[i][jj] + bv;
        if (ACT == 1) v = v * 0.5f * (1.0f + erff(v * 0.70710678118654752f));
        Y[(size_t)b * YbS + (size_t)o * S + s] = v;
      }
    }
  }
}

// ---------------------------------------------------------------------------
// L2-normalize q,k head-vectors and convert to bf16 row-major [b][h][s][32].
// K rows are stored PERMUTED within each 64-row block so that the QK^T MFMA
// accumulator layout coincides with the PV B-fragment layout (no shuffles):
//   stored_row(j) = 32*((j>>2)&1) + 16*(j>>5) + 4*((j>>3)&3) + (j&3)
// Rows s >= S are written as zeros (padding for the tail chunk).
// ---------------------------------------------------------------------------
__global__ __launch_bounds__(256)
void l2ncvt_kernel(const float* __restrict__ qkv, unsigned short* __restrict__ qd,
                   unsigned short* __restrict__ kd, int S, int Sp) {
  int idx = blockIdx.x * 256 + threadIdx.x;
  int s = idx % Sp; int t = idx / Sp;
  int h = t & 7; t >>= 3;
  int qk = t & 1; int b = t >> 1;
  if (b >= 4) return;
  unsigned short* dst;
  int srow;
  if (qk == 0) { dst = qd; srow = s; }
  else {
    dst = kd;
    int blk = s >> 6, j = s & 63;
    srow = (blk << 6) + 32 * ((j >> 2) & 1) + 16 * (j >> 5) + 4 * ((j >> 3) & 3) + (j & 3);
  }
  unsigned wbuf[16];
  if (s < S) {
    const float* base = qkv + ((size_t)b * 768 + qk * 256 + h * 32) * S + s;
    float v[32]; float ss = 0.f;
#pragma unroll
    for (int d = 0; d < 32; ++d) { v[d] = base[(size_t)d * S]; ss += v[d] * v[d]; }
    float inv = 1.0f / fmaxf(sqrtf(ss), 1e-12f);
#pragma unroll
    for (int i = 0; i < 16; ++i) wbuf[i] = packbf2(v[2 * i] * inv, v[2 * i + 1] * inv);
  } else {
#pragma unroll
    for (int i = 0; i < 16; ++i) wbuf[i] = 0u;
  }
  uint4* o = (uint4*)(dst + ((size_t)(b * 8 + h) * Sp + srow) * 32);
#pragma unroll
  for (int i = 0; i < 4; ++i)
    o[i] = make_uint4(wbuf[4 * i], wbuf[4 * i + 1], wbuf[4 * i + 2], wbuf[4 * i + 3]);
}

// ---------------------------------------------------------------------------
// Convert v to bf16, d-major layout vt[b][h][32][Sp] (natural key order),
// zero-padding columns s >= S.
// ---------------------------------------------------------------------------
__global__ __launch_bounds__(256)
void vcvt_kernel(const float* __restrict__ qkv, unsigned short* __restrict__ vt,
                 int S, int Sp) {
  int idx = blockIdx.x * 256 + threadIdx.x;
  int SpH = Sp >> 1;
  int sp = idx % SpH; int t = idx / SpH;
  int d = t & 31; t >>= 5;
  int h = t & 7; int b = t >> 3;
  if (b >= 4) return;
  const float* src = qkv + ((size_t)b * 768 + 512 + h * 32 + d) * S;
  int s2 = 2 * sp;
  float a = (s2 < S) ? src[s2] : 0.f;
  float c = (s2 + 1 < S) ? src[s2 + 1] : 0.f;
  *(unsigned*)(vt + ((size_t)(b * 8 + h) * 32 + d) * Sp + s2) = packbf2(a, c);
}

// ---------------------------------------------------------------------------
// MFMA flash attention (no LDS, no online max — logits bounded by ±0.177
// because q,k are L2-normalized). One wave per 16 q-rows; 64-key chunks.
//   S^T_tile = mfma(K_frag, Q_frag)   (swapped -> softmax column-local)
//   O^T     += mfma(V^T_frag, P_frag)
// K storage permutation makes the S^T accumulator == PV B-frag layout.
// out: f32 [b][256][S] (channel-major, feeds proj conv).
// ---------------------------------------------------------------------------
__global__ __launch_bounds__(256)
void attn_mfma_kernel(const unsigned short* __restrict__ qr,
                      const unsigned short* __restrict__ kr,
                      const unsigned short* __restrict__ vt,
                      float* __restrict__ out, int S, int Sp) {
  const float scale = 0.17677669529663687f;  // 32^-0.5
  int b = blockIdx.z, h = blockIdx.y;
  int w = threadIdx.x >> 6, lane = threadIdx.x & 63;
  int g = lane >> 4, c = lane & 15;
  int q0 = blockIdx.x * 64 + w * 16;
  const unsigned short* qbh = qr + (size_t)(b * 8 + h) * Sp * 32;
  const unsigned short* kbh = kr + (size_t)(b * 8 + h) * Sp * 32;
  const unsigned short* vbh = vt + (size_t)(b * 8 + h) * 32 * Sp;

  // Q B-frag: lane holds Q[q0+c][8g..8g+7]
  bf16x8 qf = *(const bf16x8*)(qbh + (size_t)(q0 + c) * 32 + 8 * g);

  f32x4 oacc0 = {0.f, 0.f, 0.f, 0.f};
  f32x4 oacc1 = {0.f, 0.f, 0.f, 0.f};
  float lsum = 0.f;

  for (int k0 = 0; k0 < Sp; k0 += 64) {
    // QK^T (swapped): 4 subtiles of 16 stored-rows each
    f32x4 sa[4];
#pragma unroll
    for (int t = 0; t < 4; ++t) {
      bf16x8 kf = *(const bf16x8*)(kbh + (size_t)(k0 + 16 * t + c) * 32 + 8 * g);
      f32x4 z = {0.f, 0.f, 0.f, 0.f};
      sa[t] = __builtin_amdgcn_mfma_f32_16x16x32_bf16(kf, qf, z, 0, 0, 0);
    }
    float p[4][4];
    if (k0 + 64 <= S) {
#pragma unroll
      for (int t = 0; t < 4; ++t)
#pragma unroll
        for (int r = 0; r < 4; ++r) {
          float e = __expf(sa[t][r] * scale);
          p[t][r] = e; lsum += e;
        }
    } else {
#pragma unroll
      for (int t = 0; t < 4; ++t)
#pragma unroll
        for (int r = 0; r < 4; ++r) {
          // actual key index for stored-row 16t+4g+r (inverse permutation)
          int key = k0 + 32 * (t & 1) + 8 * g + 4 * (t >> 1) + r;
          float e = (key < S) ? __expf(sa[t][r] * scale) : 0.f;
          p[t][r] = e; lsum += e;
        }
    }
    unsigned pk[4][2];
#pragma unroll
    for (int t = 0; t < 4; ++t) {
      pk[t][0] = packbf2(p[t][0], p[t][1]);
      pk[t][1] = packbf2(p[t][2], p[t][3]);
    }
    // PV: P-frag comes straight from this lane's registers (K-permutation)
#pragma unroll
    for (int kb = 0; kb < 2; ++kb) {
      union { bf16x8 v; unsigned u[4]; } pf;
      pf.u[0] = pk[kb][0];
      pf.u[1] = pk[kb][1];
      pf.u[2] = pk[2 + kb][0];
      pf.u[3] = pk[2 + kb][1];
      bf16x8 vf0 = *(const bf16x8*)(vbh + (size_t)c * Sp + k0 + 32 * kb + 8 * g);
      bf16x8 vf1 = *(const bf16x8*)(vbh + (size_t)(16 + c) * Sp + k0 + 32 * kb + 8 * g);
      oacc0 = __builtin_amdgcn_mfma_f32_16x16x32_bf16(vf0, pf.v, oacc0, 0, 0, 0);
      oacc1 = __builtin_amdgcn_mfma_f32_16x16x32_bf16(vf1, pf.v, oacc1, 0, 0, 0);
    }
  }
  // denominator: sum over the 4 lane-groups holding this q-column
  lsum += __shfl_xor(lsum, 16, 64);
  lsum += __shfl_xor(lsum, 32, 64);
  float inv = 1.0f / lsum;
  int q = q0 + c;
  if (q < S) {
    size_t ob = ((size_t)b * 256 + h * 32) * S + q;
#pragma unroll
    for (int r = 0; r < 4; ++r) {
      out[ob + (size_t)(4 * g + r) * S]      = oacc0[r] * inv;
      out[ob + (size_t)(16 + 4 * g + r) * S] = oacc1[r] * inv;
    }
  }
}

// ---------------------------------------------------------------------------
// 4x4 average pool: x[b][c][48][48] -> xg[b][c][12][12]
// ---------------------------------------------------------------------------
__global__ __launch_bounds__(256)
void pool_kernel(const float* __restrict__ x, float* __restrict__ xg) {
  int idx = blockIdx.x * 256 + threadIdx.x;
  if (idx >= 4 * 256 * 144) return;
  int wc = idx % 12;
  int t = idx / 12;
  int hc = t % 12;
  int bc = t / 12;
  const float* p = x + ((size_t)bc * 48 + hc * 4) * 48 + wc * 4;
  float s = 0.f;
#pragma unroll
  for (int dy = 0; dy < 4; ++dy)
#pragma unroll
    for (int dx = 0; dx < 4; ++dx) s += p[dy * 48 + dx];
  xg[idx] = s * (1.0f / 16.0f);
}

// ---------------------------------------------------------------------------
// Bilinear 12->48 upsample into channels 256..511 of the concat buffer.
// ---------------------------------------------------------------------------
__global__ __launch_bounds__(256)
void upsample_kernel(const float* __restrict__ g, float* __restrict__ cat) {
  int idx = blockIdx.x * 256 + threadIdx.x;
  if (idx >= 4 * 256 * 2304) return;
  int xo = idx % 48;
  int t = idx / 48;
  int yo = t % 48;
  int bc = t / 48;
  int b = bc >> 8, c = bc & 255;
  float sy = 0.25f * yo - 0.375f;
  float sx = 0.25f * xo - 0.375f;
  int y0 = (int)floorf(sy); float fy = sy - (float)y0;
  int x0 = (int)floorf(sx); float fx = sx - (float)x0;
  int y0c = min(11, max(0, y0)), y1c = min(11, max(0, y0 + 1));
  int x0c = min(11, max(0, x0)), x1c = min(11, max(0, x0 + 1));
  const float* gb = g + (size_t)bc * 144;
  float v00 = gb[y0c * 12 + x0c], v01 = gb[y0c * 12 + x1c];
  float v10 = gb[y1c * 12 + x0c], v11 = gb[y1c * 12 + x1c];
  float v = (1.f - fy) * ((1.f - fx) * v00 + fx * v01) + fy * ((1.f - fx) * v10 + fx * v11);
  cat[((size_t)b * 512 + 256 + c) * 2304 + yo * 48 + xo] = v;
}

// ---------------------------------------------------------------------------
extern "C" void kernel_launch(void* const* d_in, const int* in_sizes, int n_in,
                              void* d_out, int out_size, void* d_ws, size_t ws_size,
                              hipStream_t stream) {
  const float* x        = (const float*)d_in[0];
  const float* w_qkv_l  = (const float*)d_in[1];
  const float* w_proj_l = (const float*)d_in[2];
  const float* b_proj_l = (const float*)d_in[3];
  const float* w_qkv_g  = (const float*)d_in[4];
  const float* w_proj_g = (const float*)d_in[5];
  const float* b_proj_g = (const float*)d_in[6];
  const float* w_f1     = (const float*)d_in[7];
  const float* b_f1     = (const float*)d_in[8];
  const float* w_f2     = (const float*)d_in[9];
  const float* b_f2     = (const float*)d_in[10];
  float* out = (float*)d_out;

  const int S = 2304, Sg = 144, B = 4;
  const int Sp = 2304, Sgp = 192;  // padded row counts (multiple of 64)

  char* w = (char*)d_ws;
  size_t off = 0;
  auto alloc = [&](size_t bytes) { char* p = w + off; off = (off + bytes + 255) & ~(size_t)255; return p; };
  float* qkv_l = (float*)alloc((size_t)B * 768 * S * 4);
  float* att_l = (float*)alloc((size_t)B * 256 * S * 4);
  float* cat   = (float*)alloc((size_t)B * 512 * S * 4);
  float* hbuf  = (float*)alloc((size_t)B * 256 * S * 4);
  float* xg    = (float*)alloc((size_t)B * 256 * Sg * 4);
  float* qkv_g = (float*)alloc((size_t)B * 768 * Sg * 4);
  float* att_g = (float*)alloc((size_t)B * 256 * Sg * 4);
  float* gsm   = (float*)alloc((size_t)B * 256 * Sg * 4);
  unsigned short* qr_l = (unsigned short*)alloc((size_t)B * 8 * Sp * 32 * 2);
  unsigned short* kr_l = (unsigned short*)alloc((size_t)B * 8 * Sp * 32 * 2);
  unsigned short* vt_l = (unsigned short*)alloc((size_t)B * 8 * Sp * 32 * 2);
  unsigned short* qr_g = (unsigned short*)alloc((size_t)B * 8 * Sgp * 32 * 2);
  unsigned short* kr_g = (unsigned short*)alloc((size_t)B * 8 * Sgp * 32 * 2);
  unsigned short* vt_g = (unsigned short*)alloc((size_t)B * 8 * Sgp * 32 * 2);

  dim3 blk(256);

  // ----- local branch -----
  conv1x1_kernel<0><<<dim3(36, 12, B), blk, 0, stream>>>(
      w_qkv_l, x, nullptr, qkv_l, 768, 256, S, (size_t)768 * S);
  l2ncvt_kernel<<<dim3((B * 2 * 8 * Sp) / 256), blk, 0, stream>>>(qkv_l, qr_l, kr_l, S, Sp);
  vcvt_kernel<<<dim3((B * 8 * 32 * (Sp / 2)) / 256), blk, 0, stream>>>(qkv_l, vt_l, S, Sp);
  attn_mfma_kernel<<<dim3(Sp / 64, 8, B), blk, 0, stream>>>(qr_l, kr_l, vt_l, att_l, S, Sp);
  conv1x1_kernel<0><<<dim3(36, 4, B), blk, 0, stream>>>(
      w_proj_l, att_l, b_proj_l, cat, 256, 256, S, (size_t)512 * S);

  // ----- global branch -----
  pool_kernel<<<dim3(576), blk, 0, stream>>>(x, xg);
  conv1x1_kernel<0><<<dim3(3, 12, B), blk, 0, stream>>>(
      w_qkv_g, xg, nullptr, qkv_g, 768, 256, Sg, (size_t)768 * Sg);
  l2ncvt_kernel<<<dim3((B * 2 * 8 * Sgp) / 256), blk, 0, stream>>>(qkv_g, qr_g, kr_g, Sg, Sgp);
  vcvt_kernel<<<dim3((B * 8 * 32 * (Sgp / 2)) / 256), blk, 0, stream>>>(qkv_g, vt_g, Sg, Sgp);
  attn_mfma_kernel<<<dim3(Sgp / 64, 8, B), blk, 0, stream>>>(qr_g, kr_g, vt_g, att_g, Sg, Sgp);
  conv1x1_kernel<0><<<dim3(3, 4, B), blk, 0, stream>>>(
      w_proj_g, att_g, b_proj_g, gsm, 256, 256, Sg, (size_t)256 * Sg);
  upsample_kernel<<<dim3(9216), blk, 0, stream>>>(gsm, cat);

  // ----- fuse: f1 (GELU) then f2 -----
  conv1x1_kernel<1><<<dim3(36, 4, B), blk, 0, stream>>>(
      w_f1, cat, b_f1, hbuf, 256, 512, S, (size_t)256 * S);
  conv1x1_kernel<0><<<dim3(36, 4, B), blk, 0, stream>>>(
      w_f2, hbuf, b_f2, out, 256, 256, S, (size_t)256 * S);
}

// Round 4
// 281.073 us; speedup vs baseline: 5.9984x; 1.3552x over previous
//
#include <hip/hip_runtime.h>
#include <hip/hip_bf16.h>
#include <math.h>

typedef __attribute__((ext_vector_type(8))) short bf16x8;
typedef __attribute__((ext_vector_type(4))) float f32x4;

__device__ inline unsigned short f2bf(float x) {
  __hip_bfloat16 h = __float2bfloat16(x);
  return __builtin_bit_cast(unsigned short, h);
}
__device__ inline float bf2f(unsigned short u) {
  unsigned v = ((unsigned)u) << 16;
  return __builtin_bit_cast(float, v);
}
__device__ inline unsigned packbf2(float lo, float hi) {
  return (unsigned)f2bf(lo) | ((unsigned)f2bf(hi) << 16);
}

// ---------------------------------------------------------------------------
// Weight split: W[O][Cin] f32 -> Whl rows of 128B: [o][kb][32 hi bf16 | 32 lo].
// One thread per (o, kb) row (32 input f32, 128B output).
// Row counts per matrix: qkv_l 6144, proj_l 2048, qkv_g 6144, proj_g 2048,
// f1 4096, f2 2048  (cum 6144,8192,14336,16384,20480,22528).
// ---------------------------------------------------------------------------
__global__ __launch_bounds__(256)
void wsplit_kernel(const float* __restrict__ w0, const float* __restrict__ w1,
                   const float* __restrict__ w2, const float* __restrict__ w3,
                   const float* __restrict__ w4, const float* __restrict__ w5,
                   unsigned short* __restrict__ d0, unsigned short* __restrict__ d1,
                   unsigned short* __restrict__ d2, unsigned short* __restrict__ d3,
                   unsigned short* __restrict__ d4, unsigned short* __restrict__ d5) {
  int r = blockIdx.x * 256 + threadIdx.x;
  const float* src; unsigned short* dst;
  if (r < 6144) { src = w0; dst = d0; }
  else if (r < 8192) { src = w1; dst = d1; r -= 6144; }
  else if (r < 14336) { src = w2; dst = d2; r -= 8192; }
  else if (r < 16384) { src = w3; dst = d3; r -= 14336; }
  else if (r < 20480) { src = w4; dst = d4; r -= 16384; }
  else if (r < 22528) { src = w5; dst = d5; r -= 20480; }
  else return;
  const float* in = src + (size_t)r * 32;
  union { unsigned short u[32]; uint4 q[4]; } H, L;
#pragma unroll
  for (int i = 0; i < 32; ++i) {
    float x = in[i];
    unsigned short h = f2bf(x);
    H.u[i] = h;
    L.u[i] = f2bf(x - bf2f(h));
  }
  uint4* op = (uint4*)(dst + (size_t)r * 64);
#pragma unroll
  for (int q = 0; q < 4; ++q) { op[q] = H.q[q]; op[4 + q] = L.q[q]; }
}

// ---------------------------------------------------------------------------
// conv1x1 as split-precision MFMA GEMM:
//   Y[b,o,s] = act( sum_c W[o,c]*X[b,c,s] + bias[o] ),
//   W ~ Whi+Wlo, X ~ Xhi+Xlo (bf16 pairs), Y ≈ Whi·Xhi + Whi·Xlo + Wlo·Xhi.
// Block 256 thr = 4 waves; tile 128(o) x 64(s); K-step 32.
// X read f32 from natural [b][Cin][S] (coalesced), split in-register,
// staged to LDS rows [64 s][8 slots x 16B] with slot ^= (row&7) XOR swizzle
// (slots 0-3 = hi k-octets, 4-7 = lo). A-frags 16B direct from pre-split Whl.
// ---------------------------------------------------------------------------
template<int ACT>
__global__ __launch_bounds__(256)
void conv_mfma_kernel(const unsigned short* __restrict__ Whl,
                      const float* __restrict__ X,
                      const float* __restrict__ bias,
                      float* __restrict__ Y,
                      int Cin, int S, size_t YbS) {
  __shared__ __align__(16) unsigned short Bs[64 * 64];  // 8 KB
  const int tid = threadIdx.x;
  const int w = tid >> 6, lane = tid & 63;
  const int g = lane >> 4, c = lane & 15;
  const int s0 = blockIdx.x * 64;
  const int o0 = blockIdx.y * 128;
  const int b = blockIdx.z;
  const int KB = Cin >> 5;
  const float* Xb = X + (size_t)b * Cin * S;
  const int sRow = tid & 63;   // staging row (s within tile)
  const int jS = tid >> 6;     // staging k-octet (0..3)
  const int ss = s0 + sRow;
  const bool sIn = (ss < S);
  unsigned short* BsRow = Bs + sRow * 64;
  const int hiOff = (jS ^ (sRow & 7)) * 8;
  const int loOff = ((4 + jS) ^ (sRow & 7)) * 8;

  f32x4 acc[2][4];
#pragma unroll
  for (int oi = 0; oi < 2; ++oi)
#pragma unroll
    for (int si = 0; si < 4; ++si) acc[oi][si] = (f32x4){0.f, 0.f, 0.f, 0.f};

  for (int kb = 0; kb < KB; ++kb) {
    // ---- load + split X micro-panel: k = kb*32 + 8*jS + i at column ss ----
    union { unsigned short u[8]; bf16x8 v; } hu, lu;
    if (sIn) {
      const float* xp = Xb + (size_t)(kb * 32 + 8 * jS) * S + ss;
#pragma unroll
      for (int i = 0; i < 8; ++i) {
        float xv = xp[(size_t)i * S];
        unsigned short h = f2bf(xv);
        hu.u[i] = h;
        lu.u[i] = f2bf(xv - bf2f(h));
      }
    } else {
#pragma unroll
      for (int i = 0; i < 8; ++i) { hu.u[i] = 0; lu.u[i] = 0; }
    }
    // ---- A fragments (pre-split weights, direct global) ----
    bf16x8 ahi[2], alo[2];
#pragma unroll
    for (int oi = 0; oi < 2; ++oi) {
      const unsigned short* ap =
          Whl + ((size_t)(o0 + 32 * w + 16 * oi + c) * KB + kb) * 64;
      ahi[oi] = *(const bf16x8*)(ap + 8 * g);
      alo[oi] = *(const bf16x8*)(ap + 32 + 8 * g);
    }
    __syncthreads();  // previous iteration's B reads complete
    *(bf16x8*)(BsRow + hiOff) = hu.v;
    *(bf16x8*)(BsRow + loOff) = lu.v;
    __syncthreads();
    // ---- B fragments from swizzled LDS ----
    bf16x8 bhi[4], blo[4];
#pragma unroll
    for (int si = 0; si < 4; ++si) {
      int row = 16 * si + c;
      const unsigned short* bp = Bs + row * 64;
      bhi[si] = *(const bf16x8*)(bp + (g ^ (row & 7)) * 8);
      blo[si] = *(const bf16x8*)(bp + (((4 + g) ^ (row & 7))) * 8);
    }
#pragma unroll
    for (int oi = 0; oi < 2; ++oi)
#pragma unroll
      for (int si = 0; si < 4; ++si) {
        acc[oi][si] = __builtin_amdgcn_mfma_f32_16x16x32_bf16(ahi[oi], bhi[si], acc[oi][si], 0, 0, 0);
        acc[oi][si] = __builtin_amdgcn_mfma_f32_16x16x32_bf16(ahi[oi], blo[si], acc[oi][si], 0, 0, 0);
        acc[oi][si] = __builtin_amdgcn_mfma_f32_16x16x32_bf16(alo[oi], bhi[si], acc[oi][si], 0, 0, 0);
      }
  }
  // ---- epilogue: bias + activation + f32 store ----
#pragma unroll
  for (int oi = 0; oi < 2; ++oi) {
#pragma unroll
    for (int r = 0; r < 4; ++r) {
      int o = o0 + 32 * w + 16 * oi + 4 * g + r;
      float bv = bias ? bias[o] : 0.f;
#pragma unroll
      for (int si = 0; si < 4; ++si) {
        int s = s0 + 16 * si + c;
        if (s < S) {
          float v = acc[oi][si][r] + bv;
          if (ACT == 1) v = v * 0.5f * (1.0f + erff(v * 0.70710678118654752f));
          Y[(size_t)b * YbS + (size_t)o * S + s] = v;
        }
      }
    }
  }
}

// ---------------------------------------------------------------------------
// L2-normalize q,k head-vectors, convert to bf16 row-major [b][h][s][32].
// K rows stored permuted within 64-row blocks (QK^T acc == PV B-frag layout).
// ---------------------------------------------------------------------------
__global__ __launch_bounds__(256)
void l2ncvt_kernel(const float* __restrict__ qkv, unsigned short* __restrict__ qd,
                   unsigned short* __restrict__ kd, int S, int Sp) {
  int idx = blockIdx.x * 256 + threadIdx.x;
  int s = idx % Sp; int t = idx / Sp;
  int h = t & 7; t >>= 3;
  int qk = t & 1; int b = t >> 1;
  if (b >= 4) return;
  unsigned short* dst;
  int srow;
  if (qk == 0) { dst = qd; srow = s; }
  else {
    dst = kd;
    int blk = s >> 6, j = s & 63;
    srow = (blk << 6) + 32 * ((j >> 2) & 1) + 16 * (j >> 5) + 4 * ((j >> 3) & 3) + (j & 3);
  }
  unsigned wbuf[16];
  if (s < S) {
    const float* base = qkv + ((size_t)b * 768 + qk * 256 + h * 32) * S + s;
    float v[32]; float ss = 0.f;
#pragma unroll
    for (int d = 0; d < 32; ++d) { v[d] = base[(size_t)d * S]; ss += v[d] * v[d]; }
    float inv = 1.0f / fmaxf(sqrtf(ss), 1e-12f);
#pragma unroll
    for (int i = 0; i < 16; ++i) wbuf[i] = packbf2(v[2 * i] * inv, v[2 * i + 1] * inv);
  } else {
#pragma unroll
    for (int i = 0; i < 16; ++i) wbuf[i] = 0u;
  }
  uint4* o = (uint4*)(dst + ((size_t)(b * 8 + h) * Sp + srow) * 32);
#pragma unroll
  for (int i = 0; i < 4; ++i)
    o[i] = make_uint4(wbuf[4 * i], wbuf[4 * i + 1], wbuf[4 * i + 2], wbuf[4 * i + 3]);
}

// ---------------------------------------------------------------------------
// v -> bf16 d-major layout vt[b][h][32][Sp], zero-padded past S.
// ---------------------------------------------------------------------------
__global__ __launch_bounds__(256)
void vcvt_kernel(const float* __restrict__ qkv, unsigned short* __restrict__ vt,
                 int S, int Sp) {
  int idx = blockIdx.x * 256 + threadIdx.x;
  int SpH = Sp >> 1;
  int sp = idx % SpH; int t = idx / SpH;
  int d = t & 31; t >>= 5;
  int h = t & 7; int b = t >> 3;
  if (b >= 4) return;
  const float* src = qkv + ((size_t)b * 768 + 512 + h * 32 + d) * S;
  int s2 = 2 * sp;
  float a = (s2 < S) ? src[s2] : 0.f;
  float c = (s2 + 1 < S) ? src[s2 + 1] : 0.f;
  *(unsigned*)(vt + ((size_t)(b * 8 + h) * 32 + d) * Sp + s2) = packbf2(a, c);
}

// ---------------------------------------------------------------------------
// MFMA flash attention (no LDS, no online max — logits in ±0.177).
// ---------------------------------------------------------------------------
__global__ __launch_bounds__(256)
void attn_mfma_kernel(const unsigned short* __restrict__ qr,
                      const unsigned short* __restrict__ kr,
                      const unsigned short* __restrict__ vt,
                      float* __restrict__ out, int S, int Sp) {
  const float scale = 0.17677669529663687f;  // 32^-0.5
  int b = blockIdx.z, h = blockIdx.y;
  int w = threadIdx.x >> 6, lane = threadIdx.x & 63;
  int g = lane >> 4, c = lane & 15;
  int q0 = blockIdx.x * 64 + w * 16;
  const unsigned short* qbh = qr + (size_t)(b * 8 + h) * Sp * 32;
  const unsigned short* kbh = kr + (size_t)(b * 8 + h) * Sp * 32;
  const unsigned short* vbh = vt + (size_t)(b * 8 + h) * 32 * Sp;

  bf16x8 qf = *(const bf16x8*)(qbh + (size_t)(q0 + c) * 32 + 8 * g);

  f32x4 oacc0 = {0.f, 0.f, 0.f, 0.f};
  f32x4 oacc1 = {0.f, 0.f, 0.f, 0.f};
  float lsum = 0.f;

  for (int k0 = 0; k0 < Sp; k0 += 64) {
    f32x4 sa[4];
#pragma unroll
    for (int t = 0; t < 4; ++t) {
      bf16x8 kf = *(const bf16x8*)(kbh + (size_t)(k0 + 16 * t + c) * 32 + 8 * g);
      f32x4 z = {0.f, 0.f, 0.f, 0.f};
      sa[t] = __builtin_amdgcn_mfma_f32_16x16x32_bf16(kf, qf, z, 0, 0, 0);
    }
    float p[4][4];
    if (k0 + 64 <= S) {
#pragma unroll
      for (int t = 0; t < 4; ++t)
#pragma unroll
        for (int r = 0; r < 4; ++r) {
          float e = __expf(sa[t][r] * scale);
          p[t][r] = e; lsum += e;
        }
    } else {
#pragma unroll
      for (int t = 0; t < 4; ++t)
#pragma unroll
        for (int r = 0; r < 4; ++r) {
          int key = k0 + 32 * (t & 1) + 8 * g + 4 * (t >> 1) + r;
          float e = (key < S) ? __expf(sa[t][r] * scale) : 0.f;
          p[t][r] = e; lsum += e;
        }
    }
    unsigned pk[4][2];
#pragma unroll
    for (int t = 0; t < 4; ++t) {
      pk[t][0] = packbf2(p[t][0], p[t][1]);
      pk[t][1] = packbf2(p[t][2], p[t][3]);
    }
#pragma unroll
    for (int kb = 0; kb < 2; ++kb) {
      union { bf16x8 v; unsigned u[4]; } pf;
      pf.u[0] = pk[kb][0];
      pf.u[1] = pk[kb][1];
      pf.u[2] = pk[2 + kb][0];
      pf.u[3] = pk[2 + kb][1];
      bf16x8 vf0 = *(const bf16x8*)(vbh + (size_t)c * Sp + k0 + 32 * kb + 8 * g);
      bf16x8 vf1 = *(const bf16x8*)(vbh + (size_t)(16 + c) * Sp + k0 + 32 * kb + 8 * g);
      oacc0 = __builtin_amdgcn_mfma_f32_16x16x32_bf16(vf0, pf.v, oacc0, 0, 0, 0);
      oacc1 = __builtin_amdgcn_mfma_f32_16x16x32_bf16(vf1, pf.v, oacc1, 0, 0, 0);
    }
  }
  lsum += __shfl_xor(lsum, 16, 64);
  lsum += __shfl_xor(lsum, 32, 64);
  float inv = 1.0f / lsum;
  int q = q0 + c;
  if (q < S) {
    size_t ob = ((size_t)b * 256 + h * 32) * S + q;
#pragma unroll
    for (int r = 0; r < 4; ++r) {
      out[ob + (size_t)(4 * g + r) * S]      = oacc0[r] * inv;
      out[ob + (size_t)(16 + 4 * g + r) * S] = oacc1[r] * inv;
    }
  }
}

// ---------------------------------------------------------------------------
__global__ __launch_bounds__(256)
void pool_kernel(const float* __restrict__ x, float* __restrict__ xg) {
  int idx = blockIdx.x * 256 + threadIdx.x;
  if (idx >= 4 * 256 * 144) return;
  int wc = idx % 12;
  int t = idx / 12;
  int hc = t % 12;
  int bc = t / 12;
  const float* p = x + ((size_t)bc * 48 + hc * 4) * 48 + wc * 4;
  float s = 0.f;
#pragma unroll
  for (int dy = 0; dy < 4; ++dy)
#pragma unroll
    for (int dx = 0; dx < 4; ++dx) s += p[dy * 48 + dx];
  xg[idx] = s * (1.0f / 16.0f);
}

__global__ __launch_bounds__(256)
void upsample_kernel(const float* __restrict__ g, float* __restrict__ cat) {
  int idx = blockIdx.x * 256 + threadIdx.x;
  if (idx >= 4 * 256 * 2304) return;
  int xo = idx % 48;
  int t = idx / 48;
  int yo = t % 48;
  int bc = t / 48;
  int b = bc >> 8, c = bc & 255;
  float sy = 0.25f * yo - 0.375f;
  float sx = 0.25f * xo - 0.375f;
  int y0 = (int)floorf(sy); float fy = sy - (float)y0;
  int x0 = (int)floorf(sx); float fx = sx - (float)x0;
  int y0c = min(11, max(0, y0)), y1c = min(11, max(0, y0 + 1));
  int x0c = min(11, max(0, x0)), x1c = min(11, max(0, x0 + 1));
  const float* gb = g + (size_t)bc * 144;
  float v00 = gb[y0c * 12 + x0c], v01 = gb[y0c * 12 + x1c];
  float v10 = gb[y1c * 12 + x0c], v11 = gb[y1c * 12 + x1c];
  float v = (1.f - fy) * ((1.f - fx) * v00 + fx * v01) + fy * ((1.f - fx) * v10 + fx * v11);
  cat[((size_t)b * 512 + 256 + c) * 2304 + yo * 48 + xo] = v;
}

// ---------------------------------------------------------------------------
extern "C" void kernel_launch(void* const* d_in, const int* in_sizes, int n_in,
                              void* d_out, int out_size, void* d_ws, size_t ws_size,
                              hipStream_t stream) {
  const float* x        = (const float*)d_in[0];
  const float* w_qkv_l  = (const float*)d_in[1];
  const float* w_proj_l = (const float*)d_in[2];
  const float* b_proj_l = (const float*)d_in[3];
  const float* w_qkv_g  = (const float*)d_in[4];
  const float* w_proj_g = (const float*)d_in[5];
  const float* b_proj_g = (const float*)d_in[6];
  const float* w_f1     = (const float*)d_in[7];
  const float* b_f1     = (const float*)d_in[8];
  const float* w_f2     = (const float*)d_in[9];
  const float* b_f2     = (const float*)d_in[10];
  float* out = (float*)d_out;

  const int S = 2304, Sg = 144, B = 4;
  const int Sp = 2304, Sgp = 192;

  char* wsp = (char*)d_ws;
  size_t off = 0;
  auto alloc = [&](size_t bytes) { char* p = wsp + off; off = (off + bytes + 255) & ~(size_t)255; return p; };
  float* qkv_l = (float*)alloc((size_t)B * 768 * S * 4);
  float* att_l = (float*)alloc((size_t)B * 256 * S * 4);
  float* cat   = (float*)alloc((size_t)B * 512 * S * 4);
  float* hbuf  = (float*)alloc((size_t)B * 256 * S * 4);
  float* xg    = (float*)alloc((size_t)B * 256 * Sg * 4);
  float* qkv_g = (float*)alloc((size_t)B * 768 * Sg * 4);
  float* att_g = (float*)alloc((size_t)B * 256 * Sg * 4);
  float* gsm   = (float*)alloc((size_t)B * 256 * Sg * 4);
  unsigned short* qr_l = (unsigned short*)alloc((size_t)B * 8 * Sp * 32 * 2);
  unsigned short* kr_l = (unsigned short*)alloc((size_t)B * 8 * Sp * 32 * 2);
  unsigned short* vt_l = (unsigned short*)alloc((size_t)B * 8 * Sp * 32 * 2);
  unsigned short* qr_g = (unsigned short*)alloc((size_t)B * 8 * Sgp * 32 * 2);
  unsigned short* kr_g = (unsigned short*)alloc((size_t)B * 8 * Sgp * 32 * 2);
  unsigned short* vt_g = (unsigned short*)alloc((size_t)B * 8 * Sgp * 32 * 2);
  // pre-split weights (hi|lo 128B rows)
  unsigned short* whl_qkv_l  = (unsigned short*)alloc((size_t)768 * 256 * 2 * 2);
  unsigned short* whl_proj_l = (unsigned short*)alloc((size_t)256 * 256 * 2 * 2);
  unsigned short* whl_qkv_g  = (unsigned short*)alloc((size_t)768 * 256 * 2 * 2);
  unsigned short* whl_proj_g = (unsigned short*)alloc((size_t)256 * 256 * 2 * 2);
  unsigned short* whl_f1     = (unsigned short*)alloc((size_t)256 * 512 * 2 * 2);
  unsigned short* whl_f2     = (unsigned short*)alloc((size_t)256 * 256 * 2 * 2);

  dim3 blk(256);

  wsplit_kernel<<<dim3(88), blk, 0, stream>>>(
      w_qkv_l, w_proj_l, w_qkv_g, w_proj_g, w_f1, w_f2,
      whl_qkv_l, whl_proj_l, whl_qkv_g, whl_proj_g, whl_f1, whl_f2);

  // ----- local branch -----
  conv_mfma_kernel<0><<<dim3(36, 6, B), blk, 0, stream>>>(
      whl_qkv_l, x, nullptr, qkv_l, 256, S, (size_t)768 * S);
  l2ncvt_kernel<<<dim3((B * 2 * 8 * Sp) / 256), blk, 0, stream>>>(qkv_l, qr_l, kr_l, S, Sp);
  vcvt_kernel<<<dim3((B * 8 * 32 * (Sp / 2)) / 256), blk, 0, stream>>>(qkv_l, vt_l, S, Sp);
  attn_mfma_kernel<<<dim3(Sp / 64, 8, B), blk, 0, stream>>>(qr_l, kr_l, vt_l, att_l, S, Sp);
  conv_mfma_kernel<0><<<dim3(36, 2, B), blk, 0, stream>>>(
      whl_proj_l, att_l, b_proj_l, cat, 256, S, (size_t)512 * S);

  // ----- global branch -----
  pool_kernel<<<dim3(576), blk, 0, stream>>>(x, xg);
  conv_mfma_kernel<0><<<dim3(3, 6, B), blk, 0, stream>>>(
      whl_qkv_g, xg, nullptr, qkv_g, 256, Sg, (size_t)768 * Sg);
  l2ncvt_kernel<<<dim3((B * 2 * 8 * Sgp) / 256), blk, 0, stream>>>(qkv_g, qr_g, kr_g, Sg, Sgp);
  vcvt_kernel<<<dim3((B * 8 * 32 * (Sgp / 2)) / 256), blk, 0, stream>>>(qkv_g, vt_g, Sg, Sgp);
  attn_mfma_kernel<<<dim3(Sgp / 64, 8, B), blk, 0, stream>>>(qr_g, kr_g, vt_g, att_g, Sg, Sgp);
  conv_mfma_kernel<0><<<dim3(3, 2, B), blk, 0, stream>>>(
      whl_proj_g, att_g, b_proj_g, gsm, 256, Sg, (size_t)256 * Sg);
  upsample_kernel<<<dim3(9216), blk, 0, stream>>>(gsm, cat);

  // ----- fuse: f1 (GELU) then f2 -----
  conv_mfma_kernel<1><<<dim3(36, 2, B), blk, 0, stream>>>(
      whl_f1, cat, b_f1, hbuf, 512, S, (size_t)256 * S);
  conv_mfma_kernel<0><<<dim3(36, 2, B), blk, 0, stream>>>(
      whl_f2, hbuf, b_f2, out, 256, S, (size_t)256 * S);
}

// Round 5
// 273.482 us; speedup vs baseline: 6.1648x; 1.0278x over previous
//
#include <hip/hip_runtime.h>
#include <hip/hip_bf16.h>
#include <math.h>

typedef __attribute__((ext_vector_type(8))) short bf16x8;
typedef __attribute__((ext_vector_type(4))) float f32x4;

__device__ inline unsigned short f2bf(float x) {
  __hip_bfloat16 h = __float2bfloat16(x);
  return __builtin_bit_cast(unsigned short, h);
}
__device__ inline float bf2f(unsigned short u) {
  unsigned v = ((unsigned)u) << 16;
  return __builtin_bit_cast(float, v);
}
__device__ inline unsigned packbf2(float lo, float hi) {
  return (unsigned)f2bf(lo) | ((unsigned)f2bf(hi) << 16);
}

// ---------------------------------------------------------------------------
// Weight split: W[O][Cin] f32 -> Whl rows of 128B: [o][kb][32 hi bf16 | 32 lo].
// ---------------------------------------------------------------------------
__global__ __launch_bounds__(256)
void wsplit_kernel(const float* __restrict__ w0, const float* __restrict__ w1,
                   const float* __restrict__ w2, const float* __restrict__ w3,
                   const float* __restrict__ w4, const float* __restrict__ w5,
                   unsigned short* __restrict__ d0, unsigned short* __restrict__ d1,
                   unsigned short* __restrict__ d2, unsigned short* __restrict__ d3,
                   unsigned short* __restrict__ d4, unsigned short* __restrict__ d5) {
  int r = blockIdx.x * 256 + threadIdx.x;
  const float* src; unsigned short* dst;
  if (r < 6144) { src = w0; dst = d0; }
  else if (r < 8192) { src = w1; dst = d1; r -= 6144; }
  else if (r < 14336) { src = w2; dst = d2; r -= 8192; }
  else if (r < 16384) { src = w3; dst = d3; r -= 14336; }
  else if (r < 20480) { src = w4; dst = d4; r -= 16384; }
  else if (r < 22528) { src = w5; dst = d5; r -= 20480; }
  else return;
  const float* in = src + (size_t)r * 32;
  union { unsigned short u[32]; uint4 q[4]; } H, L;
#pragma unroll
  for (int i = 0; i < 32; ++i) {
    float x = in[i];
    unsigned short h = f2bf(x);
    H.u[i] = h;
    L.u[i] = f2bf(x - bf2f(h));
  }
  uint4* op = (uint4*)(dst + (size_t)r * 64);
#pragma unroll
  for (int q = 0; q < 4; ++q) { op[q] = H.q[q]; op[4 + q] = L.q[q]; }
}

// ---------------------------------------------------------------------------
// conv1x1 as split-precision MFMA GEMM. Tile OT(o) x 64(s), K-step 32.
// OT=128: wave handles 32 o-rows (2 frags); OT=64: 16 o-rows (1 frag).
// ---------------------------------------------------------------------------
template<int ACT, int OT>
__global__ __launch_bounds__(256)
void conv_mfma_kernel(const unsigned short* __restrict__ Whl,
                      const float* __restrict__ X,
                      const float* __restrict__ bias,
                      float* __restrict__ Y,
                      int Cin, int S, size_t YbS) {
  constexpr int OI = OT / 64;  // o-frags per wave
  __shared__ __align__(16) unsigned short Bs[64 * 64];  // 8 KB
  const int tid = threadIdx.x;
  const int w = tid >> 6, lane = tid & 63;
  const int g = lane >> 4, c = lane & 15;
  const int s0 = blockIdx.x * 64;
  const int o0 = blockIdx.y * OT;
  const int b = blockIdx.z;
  const int KB = Cin >> 5;
  const float* Xb = X + (size_t)b * Cin * S;
  const int sRow = tid & 63;
  const int jS = tid >> 6;
  const int ss = s0 + sRow;
  const bool sIn = (ss < S);
  unsigned short* BsRow = Bs + sRow * 64;
  const int hiOff = (jS ^ (sRow & 7)) * 8;
  const int loOff = ((4 + jS) ^ (sRow & 7)) * 8;

  f32x4 acc[OI][4];
#pragma unroll
  for (int oi = 0; oi < OI; ++oi)
#pragma unroll
    for (int si = 0; si < 4; ++si) acc[oi][si] = (f32x4){0.f, 0.f, 0.f, 0.f};

  for (int kb = 0; kb < KB; ++kb) {
    union { unsigned short u[8]; bf16x8 v; } hu, lu;
    if (sIn) {
      const float* xp = Xb + (size_t)(kb * 32 + 8 * jS) * S + ss;
#pragma unroll
      for (int i = 0; i < 8; ++i) {
        float xv = xp[(size_t)i * S];
        unsigned short h = f2bf(xv);
        hu.u[i] = h;
        lu.u[i] = f2bf(xv - bf2f(h));
      }
    } else {
#pragma unroll
      for (int i = 0; i < 8; ++i) { hu.u[i] = 0; lu.u[i] = 0; }
    }
    bf16x8 ahi[OI], alo[OI];
#pragma unroll
    for (int oi = 0; oi < OI; ++oi) {
      const unsigned short* ap =
          Whl + ((size_t)(o0 + 16 * OI * w + 16 * oi + c) * KB + kb) * 64;
      ahi[oi] = *(const bf16x8*)(ap + 8 * g);
      alo[oi] = *(const bf16x8*)(ap + 32 + 8 * g);
    }
    __syncthreads();
    *(bf16x8*)(BsRow + hiOff) = hu.v;
    *(bf16x8*)(BsRow + loOff) = lu.v;
    __syncthreads();
    bf16x8 bhi[4], blo[4];
#pragma unroll
    for (int si = 0; si < 4; ++si) {
      int row = 16 * si + c;
      const unsigned short* bp = Bs + row * 64;
      bhi[si] = *(const bf16x8*)(bp + (g ^ (row & 7)) * 8);
      blo[si] = *(const bf16x8*)(bp + (((4 + g) ^ (row & 7))) * 8);
    }
#pragma unroll
    for (int oi = 0; oi < OI; ++oi)
#pragma unroll
      for (int si = 0; si < 4; ++si) {
        acc[oi][si] = __builtin_amdgcn_mfma_f32_16x16x32_bf16(ahi[oi], bhi[si], acc[oi][si], 0, 0, 0);
        acc[oi][si] = __builtin_amdgcn_mfma_f32_16x16x32_bf16(ahi[oi], blo[si], acc[oi][si], 0, 0, 0);
        acc[oi][si] = __builtin_amdgcn_mfma_f32_16x16x32_bf16(alo[oi], bhi[si], acc[oi][si], 0, 0, 0);
      }
  }
#pragma unroll
  for (int oi = 0; oi < OI; ++oi) {
#pragma unroll
    for (int r = 0; r < 4; ++r) {
      int o = o0 + 16 * OI * w + 16 * oi + 4 * g + r;
      float bv = bias ? bias[o] : 0.f;
#pragma unroll
      for (int si = 0; si < 4; ++si) {
        int s = s0 + 16 * si + c;
        if (s < S) {
          float v = acc[oi][si][r] + bv;
          if (ACT == 1) v = v * 0.5f * (1.0f + erff(v * 0.70710678118654752f));
          Y[(size_t)b * YbS + (size_t)o * S + s] = v;
        }
      }
    }
  }
}

// ---------------------------------------------------------------------------
// L2-normalize q,k head-vectors, convert to bf16 row-major [b][h][s][32].
// K rows stored permuted within 64-row blocks (QK^T acc == PV B-frag layout).
// ---------------------------------------------------------------------------
__global__ __launch_bounds__(256)
void l2ncvt_kernel(const float* __restrict__ qkv, unsigned short* __restrict__ qd,
                   unsigned short* __restrict__ kd, int S, int Sp) {
  int idx = blockIdx.x * 256 + threadIdx.x;
  int s = idx % Sp; int t = idx / Sp;
  int h = t & 7; t >>= 3;
  int qk = t & 1; int b = t >> 1;
  if (b >= 4) return;
  unsigned short* dst;
  int srow;
  if (qk == 0) { dst = qd; srow = s; }
  else {
    dst = kd;
    int blk = s >> 6, j = s & 63;
    srow = (blk << 6) + 32 * ((j >> 2) & 1) + 16 * (j >> 5) + 4 * ((j >> 3) & 3) + (j & 3);
  }
  unsigned wbuf[16];
  if (s < S) {
    const float* base = qkv + ((size_t)b * 768 + qk * 256 + h * 32) * S + s;
    float v[32]; float ss = 0.f;
#pragma unroll
    for (int d = 0; d < 32; ++d) { v[d] = base[(size_t)d * S]; ss += v[d] * v[d]; }
    float inv = 1.0f / fmaxf(sqrtf(ss), 1e-12f);
#pragma unroll
    for (int i = 0; i < 16; ++i) wbuf[i] = packbf2(v[2 * i] * inv, v[2 * i + 1] * inv);
  } else {
#pragma unroll
    for (int i = 0; i < 16; ++i) wbuf[i] = 0u;
  }
  uint4* o = (uint4*)(dst + ((size_t)(b * 8 + h) * Sp + srow) * 32);
#pragma unroll
  for (int i = 0; i < 4; ++i)
    o[i] = make_uint4(wbuf[4 * i], wbuf[4 * i + 1], wbuf[4 * i + 2], wbuf[4 * i + 3]);
}

// ---------------------------------------------------------------------------
// v -> bf16 d-major layout vt[b][h][32][Sp], zero-padded past S.
// ---------------------------------------------------------------------------
__global__ __launch_bounds__(256)
void vcvt_kernel(const float* __restrict__ qkv, unsigned short* __restrict__ vt,
                 int S, int Sp) {
  int idx = blockIdx.x * 256 + threadIdx.x;
  int SpH = Sp >> 1;
  int sp = idx % SpH; int t = idx / SpH;
  int d = t & 31; t >>= 5;
  int h = t & 7; int b = t >> 3;
  if (b >= 4) return;
  const float* src = qkv + ((size_t)b * 768 + 512 + h * 32 + d) * S;
  int s2 = 2 * sp;
  float a = (s2 < S) ? src[s2] : 0.f;
  float c = (s2 + 1 < S) ? src[s2 + 1] : 0.f;
  *(unsigned*)(vt + ((size_t)(b * 8 + h) * 32 + d) * Sp + s2) = packbf2(a, c);
}

// ---------------------------------------------------------------------------
// MFMA flash attention, K-split into KS partials (no online max needed:
// logits bounded by ±0.177). Partials combine by pure summation.
// opart: unnormalized O, [KS][B][256][S]; lpart: denominators [KS][B][8][S].
// ---------------------------------------------------------------------------
template<int KS>
__global__ __launch_bounds__(256)
void attn_mfma_kernel(const unsigned short* __restrict__ qr,
                      const unsigned short* __restrict__ kr,
                      const unsigned short* __restrict__ vt,
                      float* __restrict__ opart, float* __restrict__ lpart,
                      int S, int Sp) {
  const float scale = 0.17677669529663687f;  // 32^-0.5
  int b = blockIdx.z, h = blockIdx.y;
  int qblk = blockIdx.x / KS;
  int ks = blockIdx.x - qblk * KS;
  int w = threadIdx.x >> 6, lane = threadIdx.x & 63;
  int g = lane >> 4, c = lane & 15;
  int q0 = qblk * 64 + w * 16;
  const int chunks = Sp >> 6;
  const int c0 = (ks * chunks) / KS, c1 = ((ks + 1) * chunks) / KS;
  const unsigned short* qbh = qr + (size_t)(b * 8 + h) * Sp * 32;
  const unsigned short* kbh = kr + (size_t)(b * 8 + h) * Sp * 32;
  const unsigned short* vbh = vt + (size_t)(b * 8 + h) * 32 * Sp;

  bf16x8 qf = *(const bf16x8*)(qbh + (size_t)(q0 + c) * 32 + 8 * g);

  f32x4 oacc0 = {0.f, 0.f, 0.f, 0.f};
  f32x4 oacc1 = {0.f, 0.f, 0.f, 0.f};
  float lsum = 0.f;

  for (int ch = c0; ch < c1; ++ch) {
    int k0 = ch * 64;
    f32x4 sa[4];
#pragma unroll
    for (int t = 0; t < 4; ++t) {
      bf16x8 kf = *(const bf16x8*)(kbh + (size_t)(k0 + 16 * t + c) * 32 + 8 * g);
      f32x4 z = {0.f, 0.f, 0.f, 0.f};
      sa[t] = __builtin_amdgcn_mfma_f32_16x16x32_bf16(kf, qf, z, 0, 0, 0);
    }
    float p[4][4];
    if (k0 + 64 <= S) {
#pragma unroll
      for (int t = 0; t < 4; ++t)
#pragma unroll
        for (int r = 0; r < 4; ++r) {
          float e = __expf(sa[t][r] * scale);
          p[t][r] = e; lsum += e;
        }
    } else {
#pragma unroll
      for (int t = 0; t < 4; ++t)
#pragma unroll
        for (int r = 0; r < 4; ++r) {
          int key = k0 + 32 * (t & 1) + 8 * g + 4 * (t >> 1) + r;
          float e = (key < S) ? __expf(sa[t][r] * scale) : 0.f;
          p[t][r] = e; lsum += e;
        }
    }
    unsigned pk[4][2];
#pragma unroll
    for (int t = 0; t < 4; ++t) {
      pk[t][0] = packbf2(p[t][0], p[t][1]);
      pk[t][1] = packbf2(p[t][2], p[t][3]);
    }
#pragma unroll
    for (int kb = 0; kb < 2; ++kb) {
      union { bf16x8 v; unsigned u[4]; } pf;
      pf.u[0] = pk[kb][0];
      pf.u[1] = pk[kb][1];
      pf.u[2] = pk[2 + kb][0];
      pf.u[3] = pk[2 + kb][1];
      bf16x8 vf0 = *(const bf16x8*)(vbh + (size_t)c * Sp + k0 + 32 * kb + 8 * g);
      bf16x8 vf1 = *(const bf16x8*)(vbh + (size_t)(16 + c) * Sp + k0 + 32 * kb + 8 * g);
      oacc0 = __builtin_amdgcn_mfma_f32_16x16x32_bf16(vf0, pf.v, oacc0, 0, 0, 0);
      oacc1 = __builtin_amdgcn_mfma_f32_16x16x32_bf16(vf1, pf.v, oacc1, 0, 0, 0);
    }
  }
  lsum += __shfl_xor(lsum, 16, 64);
  lsum += __shfl_xor(lsum, 32, 64);
  int q = q0 + c;
  if (q < S) {
    size_t ob = ((size_t)(ks * 4 + b) * 256 + h * 32) * S + q;
#pragma unroll
    for (int r = 0; r < 4; ++r) {
      opart[ob + (size_t)(4 * g + r) * S]      = oacc0[r];
      opart[ob + (size_t)(16 + 4 * g + r) * S] = oacc1[r];
    }
  }
  if (lane < 16 && q < S)
    lpart[((size_t)(ks * 4 + b) * 8 + h) * S + q] = lsum;
}

// ---------------------------------------------------------------------------
// Combine K-split partials: att[b][ch][s] = sum_ks O / sum_ks lsum.
// float4 over s. N threads = B*256*(S/4).
// ---------------------------------------------------------------------------
template<int KS>
__global__ __launch_bounds__(256)
void att_combine_kernel(const float* __restrict__ opart,
                        const float* __restrict__ lpart,
                        float* __restrict__ att, int S, int N) {
  int idx = blockIdx.x * 256 + threadIdx.x;
  if (idx >= N) return;
  int S4 = S >> 2;
  int sq = idx % S4; int t = idx / S4;
  int ch = t & 255; int b = t >> 8;
  int s = sq * 4;
  float4 num = {0.f, 0.f, 0.f, 0.f};
  float4 den = {0.f, 0.f, 0.f, 0.f};
#pragma unroll
  for (int ks = 0; ks < KS; ++ks) {
    float4 o4 = *(const float4*)(opart + ((size_t)(ks * 4 + b) * 256 + ch) * S + s);
    float4 l4 = *(const float4*)(lpart + ((size_t)(ks * 4 + b) * 8 + (ch >> 5)) * S + s);
    num.x += o4.x; num.y += o4.y; num.z += o4.z; num.w += o4.w;
    den.x += l4.x; den.y += l4.y; den.z += l4.z; den.w += l4.w;
  }
  float4 r;
  r.x = num.x / den.x; r.y = num.y / den.y; r.z = num.z / den.z; r.w = num.w / den.w;
  *(float4*)(att + ((size_t)b * 256 + ch) * S + s) = r;
}

// ---------------------------------------------------------------------------
__global__ __launch_bounds__(256)
void pool_kernel(const float* __restrict__ x, float* __restrict__ xg) {
  int idx = blockIdx.x * 256 + threadIdx.x;
  if (idx >= 4 * 256 * 144) return;
  int wc = idx % 12;
  int t = idx / 12;
  int hc = t % 12;
  int bc = t / 12;
  const float* p = x + ((size_t)bc * 48 + hc * 4) * 48 + wc * 4;
  float s = 0.f;
#pragma unroll
  for (int dy = 0; dy < 4; ++dy)
#pragma unroll
    for (int dx = 0; dx < 4; ++dx) s += p[dy * 48 + dx];
  xg[idx] = s * (1.0f / 16.0f);
}

__global__ __launch_bounds__(256)
void upsample_kernel(const float* __restrict__ g, float* __restrict__ cat) {
  int idx = blockIdx.x * 256 + threadIdx.x;
  if (idx >= 4 * 256 * 2304) return;
  int xo = idx % 48;
  int t = idx / 48;
  int yo = t % 48;
  int bc = t / 48;
  int b = bc >> 8, c = bc & 255;
  float sy = 0.25f * yo - 0.375f;
  float sx = 0.25f * xo - 0.375f;
  int y0 = (int)floorf(sy); float fy = sy - (float)y0;
  int x0 = (int)floorf(sx); float fx = sx - (float)x0;
  int y0c = min(11, max(0, y0)), y1c = min(11, max(0, y0 + 1));
  int x0c = min(11, max(0, x0)), x1c = min(11, max(0, x0 + 1));
  const float* gb = g + (size_t)bc * 144;
  float v00 = gb[y0c * 12 + x0c], v01 = gb[y0c * 12 + x1c];
  float v10 = gb[y1c * 12 + x0c], v11 = gb[y1c * 12 + x1c];
  float v = (1.f - fy) * ((1.f - fx) * v00 + fx * v01) + fy * ((1.f - fx) * v10 + fx * v11);
  cat[((size_t)b * 512 + 256 + c) * 2304 + yo * 48 + xo] = v;
}

// ---------------------------------------------------------------------------
extern "C" void kernel_launch(void* const* d_in, const int* in_sizes, int n_in,
                              void* d_out, int out_size, void* d_ws, size_t ws_size,
                              hipStream_t stream) {
  const float* x        = (const float*)d_in[0];
  const float* w_qkv_l  = (const float*)d_in[1];
  const float* w_proj_l = (const float*)d_in[2];
  const float* b_proj_l = (const float*)d_in[3];
  const float* w_qkv_g  = (const float*)d_in[4];
  const float* w_proj_g = (const float*)d_in[5];
  const float* b_proj_g = (const float*)d_in[6];
  const float* w_f1     = (const float*)d_in[7];
  const float* b_f1     = (const float*)d_in[8];
  const float* w_f2     = (const float*)d_in[9];
  const float* b_f2     = (const float*)d_in[10];
  float* out = (float*)d_out;

  const int S = 2304, Sg = 144, B = 4;
  const int Sp = 2304, Sgp = 192;
  const int KS = 3;

  char* wsp = (char*)d_ws;
  size_t off = 0;
  auto alloc = [&](size_t bytes) { char* p = wsp + off; off = (off + bytes + 255) & ~(size_t)255; return p; };
  float* qkv_l = (float*)alloc((size_t)B * 768 * S * 4);   // reused as opart_l
  float* att_l = (float*)alloc((size_t)B * 256 * S * 4);
  float* cat   = (float*)alloc((size_t)B * 512 * S * 4);
  float* hbuf  = (float*)alloc((size_t)B * 256 * S * 4);
  float* xg    = (float*)alloc((size_t)B * 256 * Sg * 4);
  float* qkv_g = (float*)alloc((size_t)B * 768 * Sg * 4);  // reused as opart_g
  float* att_g = (float*)alloc((size_t)B * 256 * Sg * 4);
  float* gsm   = (float*)alloc((size_t)B * 256 * Sg * 4);
  unsigned short* qr_l = (unsigned short*)alloc((size_t)B * 8 * Sp * 32 * 2);
  unsigned short* kr_l = (unsigned short*)alloc((size_t)B * 8 * Sp * 32 * 2);
  unsigned short* vt_l = (unsigned short*)alloc((size_t)B * 8 * Sp * 32 * 2);
  unsigned short* qr_g = (unsigned short*)alloc((size_t)B * 8 * Sgp * 32 * 2);
  unsigned short* kr_g = (unsigned short*)alloc((size_t)B * 8 * Sgp * 32 * 2);
  unsigned short* vt_g = (unsigned short*)alloc((size_t)B * 8 * Sgp * 32 * 2);
  unsigned short* whl_qkv_l  = (unsigned short*)alloc((size_t)768 * 256 * 2 * 2);
  unsigned short* whl_proj_l = (unsigned short*)alloc((size_t)256 * 256 * 2 * 2);
  unsigned short* whl_qkv_g  = (unsigned short*)alloc((size_t)768 * 256 * 2 * 2);
  unsigned short* whl_proj_g = (unsigned short*)alloc((size_t)256 * 256 * 2 * 2);
  unsigned short* whl_f1     = (unsigned short*)alloc((size_t)256 * 512 * 2 * 2);
  unsigned short* whl_f2     = (unsigned short*)alloc((size_t)256 * 256 * 2 * 2);
  float* lpart_l = (float*)alloc((size_t)KS * B * 8 * S * 4);
  float* lpart_g = (float*)alloc((size_t)KS * B * 8 * Sg * 4);
  float* opart_l = qkv_l;  // qkv_l dead after l2ncvt/vcvt consume it
  float* opart_g = qkv_g;

  dim3 blk(256);

  wsplit_kernel<<<dim3(88), blk, 0, stream>>>(
      w_qkv_l, w_proj_l, w_qkv_g, w_proj_g, w_f1, w_f2,
      whl_qkv_l, whl_proj_l, whl_qkv_g, whl_proj_g, whl_f1, whl_f2);

  // ----- local branch -----
  conv_mfma_kernel<0, 128><<<dim3(36, 6, B), blk, 0, stream>>>(
      whl_qkv_l, x, nullptr, qkv_l, 256, S, (size_t)768 * S);
  l2ncvt_kernel<<<dim3((B * 2 * 8 * Sp) / 256), blk, 0, stream>>>(qkv_l, qr_l, kr_l, S, Sp);
  vcvt_kernel<<<dim3((B * 8 * 32 * (Sp / 2)) / 256), blk, 0, stream>>>(qkv_l, vt_l, S, Sp);
  attn_mfma_kernel<KS><<<dim3((Sp / 64) * KS, 8, B), blk, 0, stream>>>(
      qr_l, kr_l, vt_l, opart_l, lpart_l, S, Sp);
  att_combine_kernel<KS><<<dim3((B * 256 * (S / 4) + 255) / 256), blk, 0, stream>>>(
      opart_l, lpart_l, att_l, S, B * 256 * (S / 4));
  conv_mfma_kernel<0, 64><<<dim3(36, 4, B), blk, 0, stream>>>(
      whl_proj_l, att_l, b_proj_l, cat, 256, S, (size_t)512 * S);

  // ----- global branch -----
  pool_kernel<<<dim3(576), blk, 0, stream>>>(x, xg);
  conv_mfma_kernel<0, 64><<<dim3(3, 12, B), blk, 0, stream>>>(
      whl_qkv_g, xg, nullptr, qkv_g, 256, Sg, (size_t)768 * Sg);
  l2ncvt_kernel<<<dim3((B * 2 * 8 * Sgp) / 256), blk, 0, stream>>>(qkv_g, qr_g, kr_g, Sg, Sgp);
  vcvt_kernel<<<dim3((B * 8 * 32 * (Sgp / 2)) / 256), blk, 0, stream>>>(qkv_g, vt_g, Sg, Sgp);
  attn_mfma_kernel<KS><<<dim3((Sgp / 64) * KS, 8, B), blk, 0, stream>>>(
      qr_g, kr_g, vt_g, opart_g, lpart_g, Sg, Sgp);
  att_combine_kernel<KS><<<dim3((B * 256 * (Sg / 4) + 255) / 256), blk, 0, stream>>>(
      opart_g, lpart_g, att_g, Sg, B * 256 * (Sg / 4));
  conv_mfma_kernel<0, 64><<<dim3(3, 4, B), blk, 0, stream>>>(
      whl_proj_g, att_g, b_proj_g, gsm, 256, Sg, (size_t)256 * Sg);
  upsample_kernel<<<dim3(9216), blk, 0, stream>>>(gsm, cat);

  // ----- fuse: f1 (GELU) then f2 -----
  conv_mfma_kernel<1, 64><<<dim3(36, 4, B), blk, 0, stream>>>(
      whl_f1, cat, b_f1, hbuf, 512, S, (size_t)256 * S);
  conv_mfma_kernel<0, 64><<<dim3(36, 4, B), blk, 0, stream>>>(
      whl_f2, hbuf, b_f2, out, 256, S, (size_t)256 * S);
}

// Round 6
// 260.278 us; speedup vs baseline: 6.4776x; 1.0507x over previous
//
#include <hip/hip_runtime.h>
#include <hip/hip_bf16.h>
#include <math.h>

typedef __attribute__((ext_vector_type(8))) short bf16x8;
typedef __attribute__((ext_vector_type(4))) float f32x4;

__device__ inline unsigned short f2bf(float x) {
  __hip_bfloat16 h = __float2bfloat16(x);
  return __builtin_bit_cast(unsigned short, h);
}
__device__ inline float bf2f(unsigned short u) {
  unsigned v = ((unsigned)u) << 16;
  return __builtin_bit_cast(float, v);
}
__device__ inline unsigned packbf2(float lo, float hi) {
  return (unsigned)f2bf(lo) | ((unsigned)f2bf(hi) << 16);
}

// ---------------------------------------------------------------------------
// Weight split: W[O][Cin] f32 -> Whl rows of 128B: [o][kb][32 hi bf16 | 32 lo].
// ---------------------------------------------------------------------------
__global__ __launch_bounds__(256)
void wsplit_kernel(const float* __restrict__ w0, const float* __restrict__ w1,
                   const float* __restrict__ w2, const float* __restrict__ w3,
                   const float* __restrict__ w4, const float* __restrict__ w5,
                   unsigned short* __restrict__ d0, unsigned short* __restrict__ d1,
                   unsigned short* __restrict__ d2, unsigned short* __restrict__ d3,
                   unsigned short* __restrict__ d4, unsigned short* __restrict__ d5) {
  int r = blockIdx.x * 256 + threadIdx.x;
  const float* src; unsigned short* dst;
  if (r < 6144) { src = w0; dst = d0; }
  else if (r < 8192) { src = w1; dst = d1; r -= 6144; }
  else if (r < 14336) { src = w2; dst = d2; r -= 8192; }
  else if (r < 16384) { src = w3; dst = d3; r -= 14336; }
  else if (r < 20480) { src = w4; dst = d4; r -= 16384; }
  else if (r < 22528) { src = w5; dst = d5; r -= 20480; }
  else return;
  const float* in = src + (size_t)r * 32;
  union { unsigned short u[32]; uint4 q[4]; } H, L;
#pragma unroll
  for (int i = 0; i < 32; ++i) {
    float x = in[i];
    unsigned short h = f2bf(x);
    H.u[i] = h;
    L.u[i] = f2bf(x - bf2f(h));
  }
  uint4* op = (uint4*)(dst + (size_t)r * 64);
#pragma unroll
  for (int q = 0; q < 4; ++q) { op[q] = H.q[q]; op[4 + q] = L.q[q]; }
}

// ---------------------------------------------------------------------------
// conv1x1 as split-precision MFMA GEMM. Tile OT(o) x 64(s), K-step 32.
// ---------------------------------------------------------------------------
template<int ACT, int OT>
__global__ __launch_bounds__(256)
void conv_mfma_kernel(const unsigned short* __restrict__ Whl,
                      const float* __restrict__ X,
                      const float* __restrict__ bias,
                      float* __restrict__ Y,
                      int Cin, int S, size_t YbS) {
  constexpr int OI = OT / 64;  // o-frags per wave
  __shared__ __align__(16) unsigned short Bs[64 * 64];  // 8 KB
  const int tid = threadIdx.x;
  const int w = tid >> 6, lane = tid & 63;
  const int g = lane >> 4, c = lane & 15;
  const int s0 = blockIdx.x * 64;
  const int o0 = blockIdx.y * OT;
  const int b = blockIdx.z;
  const int KB = Cin >> 5;
  const float* Xb = X + (size_t)b * Cin * S;
  const int sRow = tid & 63;
  const int jS = tid >> 6;
  const int ss = s0 + sRow;
  const bool sIn = (ss < S);
  unsigned short* BsRow = Bs + sRow * 64;
  const int hiOff = (jS ^ (sRow & 7)) * 8;
  const int loOff = ((4 + jS) ^ (sRow & 7)) * 8;

  f32x4 acc[OI][4];
#pragma unroll
  for (int oi = 0; oi < OI; ++oi)
#pragma unroll
    for (int si = 0; si < 4; ++si) acc[oi][si] = (f32x4){0.f, 0.f, 0.f, 0.f};

  for (int kb = 0; kb < KB; ++kb) {
    union { unsigned short u[8]; bf16x8 v; } hu, lu;
    if (sIn) {
      const float* xp = Xb + (size_t)(kb * 32 + 8 * jS) * S + ss;
#pragma unroll
      for (int i = 0; i < 8; ++i) {
        float xv = xp[(size_t)i * S];
        unsigned short h = f2bf(xv);
        hu.u[i] = h;
        lu.u[i] = f2bf(xv - bf2f(h));
      }
    } else {
#pragma unroll
      for (int i = 0; i < 8; ++i) { hu.u[i] = 0; lu.u[i] = 0; }
    }
    bf16x8 ahi[OI], alo[OI];
#pragma unroll
    for (int oi = 0; oi < OI; ++oi) {
      const unsigned short* ap =
          Whl + ((size_t)(o0 + 16 * OI * w + 16 * oi + c) * KB + kb) * 64;
      ahi[oi] = *(const bf16x8*)(ap + 8 * g);
      alo[oi] = *(const bf16x8*)(ap + 32 + 8 * g);
    }
    __syncthreads();
    *(bf16x8*)(BsRow + hiOff) = hu.v;
    *(bf16x8*)(BsRow + loOff) = lu.v;
    __syncthreads();
    bf16x8 bhi[4], blo[4];
#pragma unroll
    for (int si = 0; si < 4; ++si) {
      int row = 16 * si + c;
      const unsigned short* bp = Bs + row * 64;
      bhi[si] = *(const bf16x8*)(bp + (g ^ (row & 7)) * 8);
      blo[si] = *(const bf16x8*)(bp + (((4 + g) ^ (row & 7))) * 8);
    }
#pragma unroll
    for (int oi = 0; oi < OI; ++oi)
#pragma unroll
      for (int si = 0; si < 4; ++si) {
        acc[oi][si] = __builtin_amdgcn_mfma_f32_16x16x32_bf16(ahi[oi], bhi[si], acc[oi][si], 0, 0, 0);
        acc[oi][si] = __builtin_amdgcn_mfma_f32_16x16x32_bf16(ahi[oi], blo[si], acc[oi][si], 0, 0, 0);
        acc[oi][si] = __builtin_amdgcn_mfma_f32_16x16x32_bf16(alo[oi], bhi[si], acc[oi][si], 0, 0, 0);
      }
  }
#pragma unroll
  for (int oi = 0; oi < OI; ++oi) {
#pragma unroll
    for (int r = 0; r < 4; ++r) {
      int o = o0 + 16 * OI * w + 16 * oi + 4 * g + r;
      float bv = bias ? bias[o] : 0.f;
#pragma unroll
      for (int si = 0; si < 4; ++si) {
        int s = s0 + 16 * si + c;
        if (s < S) {
          float v = acc[oi][si][r] + bv;
          if (ACT == 1) v = v * 0.5f * (1.0f + erff(v * 0.70710678118654752f));
          Y[(size_t)b * YbS + (size_t)o * S + s] = v;
        }
      }
    }
  }
}

// ---------------------------------------------------------------------------
// L2-normalize q,k head-vectors, convert to bf16 row-major [b][h][s][32].
// q additionally pre-scaled by hd^-0.5 * log2(e) so attention can use exp2.
// K rows stored permuted within 64-row blocks (QK^T acc == PV B-frag layout).
// ---------------------------------------------------------------------------
__global__ __launch_bounds__(256)
void l2ncvt_kernel(const float* __restrict__ qkv, unsigned short* __restrict__ qd,
                   unsigned short* __restrict__ kd, int S, int Sp) {
  int idx = blockIdx.x * 256 + threadIdx.x;
  int s = idx % Sp; int t = idx / Sp;
  int h = t & 7; t >>= 3;
  int qk = t & 1; int b = t >> 1;
  if (b >= 4) return;
  unsigned short* dst;
  int srow;
  if (qk == 0) { dst = qd; srow = s; }
  else {
    dst = kd;
    int blk = s >> 6, j = s & 63;
    srow = (blk << 6) + 32 * ((j >> 2) & 1) + 16 * (j >> 5) + 4 * ((j >> 3) & 3) + (j & 3);
  }
  unsigned wbuf[16];
  if (s < S) {
    const float* base = qkv + ((size_t)b * 768 + qk * 256 + h * 32) * S + s;
    float v[32]; float ss = 0.f;
#pragma unroll
    for (int d = 0; d < 32; ++d) { v[d] = base[(size_t)d * S]; ss += v[d] * v[d]; }
    float inv = 1.0f / fmaxf(sqrtf(ss), 1e-12f);
    if (qk == 0) inv *= 0.25506607138105343f;  // 32^-0.5 * log2(e)
#pragma unroll
    for (int i = 0; i < 16; ++i) wbuf[i] = packbf2(v[2 * i] * inv, v[2 * i + 1] * inv);
  } else {
#pragma unroll
    for (int i = 0; i < 16; ++i) wbuf[i] = 0u;
  }
  uint4* o = (uint4*)(dst + ((size_t)(b * 8 + h) * Sp + srow) * 32);
#pragma unroll
  for (int i = 0; i < 4; ++i)
    o[i] = make_uint4(wbuf[4 * i], wbuf[4 * i + 1], wbuf[4 * i + 2], wbuf[4 * i + 3]);
}

// ---------------------------------------------------------------------------
// v -> bf16 d-major layout vt[b][h][32][Sp], zero-padded past S.
// ---------------------------------------------------------------------------
__global__ __launch_bounds__(256)
void vcvt_kernel(const float* __restrict__ qkv, unsigned short* __restrict__ vt,
                 int S, int Sp) {
  int idx = blockIdx.x * 256 + threadIdx.x;
  int SpH = Sp >> 1;
  int sp = idx % SpH; int t = idx / SpH;
  int d = t & 31; t >>= 5;
  int h = t & 7; int b = t >> 3;
  if (b >= 4) return;
  const float* src = qkv + ((size_t)b * 768 + 512 + h * 32 + d) * S;
  int s2 = 2 * sp;
  float a = (s2 < S) ? src[s2] : 0.f;
  float c = (s2 + 1 < S) ? src[s2 + 1] : 0.f;
  *(unsigned*)(vt + ((size_t)(b * 8 + h) * 32 + d) * Sp + s2) = packbf2(a, c);
}

// ---------------------------------------------------------------------------
// MFMA flash attention, K-split into KS partials. No online max (logits
// bounded: q,k L2-normalized). Partials combine by pure summation.
// GRID IS (8=h, qblk*KS, b): blockIdx.x fastest in dispatch -> lin%8 == h,
// pinning each head to one XCD so its K/V (~2.4 MB over 4 batches) stays
// resident in that XCD's private L2 instead of thrashing all 8.
// ---------------------------------------------------------------------------
template<int KS>
__global__ __launch_bounds__(256)
void attn_mfma_kernel(const unsigned short* __restrict__ qr,
                      const unsigned short* __restrict__ kr,
                      const unsigned short* __restrict__ vt,
                      float* __restrict__ opart, float* __restrict__ lpart,
                      int S, int Sp) {
  int h = blockIdx.x, b = blockIdx.z;
  int qblk = blockIdx.y / KS;
  int ks = blockIdx.y - qblk * KS;
  int w = threadIdx.x >> 6, lane = threadIdx.x & 63;
  int g = lane >> 4, c = lane & 15;
  int q0 = qblk * 64 + w * 16;
  const int chunks = Sp >> 6;
  const int c0 = (ks * chunks) / KS, c1 = ((ks + 1) * chunks) / KS;
  const unsigned short* qbh = qr + (size_t)(b * 8 + h) * Sp * 32;
  const unsigned short* kbh = kr + (size_t)(b * 8 + h) * Sp * 32;
  const unsigned short* vbh = vt + (size_t)(b * 8 + h) * 32 * Sp;

  bf16x8 qf = *(const bf16x8*)(qbh + (size_t)(q0 + c) * 32 + 8 * g);

  f32x4 oacc0 = {0.f, 0.f, 0.f, 0.f};
  f32x4 oacc1 = {0.f, 0.f, 0.f, 0.f};
  float lsum = 0.f;

  for (int ch = c0; ch < c1; ++ch) {
    int k0 = ch * 64;
    f32x4 sa[4];
#pragma unroll
    for (int t = 0; t < 4; ++t) {
      bf16x8 kf = *(const bf16x8*)(kbh + (size_t)(k0 + 16 * t + c) * 32 + 8 * g);
      f32x4 z = {0.f, 0.f, 0.f, 0.f};
      sa[t] = __builtin_amdgcn_mfma_f32_16x16x32_bf16(kf, qf, z, 0, 0, 0);
    }
    float p[4][4];
    if (k0 + 64 <= S) {
#pragma unroll
      for (int t = 0; t < 4; ++t)
#pragma unroll
        for (int r = 0; r < 4; ++r) {
          float e = exp2f(sa[t][r]);   // q pre-scaled by scale*log2e
          p[t][r] = e; lsum += e;
        }
    } else {
#pragma unroll
      for (int t = 0; t < 4; ++t)
#pragma unroll
        for (int r = 0; r < 4; ++r) {
          int key = k0 + 32 * (t & 1) + 8 * g + 4 * (t >> 1) + r;
          float e = (key < S) ? exp2f(sa[t][r]) : 0.f;
          p[t][r] = e; lsum += e;
        }
    }
    unsigned pk[4][2];
#pragma unroll
    for (int t = 0; t < 4; ++t) {
      pk[t][0] = packbf2(p[t][0], p[t][1]);
      pk[t][1] = packbf2(p[t][2], p[t][3]);
    }
#pragma unroll
    for (int kb = 0; kb < 2; ++kb) {
      union { bf16x8 v; unsigned u[4]; } pf;
      pf.u[0] = pk[kb][0];
      pf.u[1] = pk[kb][1];
      pf.u[2] = pk[2 + kb][0];
      pf.u[3] = pk[2 + kb][1];
      bf16x8 vf0 = *(const bf16x8*)(vbh + (size_t)c * Sp + k0 + 32 * kb + 8 * g);
      bf16x8 vf1 = *(const bf16x8*)(vbh + (size_t)(16 + c) * Sp + k0 + 32 * kb + 8 * g);
      oacc0 = __builtin_amdgcn_mfma_f32_16x16x32_bf16(vf0, pf.v, oacc0, 0, 0, 0);
      oacc1 = __builtin_amdgcn_mfma_f32_16x16x32_bf16(vf1, pf.v, oacc1, 0, 0, 0);
    }
  }
  lsum += __shfl_xor(lsum, 16, 64);
  lsum += __shfl_xor(lsum, 32, 64);
  int q = q0 + c;
  if (q < S) {
    size_t ob = ((size_t)(ks * 4 + b) * 256 + h * 32) * S + q;
#pragma unroll
    for (int r = 0; r < 4; ++r) {
      opart[ob + (size_t)(4 * g + r) * S]      = oacc0[r];
      opart[ob + (size_t)(16 + 4 * g + r) * S] = oacc1[r];
    }
  }
  if (lane < 16 && q < S)
    lpart[((size_t)(ks * 4 + b) * 8 + h) * S + q] = lsum;
}

// ---------------------------------------------------------------------------
// Combine K-split partials: att[b][ch][s] = sum_ks O / sum_ks lsum.
// ---------------------------------------------------------------------------
template<int KS>
__global__ __launch_bounds__(256)
void att_combine_kernel(const float* __restrict__ opart,
                        const float* __restrict__ lpart,
                        float* __restrict__ att, int S, int N) {
  int idx = blockIdx.x * 256 + threadIdx.x;
  if (idx >= N) return;
  int S4 = S >> 2;
  int sq = idx % S4; int t = idx / S4;
  int ch = t & 255; int b = t >> 8;
  int s = sq * 4;
  float4 num = {0.f, 0.f, 0.f, 0.f};
  float4 den = {0.f, 0.f, 0.f, 0.f};
#pragma unroll
  for (int ks = 0; ks < KS; ++ks) {
    float4 o4 = *(const float4*)(opart + ((size_t)(ks * 4 + b) * 256 + ch) * S + s);
    float4 l4 = *(const float4*)(lpart + ((size_t)(ks * 4 + b) * 8 + (ch >> 5)) * S + s);
    num.x += o4.x; num.y += o4.y; num.z += o4.z; num.w += o4.w;
    den.x += l4.x; den.y += l4.y; den.z += l4.z; den.w += l4.w;
  }
  float4 r;
  r.x = num.x / den.x; r.y = num.y / den.y; r.z = num.z / den.z; r.w = num.w / den.w;
  *(float4*)(att + ((size_t)b * 256 + ch) * S + s) = r;
}

// ---------------------------------------------------------------------------
__global__ __launch_bounds__(256)
void pool_kernel(const float* __restrict__ x, float* __restrict__ xg) {
  int idx = blockIdx.x * 256 + threadIdx.x;
  if (idx >= 4 * 256 * 144) return;
  int wc = idx % 12;
  int t = idx / 12;
  int hc = t % 12;
  int bc = t / 12;
  const float* p = x + ((size_t)bc * 48 + hc * 4) * 48 + wc * 4;
  float s = 0.f;
#pragma unroll
  for (int dy = 0; dy < 4; ++dy)
#pragma unroll
    for (int dx = 0; dx < 4; ++dx) s += p[dy * 48 + dx];
  xg[idx] = s * (1.0f / 16.0f);
}

__global__ __launch_bounds__(256)
void upsample_kernel(const float* __restrict__ g, float* __restrict__ cat) {
  int idx = blockIdx.x * 256 + threadIdx.x;
  if (idx >= 4 * 256 * 2304) return;
  int xo = idx % 48;
  int t = idx / 48;
  int yo = t % 48;
  int bc = t / 48;
  int b = bc >> 8, c = bc & 255;
  float sy = 0.25f * yo - 0.375f;
  float sx = 0.25f * xo - 0.375f;
  int y0 = (int)floorf(sy); float fy = sy - (float)y0;
  int x0 = (int)floorf(sx); float fx = sx - (float)x0;
  int y0c = min(11, max(0, y0)), y1c = min(11, max(0, y0 + 1));
  int x0c = min(11, max(0, x0)), x1c = min(11, max(0, x0 + 1));
  const float* gb = g + (size_t)bc * 144;
  float v00 = gb[y0c * 12 + x0c], v01 = gb[y0c * 12 + x1c];
  float v10 = gb[y1c * 12 + x0c], v11 = gb[y1c * 12 + x1c];
  float v = (1.f - fy) * ((1.f - fx) * v00 + fx * v01) + fy * ((1.f - fx) * v10 + fx * v11);
  cat[((size_t)b * 512 + 256 + c) * 2304 + yo * 48 + xo] = v;
}

// ---------------------------------------------------------------------------
extern "C" void kernel_launch(void* const* d_in, const int* in_sizes, int n_in,
                              void* d_out, int out_size, void* d_ws, size_t ws_size,
                              hipStream_t stream) {
  const float* x        = (const float*)d_in[0];
  const float* w_qkv_l  = (const float*)d_in[1];
  const float* w_proj_l = (const float*)d_in[2];
  const float* b_proj_l = (const float*)d_in[3];
  const float* w_qkv_g  = (const float*)d_in[4];
  const float* w_proj_g = (const float*)d_in[5];
  const float* b_proj_g = (const float*)d_in[6];
  const float* w_f1     = (const float*)d_in[7];
  const float* b_f1     = (const float*)d_in[8];
  const float* w_f2     = (const float*)d_in[9];
  const float* b_f2     = (const float*)d_in[10];
  float* out = (float*)d_out;

  const int S = 2304, Sg = 144, B = 4;
  const int Sp = 2304, Sgp = 192;
  const int KS = 3;

  char* wsp = (char*)d_ws;
  size_t off = 0;
  auto alloc = [&](size_t bytes) { char* p = wsp + off; off = (off + bytes + 255) & ~(size_t)255; return p; };
  float* qkv_l = (float*)alloc((size_t)B * 768 * S * 4);   // reused as opart_l
  float* att_l = (float*)alloc((size_t)B * 256 * S * 4);
  float* cat   = (float*)alloc((size_t)B * 512 * S * 4);
  float* hbuf  = (float*)alloc((size_t)B * 256 * S * 4);
  float* xg    = (float*)alloc((size_t)B * 256 * Sg * 4);
  float* qkv_g = (float*)alloc((size_t)B * 768 * Sg * 4);  // reused as opart_g
  float* att_g = (float*)alloc((size_t)B * 256 * Sg * 4);
  float* gsm   = (float*)alloc((size_t)B * 256 * Sg * 4);
  unsigned short* qr_l = (unsigned short*)alloc((size_t)B * 8 * Sp * 32 * 2);
  unsigned short* kr_l = (unsigned short*)alloc((size_t)B * 8 * Sp * 32 * 2);
  unsigned short* vt_l = (unsigned short*)alloc((size_t)B * 8 * Sp * 32 * 2);
  unsigned short* qr_g = (unsigned short*)alloc((size_t)B * 8 * Sgp * 32 * 2);
  unsigned short* kr_g = (unsigned short*)alloc((size_t)B * 8 * Sgp * 32 * 2);
  unsigned short* vt_g = (unsigned short*)alloc((size_t)B * 8 * Sgp * 32 * 2);
  unsigned short* whl_qkv_l  = (unsigned short*)alloc((size_t)768 * 256 * 2 * 2);
  unsigned short* whl_proj_l = (unsigned short*)alloc((size_t)256 * 256 * 2 * 2);
  unsigned short* whl_qkv_g  = (unsigned short*)alloc((size_t)768 * 256 * 2 * 2);
  unsigned short* whl_proj_g = (unsigned short*)alloc((size_t)256 * 256 * 2 * 2);
  unsigned short* whl_f1     = (unsigned short*)alloc((size_t)256 * 512 * 2 * 2);
  unsigned short* whl_f2     = (unsigned short*)alloc((size_t)256 * 256 * 2 * 2);
  float* lpart_l = (float*)alloc((size_t)KS * B * 8 * S * 4);
  float* lpart_g = (float*)alloc((size_t)KS * B * 8 * Sg * 4);
  float* opart_l = qkv_l;  // qkv_l dead after l2ncvt/vcvt consume it
  float* opart_g = qkv_g;

  dim3 blk(256);

  wsplit_kernel<<<dim3(88), blk, 0, stream>>>(
      w_qkv_l, w_proj_l, w_qkv_g, w_proj_g, w_f1, w_f2,
      whl_qkv_l, whl_proj_l, whl_qkv_g, whl_proj_g, whl_f1, whl_f2);

  // ----- local branch -----
  conv_mfma_kernel<0, 128><<<dim3(36, 6, B), blk, 0, stream>>>(
      whl_qkv_l, x, nullptr, qkv_l, 256, S, (size_t)768 * S);
  l2ncvt_kernel<<<dim3((B * 2 * 8 * Sp) / 256), blk, 0, stream>>>(qkv_l, qr_l, kr_l, S, Sp);
  vcvt_kernel<<<dim3((B * 8 * 32 * (Sp / 2)) / 256), blk, 0, stream>>>(qkv_l, vt_l, S, Sp);
  attn_mfma_kernel<KS><<<dim3(8, (Sp / 64) * KS, B), blk, 0, stream>>>(
      qr_l, kr_l, vt_l, opart_l, lpart_l, S, Sp);
  att_combine_kernel<KS><<<dim3((B * 256 * (S / 4) + 255) / 256), blk, 0, stream>>>(
      opart_l, lpart_l, att_l, S, B * 256 * (S / 4));
  conv_mfma_kernel<0, 64><<<dim3(36, 4, B), blk, 0, stream>>>(
      whl_proj_l, att_l, b_proj_l, cat, 256, S, (size_t)512 * S);

  // ----- global branch -----
  pool_kernel<<<dim3(576), blk, 0, stream>>>(x, xg);
  conv_mfma_kernel<0, 64><<<dim3(3, 12, B), blk, 0, stream>>>(
      whl_qkv_g, xg, nullptr, qkv_g, 256, Sg, (size_t)768 * Sg);
  l2ncvt_kernel<<<dim3((B * 2 * 8 * Sgp) / 256), blk, 0, stream>>>(qkv_g, qr_g, kr_g, Sg, Sgp);
  vcvt_kernel<<<dim3((B * 8 * 32 * (Sgp / 2)) / 256), blk, 0, stream>>>(qkv_g, vt_g, Sg, Sgp);
  attn_mfma_kernel<KS><<<dim3(8, (Sgp / 64) * KS, B), blk, 0, stream>>>(
      qr_g, kr_g, vt_g, opart_g, lpart_g, Sg, Sgp);
  att_combine_kernel<KS><<<dim3((B * 256 * (Sg / 4) + 255) / 256), blk, 0, stream>>>(
      opart_g, lpart_g, att_g, Sg, B * 256 * (Sg / 4));
  conv_mfma_kernel<0, 64><<<dim3(3, 4, B), blk, 0, stream>>>(
      whl_proj_g, att_g, b_proj_g, gsm, 256, Sg, (size_t)256 * Sg);
  upsample_kernel<<<dim3(9216), blk, 0, stream>>>(gsm, cat);

  // ----- fuse: f1 (GELU) then f2 -----
  conv_mfma_kernel<1, 64><<<dim3(36, 4, B), blk, 0, stream>>>(
      whl_f1, cat, b_f1, hbuf, 512, S, (size_t)256 * S);
  conv_mfma_kernel<0, 64><<<dim3(36, 4, B), blk, 0, stream>>>(
      whl_f2, hbuf, b_f2, out, 256, S, (size_t)256 * S);
}

// Round 7
// 259.088 us; speedup vs baseline: 6.5073x; 1.0046x over previous
//
#include <hip/hip_runtime.h>
#include <hip/hip_bf16.h>
#include <math.h>

typedef __attribute__((ext_vector_type(8))) short bf16x8;
typedef __attribute__((ext_vector_type(4))) float f32x4;

__device__ inline unsigned short f2bf(float x) {
  __hip_bfloat16 h = __float2bfloat16(x);
  return __builtin_bit_cast(unsigned short, h);
}
__device__ inline float bf2f(unsigned short u) {
  unsigned v = ((unsigned)u) << 16;
  return __builtin_bit_cast(float, v);
}
__device__ inline unsigned packbf2(float lo, float hi) {
  return (unsigned)f2bf(lo) | ((unsigned)f2bf(hi) << 16);
}
// One-instruction RNE pack of two f32 -> packed bf16x2 (low = a, high = b).
__device__ inline unsigned cvtpk(float a, float b) {
  unsigned r;
  asm("v_cvt_pk_bf16_f32 %0, %1, %2" : "=v"(r) : "v"(a), "v"(b));
  return r;
}
__device__ inline float bf2f_lo(unsigned p) {
  return __builtin_bit_cast(float, p << 16);
}
__device__ inline float bf2f_hi(unsigned p) {
  return __builtin_bit_cast(float, p & 0xffff0000u);
}

// ---------------------------------------------------------------------------
// Weight split: W[O][Cin] f32 -> Whl rows of 128B: [o][kb][32 hi bf16 | 32 lo].
// ---------------------------------------------------------------------------
__global__ __launch_bounds__(256)
void wsplit_kernel(const float* __restrict__ w0, const float* __restrict__ w1,
                   const float* __restrict__ w2, const float* __restrict__ w3,
                   const float* __restrict__ w4, const float* __restrict__ w5,
                   unsigned short* __restrict__ d0, unsigned short* __restrict__ d1,
                   unsigned short* __restrict__ d2, unsigned short* __restrict__ d3,
                   unsigned short* __restrict__ d4, unsigned short* __restrict__ d5) {
  int r = blockIdx.x * 256 + threadIdx.x;
  const float* src; unsigned short* dst;
  if (r < 6144) { src = w0; dst = d0; }
  else if (r < 8192) { src = w1; dst = d1; r -= 6144; }
  else if (r < 14336) { src = w2; dst = d2; r -= 8192; }
  else if (r < 16384) { src = w3; dst = d3; r -= 14336; }
  else if (r < 20480) { src = w4; dst = d4; r -= 16384; }
  else if (r < 22528) { src = w5; dst = d5; r -= 20480; }
  else return;
  const float* in = src + (size_t)r * 32;
  union { unsigned short u[32]; uint4 q[4]; } H, L;
#pragma unroll
  for (int i = 0; i < 32; ++i) {
    float x = in[i];
    unsigned short h = f2bf(x);
    H.u[i] = h;
    L.u[i] = f2bf(x - bf2f(h));
  }
  uint4* op = (uint4*)(dst + (size_t)r * 64);
#pragma unroll
  for (int q = 0; q < 4; ++q) { op[q] = H.q[q]; op[4 + q] = L.q[q]; }
}

// ---------------------------------------------------------------------------
// conv1x1 as split-precision MFMA GEMM. Tile OT(o) x 64(s), K-step 32.
// Staging uses v_cvt_pk_bf16_f32 (1 instr per bf16 pair) for the hi/lo split.
// ---------------------------------------------------------------------------
template<int ACT, int OT>
__global__ __launch_bounds__(256)
void conv_mfma_kernel(const unsigned short* __restrict__ Whl,
                      const float* __restrict__ X,
                      const float* __restrict__ bias,
                      float* __restrict__ Y,
                      int Cin, int S, size_t YbS) {
  constexpr int OI = OT / 64;  // o-frags per wave
  __shared__ __align__(16) unsigned short Bs[64 * 64];  // 8 KB
  const int tid = threadIdx.x;
  const int w = tid >> 6, lane = tid & 63;
  const int g = lane >> 4, c = lane & 15;
  const int s0 = blockIdx.x * 64;
  const int o0 = blockIdx.y * OT;
  const int b = blockIdx.z;
  const int KB = Cin >> 5;
  const float* Xb = X + (size_t)b * Cin * S;
  const int sRow = tid & 63;
  const int jS = tid >> 6;
  const int ss = s0 + sRow;
  const bool sIn = (ss < S);
  unsigned short* BsRow = Bs + sRow * 64;
  const int hiOff = (jS ^ (sRow & 7)) * 8;
  const int loOff = ((4 + jS) ^ (sRow & 7)) * 8;

  f32x4 acc[OI][4];
#pragma unroll
  for (int oi = 0; oi < OI; ++oi)
#pragma unroll
    for (int si = 0; si < 4; ++si) acc[oi][si] = (f32x4){0.f, 0.f, 0.f, 0.f};

  for (int kb = 0; kb < KB; ++kb) {
    union { unsigned u[4]; bf16x8 v; } hu, lu;
    if (sIn) {
      const float* xp = Xb + (size_t)(kb * 32 + 8 * jS) * S + ss;
#pragma unroll
      for (int i = 0; i < 4; ++i) {
        float x0 = xp[(size_t)(2 * i) * S];
        float x1 = xp[(size_t)(2 * i + 1) * S];
        unsigned hp = cvtpk(x0, x1);
        unsigned lp = cvtpk(x0 - bf2f_lo(hp), x1 - bf2f_hi(hp));
        hu.u[i] = hp; lu.u[i] = lp;
      }
    } else {
#pragma unroll
      for (int i = 0; i < 4; ++i) { hu.u[i] = 0; lu.u[i] = 0; }
    }
    bf16x8 ahi[OI], alo[OI];
#pragma unroll
    for (int oi = 0; oi < OI; ++oi) {
      const unsigned short* ap =
          Whl + ((size_t)(o0 + 16 * OI * w + 16 * oi + c) * KB + kb) * 64;
      ahi[oi] = *(const bf16x8*)(ap + 8 * g);
      alo[oi] = *(const bf16x8*)(ap + 32 + 8 * g);
    }
    __syncthreads();
    *(bf16x8*)(BsRow + hiOff) = hu.v;
    *(bf16x8*)(BsRow + loOff) = lu.v;
    __syncthreads();
    bf16x8 bhi[4], blo[4];
#pragma unroll
    for (int si = 0; si < 4; ++si) {
      int row = 16 * si + c;
      const unsigned short* bp = Bs + row * 64;
      bhi[si] = *(const bf16x8*)(bp + (g ^ (row & 7)) * 8);
      blo[si] = *(const bf16x8*)(bp + (((4 + g) ^ (row & 7))) * 8);
    }
#pragma unroll
    for (int oi = 0; oi < OI; ++oi)
#pragma unroll
      for (int si = 0; si < 4; ++si) {
        acc[oi][si] = __builtin_amdgcn_mfma_f32_16x16x32_bf16(ahi[oi], bhi[si], acc[oi][si], 0, 0, 0);
        acc[oi][si] = __builtin_amdgcn_mfma_f32_16x16x32_bf16(ahi[oi], blo[si], acc[oi][si], 0, 0, 0);
        acc[oi][si] = __builtin_amdgcn_mfma_f32_16x16x32_bf16(alo[oi], bhi[si], acc[oi][si], 0, 0, 0);
      }
  }
#pragma unroll
  for (int oi = 0; oi < OI; ++oi) {
#pragma unroll
    for (int r = 0; r < 4; ++r) {
      int o = o0 + 16 * OI * w + 16 * oi + 4 * g + r;
      float bv = bias ? bias[o] : 0.f;
#pragma unroll
      for (int si = 0; si < 4; ++si) {
        int s = s0 + 16 * si + c;
        if (s < S) {
          float v = acc[oi][si][r] + bv;
          if (ACT == 1) v = v * 0.5f * (1.0f + erff(v * 0.70710678118654752f));
          Y[(size_t)b * YbS + (size_t)o * S + s] = v;
        }
      }
    }
  }
}

// ---------------------------------------------------------------------------
// L2-normalize q,k head-vectors, convert to bf16 row-major [b][h][s][32].
// q additionally pre-scaled by hd^-0.5 * log2(e) so attention can use exp2.
// K rows stored permuted within 64-row blocks (QK^T acc == PV B-frag layout).
// ---------------------------------------------------------------------------
__global__ __launch_bounds__(256)
void l2ncvt_kernel(const float* __restrict__ qkv, unsigned short* __restrict__ qd,
                   unsigned short* __restrict__ kd, int S, int Sp) {
  int idx = blockIdx.x * 256 + threadIdx.x;
  int s = idx % Sp; int t = idx / Sp;
  int h = t & 7; t >>= 3;
  int qk = t & 1; int b = t >> 1;
  if (b >= 4) return;
  unsigned short* dst;
  int srow;
  if (qk == 0) { dst = qd; srow = s; }
  else {
    dst = kd;
    int blk = s >> 6, j = s & 63;
    srow = (blk << 6) + 32 * ((j >> 2) & 1) + 16 * (j >> 5) + 4 * ((j >> 3) & 3) + (j & 3);
  }
  unsigned wbuf[16];
  if (s < S) {
    const float* base = qkv + ((size_t)b * 768 + qk * 256 + h * 32) * S + s;
    float v[32]; float ss = 0.f;
#pragma unroll
    for (int d = 0; d < 32; ++d) { v[d] = base[(size_t)d * S]; ss += v[d] * v[d]; }
    float inv = 1.0f / fmaxf(sqrtf(ss), 1e-12f);
    if (qk == 0) inv *= 0.25506607138105343f;  // 32^-0.5 * log2(e)
#pragma unroll
    for (int i = 0; i < 16; ++i) wbuf[i] = cvtpk(v[2 * i] * inv, v[2 * i + 1] * inv);
  } else {
#pragma unroll
    for (int i = 0; i < 16; ++i) wbuf[i] = 0u;
  }
  uint4* o = (uint4*)(dst + ((size_t)(b * 8 + h) * Sp + srow) * 32);
#pragma unroll
  for (int i = 0; i < 4; ++i)
    o[i] = make_uint4(wbuf[4 * i], wbuf[4 * i + 1], wbuf[4 * i + 2], wbuf[4 * i + 3]);
}

// ---------------------------------------------------------------------------
// v -> bf16 d-major layout vt[b][h][32][Sp], zero-padded past S.
// ---------------------------------------------------------------------------
__global__ __launch_bounds__(256)
void vcvt_kernel(const float* __restrict__ qkv, unsigned short* __restrict__ vt,
                 int S, int Sp) {
  int idx = blockIdx.x * 256 + threadIdx.x;
  int SpH = Sp >> 1;
  int sp = idx % SpH; int t = idx / SpH;
  int d = t & 31; t >>= 5;
  int h = t & 7; int b = t >> 3;
  if (b >= 4) return;
  const float* src = qkv + ((size_t)b * 768 + 512 + h * 32 + d) * S;
  int s2 = 2 * sp;
  float a = (s2 < S) ? src[s2] : 0.f;
  float c = (s2 + 1 < S) ? src[s2 + 1] : 0.f;
  *(unsigned*)(vt + ((size_t)(b * 8 + h) * 32 + d) * Sp + s2) = cvtpk(a, c);
}

// ---------------------------------------------------------------------------
// MFMA flash attention, K-split into KS partials. No online max (logits
// bounded: q,k L2-normalized). Partials combine by pure summation.
// GRID (8=h, qblk*KS, b): lin%8==h pins each head's K/V to one XCD's L2.
// exp via raw v_exp_f32; P-pack via v_cvt_pk_bf16_f32.
// ---------------------------------------------------------------------------
template<int KS>
__global__ __launch_bounds__(256)
void attn_mfma_kernel(const unsigned short* __restrict__ qr,
                      const unsigned short* __restrict__ kr,
                      const unsigned short* __restrict__ vt,
                      float* __restrict__ opart, float* __restrict__ lpart,
                      int S, int Sp) {
  int h = blockIdx.x, b = blockIdx.z;
  int qblk = blockIdx.y / KS;
  int ks = blockIdx.y - qblk * KS;
  int w = threadIdx.x >> 6, lane = threadIdx.x & 63;
  int g = lane >> 4, c = lane & 15;
  int q0 = qblk * 64 + w * 16;
  const int chunks = Sp >> 6;
  const int c0 = (ks * chunks) / KS, c1 = ((ks + 1) * chunks) / KS;
  const unsigned short* qbh = qr + (size_t)(b * 8 + h) * Sp * 32;
  const unsigned short* kbh = kr + (size_t)(b * 8 + h) * Sp * 32;
  const unsigned short* vbh = vt + (size_t)(b * 8 + h) * 32 * Sp;

  bf16x8 qf = *(const bf16x8*)(qbh + (size_t)(q0 + c) * 32 + 8 * g);

  f32x4 oacc0 = {0.f, 0.f, 0.f, 0.f};
  f32x4 oacc1 = {0.f, 0.f, 0.f, 0.f};
  float lsum = 0.f;

  for (int ch = c0; ch < c1; ++ch) {
    int k0 = ch * 64;
    f32x4 sa[4];
#pragma unroll
    for (int t = 0; t < 4; ++t) {
      bf16x8 kf = *(const bf16x8*)(kbh + (size_t)(k0 + 16 * t + c) * 32 + 8 * g);
      f32x4 z = {0.f, 0.f, 0.f, 0.f};
      sa[t] = __builtin_amdgcn_mfma_f32_16x16x32_bf16(kf, qf, z, 0, 0, 0);
    }
    // V fragments issued early so L2 latency hides under softmax VALU.
    bf16x8 vf00 = *(const bf16x8*)(vbh + (size_t)c * Sp + k0 + 8 * g);
    bf16x8 vf01 = *(const bf16x8*)(vbh + (size_t)(16 + c) * Sp + k0 + 8 * g);
    bf16x8 vf10 = *(const bf16x8*)(vbh + (size_t)c * Sp + k0 + 32 + 8 * g);
    bf16x8 vf11 = *(const bf16x8*)(vbh + (size_t)(16 + c) * Sp + k0 + 32 + 8 * g);
    float p[4][4];
    if (k0 + 64 <= S) {
#pragma unroll
      for (int t = 0; t < 4; ++t)
#pragma unroll
        for (int r = 0; r < 4; ++r) {
          float e = __builtin_amdgcn_exp2f(sa[t][r]);  // q pre-scaled
          p[t][r] = e; lsum += e;
        }
    } else {
#pragma unroll
      for (int t = 0; t < 4; ++t)
#pragma unroll
        for (int r = 0; r < 4; ++r) {
          int key = k0 + 32 * (t & 1) + 8 * g + 4 * (t >> 1) + r;
          float e = (key < S) ? __builtin_amdgcn_exp2f(sa[t][r]) : 0.f;
          p[t][r] = e; lsum += e;
        }
    }
    union { bf16x8 v; unsigned u[4]; } pf0, pf1;
#pragma unroll
    for (int t = 0; t < 2; ++t) {
      pf0.u[2 * t]     = cvtpk(p[2 * t][0], p[2 * t][1]);
      pf0.u[2 * t + 1] = cvtpk(p[2 * t][2], p[2 * t][3]);
      pf1.u[2 * t]     = cvtpk(p[2 * t + 1][0], p[2 * t + 1][1]);
      pf1.u[2 * t + 1] = cvtpk(p[2 * t + 1][2], p[2 * t + 1][3]);
    }
    oacc0 = __builtin_amdgcn_mfma_f32_16x16x32_bf16(vf00, pf0.v, oacc0, 0, 0, 0);
    oacc1 = __builtin_amdgcn_mfma_f32_16x16x32_bf16(vf01, pf0.v, oacc1, 0, 0, 0);
    oacc0 = __builtin_amdgcn_mfma_f32_16x16x32_bf16(vf10, pf1.v, oacc0, 0, 0, 0);
    oacc1 = __builtin_amdgcn_mfma_f32_16x16x32_bf16(vf11, pf1.v, oacc1, 0, 0, 0);
  }
  lsum += __shfl_xor(lsum, 16, 64);
  lsum += __shfl_xor(lsum, 32, 64);
  int q = q0 + c;
  if (q < S) {
    size_t ob = ((size_t)(ks * 4 + b) * 256 + h * 32) * S + q;
#pragma unroll
    for (int r = 0; r < 4; ++r) {
      opart[ob + (size_t)(4 * g + r) * S]      = oacc0[r];
      opart[ob + (size_t)(16 + 4 * g + r) * S] = oacc1[r];
    }
  }
  if (lane < 16 && q < S)
    lpart[((size_t)(ks * 4 + b) * 8 + h) * S + q] = lsum;
}

// ---------------------------------------------------------------------------
// Combine K-split partials: att[b][ch][s] = sum_ks O / sum_ks lsum.
// ---------------------------------------------------------------------------
template<int KS>
__global__ __launch_bounds__(256)
void att_combine_kernel(const float* __restrict__ opart,
                        const float* __restrict__ lpart,
                        float* __restrict__ att, int S, int N) {
  int idx = blockIdx.x * 256 + threadIdx.x;
  if (idx >= N) return;
  int S4 = S >> 2;
  int sq = idx % S4; int t = idx / S4;
  int ch = t & 255; int b = t >> 8;
  int s = sq * 4;
  float4 num = {0.f, 0.f, 0.f, 0.f};
  float4 den = {0.f, 0.f, 0.f, 0.f};
#pragma unroll
  for (int ks = 0; ks < KS; ++ks) {
    float4 o4 = *(const float4*)(opart + ((size_t)(ks * 4 + b) * 256 + ch) * S + s);
    float4 l4 = *(const float4*)(lpart + ((size_t)(ks * 4 + b) * 8 + (ch >> 5)) * S + s);
    num.x += o4.x; num.y += o4.y; num.z += o4.z; num.w += o4.w;
    den.x += l4.x; den.y += l4.y; den.z += l4.z; den.w += l4.w;
  }
  float4 r;
  r.x = num.x / den.x; r.y = num.y / den.y; r.z = num.z / den.z; r.w = num.w / den.w;
  *(float4*)(att + ((size_t)b * 256 + ch) * S + s) = r;
}

// ---------------------------------------------------------------------------
__global__ __launch_bounds__(256)
void pool_kernel(const float* __restrict__ x, float* __restrict__ xg) {
  int idx = blockIdx.x * 256 + threadIdx.x;
  if (idx >= 4 * 256 * 144) return;
  int wc = idx % 12;
  int t = idx / 12;
  int hc = t % 12;
  int bc = t / 12;
  const float* p = x + ((size_t)bc * 48 + hc * 4) * 48 + wc * 4;
  float s = 0.f;
#pragma unroll
  for (int dy = 0; dy < 4; ++dy)
#pragma unroll
    for (int dx = 0; dx < 4; ++dx) s += p[dy * 48 + dx];
  xg[idx] = s * (1.0f / 16.0f);
}

__global__ __launch_bounds__(256)
void upsample_kernel(const float* __restrict__ g, float* __restrict__ cat) {
  int idx = blockIdx.x * 256 + threadIdx.x;
  if (idx >= 4 * 256 * 2304) return;
  int xo = idx % 48;
  int t = idx / 48;
  int yo = t % 48;
  int bc = t / 48;
  int b = bc >> 8, c = bc & 255;
  float sy = 0.25f * yo - 0.375f;
  float sx = 0.25f * xo - 0.375f;
  int y0 = (int)floorf(sy); float fy = sy - (float)y0;
  int x0 = (int)floorf(sx); float fx = sx - (float)x0;
  int y0c = min(11, max(0, y0)), y1c = min(11, max(0, y0 + 1));
  int x0c = min(11, max(0, x0)), x1c = min(11, max(0, x0 + 1));
  const float* gb = g + (size_t)bc * 144;
  float v00 = gb[y0c * 12 + x0c], v01 = gb[y0c * 12 + x1c];
  float v10 = gb[y1c * 12 + x0c], v11 = gb[y1c * 12 + x1c];
  float v = (1.f - fy) * ((1.f - fx) * v00 + fx * v01) + fy * ((1.f - fx) * v10 + fx * v11);
  cat[((size_t)b * 512 + 256 + c) * 2304 + yo * 48 + xo] = v;
}

// ---------------------------------------------------------------------------
extern "C" void kernel_launch(void* const* d_in, const int* in_sizes, int n_in,
                              void* d_out, int out_size, void* d_ws, size_t ws_size,
                              hipStream_t stream) {
  const float* x        = (const float*)d_in[0];
  const float* w_qkv_l  = (const float*)d_in[1];
  const float* w_proj_l = (const float*)d_in[2];
  const float* b_proj_l = (const float*)d_in[3];
  const float* w_qkv_g  = (const float*)d_in[4];
  const float* w_proj_g = (const float*)d_in[5];
  const float* b_proj_g = (const float*)d_in[6];
  const float* w_f1     = (const float*)d_in[7];
  const float* b_f1     = (const float*)d_in[8];
  const float* w_f2     = (const float*)d_in[9];
  const float* b_f2     = (const float*)d_in[10];
  float* out = (float*)d_out;

  const int S = 2304, Sg = 144, B = 4;
  const int Sp = 2304, Sgp = 192;
  const int KS = 3;

  char* wsp = (char*)d_ws;
  size_t off = 0;
  auto alloc = [&](size_t bytes) { char* p = wsp + off; off = (off + bytes + 255) & ~(size_t)255; return p; };
  float* qkv_l = (float*)alloc((size_t)B * 768 * S * 4);   // reused as opart_l
  float* att_l = (float*)alloc((size_t)B * 256 * S * 4);
  float* cat   = (float*)alloc((size_t)B * 512 * S * 4);
  float* hbuf  = (float*)alloc((size_t)B * 256 * S * 4);
  float* xg    = (float*)alloc((size_t)B * 256 * Sg * 4);
  float* qkv_g = (float*)alloc((size_t)B * 768 * Sg * 4);  // reused as opart_g
  float* att_g = (float*)alloc((size_t)B * 256 * Sg * 4);
  float* gsm   = (float*)alloc((size_t)B * 256 * Sg * 4);
  unsigned short* qr_l = (unsigned short*)alloc((size_t)B * 8 * Sp * 32 * 2);
  unsigned short* kr_l = (unsigned short*)alloc((size_t)B * 8 * Sp * 32 * 2);
  unsigned short* vt_l = (unsigned short*)alloc((size_t)B * 8 * Sp * 32 * 2);
  unsigned short* qr_g = (unsigned short*)alloc((size_t)B * 8 * Sgp * 32 * 2);
  unsigned short* kr_g = (unsigned short*)alloc((size_t)B * 8 * Sgp * 32 * 2);
  unsigned short* vt_g = (unsigned short*)alloc((size_t)B * 8 * Sgp * 32 * 2);
  unsigned short* whl_qkv_l  = (unsigned short*)alloc((size_t)768 * 256 * 2 * 2);
  unsigned short* whl_proj_l = (unsigned short*)alloc((size_t)256 * 256 * 2 * 2);
  unsigned short* whl_qkv_g  = (unsigned short*)alloc((size_t)768 * 256 * 2 * 2);
  unsigned short* whl_proj_g = (unsigned short*)alloc((size_t)256 * 256 * 2 * 2);
  unsigned short* whl_f1     = (unsigned short*)alloc((size_t)256 * 512 * 2 * 2);
  unsigned short* whl_f2     = (unsigned short*)alloc((size_t)256 * 256 * 2 * 2);
  float* lpart_l = (float*)alloc((size_t)KS * B * 8 * S * 4);
  float* lpart_g = (float*)alloc((size_t)KS * B * 8 * Sg * 4);
  float* opart_l = qkv_l;  // qkv_l dead after l2ncvt/vcvt consume it
  float* opart_g = qkv_g;

  dim3 blk(256);

  wsplit_kernel<<<dim3(88), blk, 0, stream>>>(
      w_qkv_l, w_proj_l, w_qkv_g, w_proj_g, w_f1, w_f2,
      whl_qkv_l, whl_proj_l, whl_qkv_g, whl_proj_g, whl_f1, whl_f2);

  // ----- local branch -----
  conv_mfma_kernel<0, 128><<<dim3(36, 6, B), blk, 0, stream>>>(
      whl_qkv_l, x, nullptr, qkv_l, 256, S, (size_t)768 * S);
  l2ncvt_kernel<<<dim3((B * 2 * 8 * Sp) / 256), blk, 0, stream>>>(qkv_l, qr_l, kr_l, S, Sp);
  vcvt_kernel<<<dim3((B * 8 * 32 * (Sp / 2)) / 256), blk, 0, stream>>>(qkv_l, vt_l, S, Sp);
  attn_mfma_kernel<KS><<<dim3(8, (Sp / 64) * KS, B), blk, 0, stream>>>(
      qr_l, kr_l, vt_l, opart_l, lpart_l, S, Sp);
  att_combine_kernel<KS><<<dim3((B * 256 * (S / 4) + 255) / 256), blk, 0, stream>>>(
      opart_l, lpart_l, att_l, S, B * 256 * (S / 4));
  conv_mfma_kernel<0, 64><<<dim3(36, 4, B), blk, 0, stream>>>(
      whl_proj_l, att_l, b_proj_l, cat, 256, S, (size_t)512 * S);

  // ----- global branch -----
  pool_kernel<<<dim3(576), blk, 0, stream>>>(x, xg);
  conv_mfma_kernel<0, 64><<<dim3(3, 12, B), blk, 0, stream>>>(
      whl_qkv_g, xg, nullptr, qkv_g, 256, Sg, (size_t)768 * Sg);
  l2ncvt_kernel<<<dim3((B * 2 * 8 * Sgp) / 256), blk, 0, stream>>>(qkv_g, qr_g, kr_g, Sg, Sgp);
  vcvt_kernel<<<dim3((B * 8 * 32 * (Sgp / 2)) / 256), blk, 0, stream>>>(qkv_g, vt_g, Sg, Sgp);
  attn_mfma_kernel<KS><<<dim3(8, (Sgp / 64) * KS, B), blk, 0, stream>>>(
      qr_g, kr_g, vt_g, opart_g, lpart_g, Sg, Sgp);
  att_combine_kernel<KS><<<dim3((B * 256 * (Sg / 4) + 255) / 256), blk, 0, stream>>>(
      opart_g, lpart_g, att_g, Sg, B * 256 * (Sg / 4));
  conv_mfma_kernel<0, 64><<<dim3(3, 4, B), blk, 0, stream>>>(
      whl_proj_g, att_g, b_proj_g, gsm, 256, Sg, (size_t)256 * Sg);
  upsample_kernel<<<dim3(9216), blk, 0, stream>>>(gsm, cat);

  // ----- fuse: f1 (GELU) then f2 -----
  conv_mfma_kernel<1, 64><<<dim3(36, 4, B), blk, 0, stream>>>(
      whl_f1, cat, b_f1, hbuf, 512, S, (size_t)256 * S);
  conv_mfma_kernel<0, 64><<<dim3(36, 4, B), blk, 0, stream>>>(
      whl_f2, hbuf, b_f2, out, 256, S, (size_t)256 * S);
}

// Round 8
// 204.219 us; speedup vs baseline: 8.2557x; 1.2687x over previous
//
#include <hip/hip_runtime.h>
#include <hip/hip_bf16.h>
#include <math.h>

typedef __attribute__((ext_vector_type(8))) short bf16x8;
typedef __attribute__((ext_vector_type(4))) float f32x4;

__device__ inline unsigned short f2bf(float x) {
  __hip_bfloat16 h = __float2bfloat16(x);
  return __builtin_bit_cast(unsigned short, h);
}
__device__ inline float bf2f(unsigned short u) {
  unsigned v = ((unsigned)u) << 16;
  return __builtin_bit_cast(float, v);
}
// One-instruction RNE pack of two f32 -> packed bf16x2 (low = a, high = b).
__device__ inline unsigned cvtpk(float a, float b) {
  unsigned r;
  asm("v_cvt_pk_bf16_f32 %0, %1, %2" : "=v"(r) : "v"(a), "v"(b));
  return r;
}
__device__ inline float bf2f_lo(unsigned p) {
  return __builtin_bit_cast(float, p << 16);
}
__device__ inline float bf2f_hi(unsigned p) {
  return __builtin_bit_cast(float, p & 0xffff0000u);
}

// ---------------------------------------------------------------------------
// Weight split: W[O][Cin] f32 -> Whl rows of 128B: [o][kb][32 hi bf16 | 32 lo].
// ---------------------------------------------------------------------------
__global__ __launch_bounds__(256)
void wsplit_kernel(const float* __restrict__ w0, const float* __restrict__ w1,
                   const float* __restrict__ w2, const float* __restrict__ w3,
                   const float* __restrict__ w4, const float* __restrict__ w5,
                   unsigned short* __restrict__ d0, unsigned short* __restrict__ d1,
                   unsigned short* __restrict__ d2, unsigned short* __restrict__ d3,
                   unsigned short* __restrict__ d4, unsigned short* __restrict__ d5) {
  int r = blockIdx.x * 256 + threadIdx.x;
  const float* src; unsigned short* dst;
  if (r < 6144) { src = w0; dst = d0; }
  else if (r < 8192) { src = w1; dst = d1; r -= 6144; }
  else if (r < 14336) { src = w2; dst = d2; r -= 8192; }
  else if (r < 16384) { src = w3; dst = d3; r -= 14336; }
  else if (r < 20480) { src = w4; dst = d4; r -= 16384; }
  else if (r < 22528) { src = w5; dst = d5; r -= 20480; }
  else return;
  const float* in = src + (size_t)r * 32;
  union { unsigned short u[32]; uint4 q[4]; } H, L;
#pragma unroll
  for (int i = 0; i < 32; ++i) {
    float x = in[i];
    unsigned short h = f2bf(x);
    H.u[i] = h;
    L.u[i] = f2bf(x - bf2f(h));
  }
  uint4* op = (uint4*)(dst + (size_t)r * 64);
#pragma unroll
  for (int q = 0; q < 4; ++q) { op[q] = H.q[q]; op[4 + q] = L.q[q]; }
}

// ---------------------------------------------------------------------------
// conv1x1 as split-precision MFMA GEMM. Tile OT(o) x 64(s), K-step 32.
// ---------------------------------------------------------------------------
template<int ACT, int OT>
__global__ __launch_bounds__(256)
void conv_mfma_kernel(const unsigned short* __restrict__ Whl,
                      const float* __restrict__ X,
                      const float* __restrict__ bias,
                      float* __restrict__ Y,
                      int Cin, int S, size_t YbS) {
  constexpr int OI = OT / 64;  // o-frags per wave
  __shared__ __align__(16) unsigned short Bs[64 * 64];  // 8 KB
  const int tid = threadIdx.x;
  const int w = tid >> 6, lane = tid & 63;
  const int g = lane >> 4, c = lane & 15;
  const int s0 = blockIdx.x * 64;
  const int o0 = blockIdx.y * OT;
  const int b = blockIdx.z;
  const int KB = Cin >> 5;
  const float* Xb = X + (size_t)b * Cin * S;
  const int sRow = tid & 63;
  const int jS = tid >> 6;
  const int ss = s0 + sRow;
  const bool sIn = (ss < S);
  unsigned short* BsRow = Bs + sRow * 64;
  const int hiOff = (jS ^ (sRow & 7)) * 8;
  const int loOff = ((4 + jS) ^ (sRow & 7)) * 8;

  f32x4 acc[OI][4];
#pragma unroll
  for (int oi = 0; oi < OI; ++oi)
#pragma unroll
    for (int si = 0; si < 4; ++si) acc[oi][si] = (f32x4){0.f, 0.f, 0.f, 0.f};

  for (int kb = 0; kb < KB; ++kb) {
    union { unsigned u[4]; bf16x8 v; } hu, lu;
    if (sIn) {
      const float* xp = Xb + (size_t)(kb * 32 + 8 * jS) * S + ss;
#pragma unroll
      for (int i = 0; i < 4; ++i) {
        float x0 = xp[(size_t)(2 * i) * S];
        float x1 = xp[(size_t)(2 * i + 1) * S];
        unsigned hp = cvtpk(x0, x1);
        unsigned lp = cvtpk(x0 - bf2f_lo(hp), x1 - bf2f_hi(hp));
        hu.u[i] = hp; lu.u[i] = lp;
      }
    } else {
#pragma unroll
      for (int i = 0; i < 4; ++i) { hu.u[i] = 0; lu.u[i] = 0; }
    }
    bf16x8 ahi[OI], alo[OI];
#pragma unroll
    for (int oi = 0; oi < OI; ++oi) {
      const unsigned short* ap =
          Whl + ((size_t)(o0 + 16 * OI * w + 16 * oi + c) * KB + kb) * 64;
      ahi[oi] = *(const bf16x8*)(ap + 8 * g);
      alo[oi] = *(const bf16x8*)(ap + 32 + 8 * g);
    }
    __syncthreads();
    *(bf16x8*)(BsRow + hiOff) = hu.v;
    *(bf16x8*)(BsRow + loOff) = lu.v;
    __syncthreads();
    bf16x8 bhi[4], blo[4];
#pragma unroll
    for (int si = 0; si < 4; ++si) {
      int row = 16 * si + c;
      const unsigned short* bp = Bs + row * 64;
      bhi[si] = *(const bf16x8*)(bp + (g ^ (row & 7)) * 8);
      blo[si] = *(const bf16x8*)(bp + (((4 + g) ^ (row & 7))) * 8);
    }
#pragma unroll
    for (int oi = 0; oi < OI; ++oi)
#pragma unroll
      for (int si = 0; si < 4; ++si) {
        acc[oi][si] = __builtin_amdgcn_mfma_f32_16x16x32_bf16(ahi[oi], bhi[si], acc[oi][si], 0, 0, 0);
        acc[oi][si] = __builtin_amdgcn_mfma_f32_16x16x32_bf16(ahi[oi], blo[si], acc[oi][si], 0, 0, 0);
        acc[oi][si] = __builtin_amdgcn_mfma_f32_16x16x32_bf16(alo[oi], bhi[si], acc[oi][si], 0, 0, 0);
      }
  }
#pragma unroll
  for (int oi = 0; oi < OI; ++oi) {
#pragma unroll
    for (int r = 0; r < 4; ++r) {
      int o = o0 + 16 * OI * w + 16 * oi + 4 * g + r;
      float bv = bias ? bias[o] : 0.f;
#pragma unroll
      for (int si = 0; si < 4; ++si) {
        int s = s0 + 16 * si + c;
        if (s < S) {
          float v = acc[oi][si][r] + bv;
          if (ACT == 1) v = v * 0.5f * (1.0f + erff(v * 0.70710678118654752f));
          Y[(size_t)b * YbS + (size_t)o * S + s] = v;
        }
      }
    }
  }
}

// ---------------------------------------------------------------------------
// L2-normalize q,k head-vectors, convert to bf16 row-major [b][h][s][32].
// q additionally pre-scaled by hd^-0.5 * log2(e) so attention can use exp2.
// K rows stored permuted within 64-row blocks (QK^T acc == PV B-frag layout).
// ---------------------------------------------------------------------------
__global__ __launch_bounds__(256)
void l2ncvt_kernel(const float* __restrict__ qkv, unsigned short* __restrict__ qd,
                   unsigned short* __restrict__ kd, int S, int Sp) {
  int idx = blockIdx.x * 256 + threadIdx.x;
  int s = idx % Sp; int t = idx / Sp;
  int h = t & 7; t >>= 3;
  int qk = t & 1; int b = t >> 1;
  if (b >= 4) return;
  unsigned short* dst;
  int srow;
  if (qk == 0) { dst = qd; srow = s; }
  else {
    dst = kd;
    int blk = s >> 6, j = s & 63;
    srow = (blk << 6) + 32 * ((j >> 2) & 1) + 16 * (j >> 5) + 4 * ((j >> 3) & 3) + (j & 3);
  }
  unsigned wbuf[16];
  if (s < S) {
    const float* base = qkv + ((size_t)b * 768 + qk * 256 + h * 32) * S + s;
    float v[32]; float ss = 0.f;
#pragma unroll
    for (int d = 0; d < 32; ++d) { v[d] = base[(size_t)d * S]; ss += v[d] * v[d]; }
    float inv = 1.0f / fmaxf(sqrtf(ss), 1e-12f);
    if (qk == 0) inv *= 0.25506607138105343f;  // 32^-0.5 * log2(e)
#pragma unroll
    for (int i = 0; i < 16; ++i) wbuf[i] = cvtpk(v[2 * i] * inv, v[2 * i + 1] * inv);
  } else {
#pragma unroll
    for (int i = 0; i < 16; ++i) wbuf[i] = 0u;
  }
  uint4* o = (uint4*)(dst + ((size_t)(b * 8 + h) * Sp + srow) * 32);
#pragma unroll
  for (int i = 0; i < 4; ++i)
    o[i] = make_uint4(wbuf[4 * i], wbuf[4 * i + 1], wbuf[4 * i + 2], wbuf[4 * i + 3]);
}

// ---------------------------------------------------------------------------
// v -> bf16 d-major layout vt[b][h][32][Sp], zero-padded past S.
// ---------------------------------------------------------------------------
__global__ __launch_bounds__(256)
void vcvt_kernel(const float* __restrict__ qkv, unsigned short* __restrict__ vt,
                 int S, int Sp) {
  int idx = blockIdx.x * 256 + threadIdx.x;
  int SpH = Sp >> 1;
  int sp = idx % SpH; int t = idx / SpH;
  int d = t & 31; t >>= 5;
  int h = t & 7; int b = t >> 3;
  if (b >= 4) return;
  const float* src = qkv + ((size_t)b * 768 + 512 + h * 32 + d) * S;
  int s2 = 2 * sp;
  float a = (s2 < S) ? src[s2] : 0.f;
  float c = (s2 + 1 < S) ? src[s2 + 1] : 0.f;
  *(unsigned*)(vt + ((size_t)(b * 8 + h) * 32 + d) * Sp + s2) = cvtpk(a, c);
}

// ---------------------------------------------------------------------------
// MFMA flash attention, K-split into KS partials. No online max (logits
// bounded: q,k L2-normalized). 32 q-rows per wave (two Q frags share each
// K/V fragment load -> 16 MFMA per 8 loads), K prefetched one chunk ahead.
// GRID (8=h, qblk*KS, b): lin%8==h pins each head's K/V to one XCD's L2.
// ---------------------------------------------------------------------------
template<int KS>
__global__ __launch_bounds__(256)
void attn_mfma_kernel(const unsigned short* __restrict__ qr,
                      const unsigned short* __restrict__ kr,
                      const unsigned short* __restrict__ vt,
                      float* __restrict__ opart, float* __restrict__ lpart,
                      int S, int Sp) {
  int h = blockIdx.x, b = blockIdx.z;
  int qblk = blockIdx.y / KS;
  int ks = blockIdx.y - qblk * KS;
  int w = threadIdx.x >> 6, lane = threadIdx.x & 63;
  int g = lane >> 4, c = lane & 15;
  int q0 = qblk * 128 + w * 32;
  const int chunks = Sp >> 6;
  const int c0 = (ks * chunks) / KS, c1 = ((ks + 1) * chunks) / KS;
  const unsigned short* qbh = qr + (size_t)(b * 8 + h) * Sp * 32;
  const unsigned short* kbh = kr + (size_t)(b * 8 + h) * Sp * 32;
  const unsigned short* vbh = vt + (size_t)(b * 8 + h) * 32 * Sp;

  bf16x8 qfA = *(const bf16x8*)(qbh + (size_t)(q0 + c) * 32 + 8 * g);
  bf16x8 qfB = *(const bf16x8*)(qbh + (size_t)(q0 + 16 + c) * 32 + 8 * g);

  f32x4 oA0 = {0.f,0.f,0.f,0.f}, oA1 = {0.f,0.f,0.f,0.f};
  f32x4 oB0 = {0.f,0.f,0.f,0.f}, oB1 = {0.f,0.f,0.f,0.f};
  float lsA = 0.f, lsB = 0.f;

  bf16x8 kf[4];
  {
    int k0 = c0 * 64;
#pragma unroll
    for (int t = 0; t < 4; ++t)
      kf[t] = *(const bf16x8*)(kbh + (size_t)(k0 + 16 * t + c) * 32 + 8 * g);
  }

  for (int ch = c0; ch < c1; ++ch) {
    int k0 = ch * 64;
    const f32x4 z = {0.f, 0.f, 0.f, 0.f};
    f32x4 saA[4], saB[4];
#pragma unroll
    for (int t = 0; t < 4; ++t) {
      saA[t] = __builtin_amdgcn_mfma_f32_16x16x32_bf16(kf[t], qfA, z, 0, 0, 0);
      saB[t] = __builtin_amdgcn_mfma_f32_16x16x32_bf16(kf[t], qfB, z, 0, 0, 0);
    }
    // V fragments for this chunk (latency hidden under softmax below)
    bf16x8 vf00 = *(const bf16x8*)(vbh + (size_t)c * Sp + k0 + 8 * g);
    bf16x8 vf01 = *(const bf16x8*)(vbh + (size_t)(16 + c) * Sp + k0 + 8 * g);
    bf16x8 vf10 = *(const bf16x8*)(vbh + (size_t)c * Sp + k0 + 32 + 8 * g);
    bf16x8 vf11 = *(const bf16x8*)(vbh + (size_t)(16 + c) * Sp + k0 + 32 + 8 * g);
    // K prefetch for next chunk
    if (ch + 1 < c1) {
      int kn = (ch + 1) * 64;
#pragma unroll
      for (int t = 0; t < 4; ++t)
        kf[t] = *(const bf16x8*)(kbh + (size_t)(kn + 16 * t + c) * 32 + 8 * g);
    }
    float pA[4][4], pB[4][4];
    if (k0 + 64 <= S) {
#pragma unroll
      for (int t = 0; t < 4; ++t)
#pragma unroll
        for (int r = 0; r < 4; ++r) {
          float eA = __builtin_amdgcn_exp2f(saA[t][r]);
          float eB = __builtin_amdgcn_exp2f(saB[t][r]);
          pA[t][r] = eA; lsA += eA;
          pB[t][r] = eB; lsB += eB;
        }
    } else {
#pragma unroll
      for (int t = 0; t < 4; ++t)
#pragma unroll
        for (int r = 0; r < 4; ++r) {
          int key = k0 + 32 * (t & 1) + 8 * g + 4 * (t >> 1) + r;
          bool in = (key < S);
          float eA = in ? __builtin_amdgcn_exp2f(saA[t][r]) : 0.f;
          float eB = in ? __builtin_amdgcn_exp2f(saB[t][r]) : 0.f;
          pA[t][r] = eA; lsA += eA;
          pB[t][r] = eB; lsB += eB;
        }
    }
    union { bf16x8 v; unsigned u[4]; } pfA0, pfA1, pfB0, pfB1;
#pragma unroll
    for (int t = 0; t < 2; ++t) {
      pfA0.u[2 * t]     = cvtpk(pA[2 * t][0], pA[2 * t][1]);
      pfA0.u[2 * t + 1] = cvtpk(pA[2 * t][2], pA[2 * t][3]);
      pfA1.u[2 * t]     = cvtpk(pA[2 * t + 1][0], pA[2 * t + 1][1]);
      pfA1.u[2 * t + 1] = cvtpk(pA[2 * t + 1][2], pA[2 * t + 1][3]);
      pfB0.u[2 * t]     = cvtpk(pB[2 * t][0], pB[2 * t][1]);
      pfB0.u[2 * t + 1] = cvtpk(pB[2 * t][2], pB[2 * t][3]);
      pfB1.u[2 * t]     = cvtpk(pB[2 * t + 1][0], pB[2 * t + 1][1]);
      pfB1.u[2 * t + 1] = cvtpk(pB[2 * t + 1][2], pB[2 * t + 1][3]);
    }
    oA0 = __builtin_amdgcn_mfma_f32_16x16x32_bf16(vf00, pfA0.v, oA0, 0, 0, 0);
    oA1 = __builtin_amdgcn_mfma_f32_16x16x32_bf16(vf01, pfA0.v, oA1, 0, 0, 0);
    oB0 = __builtin_amdgcn_mfma_f32_16x16x32_bf16(vf00, pfB0.v, oB0, 0, 0, 0);
    oB1 = __builtin_amdgcn_mfma_f32_16x16x32_bf16(vf01, pfB0.v, oB1, 0, 0, 0);
    oA0 = __builtin_amdgcn_mfma_f32_16x16x32_bf16(vf10, pfA1.v, oA0, 0, 0, 0);
    oA1 = __builtin_amdgcn_mfma_f32_16x16x32_bf16(vf11, pfA1.v, oA1, 0, 0, 0);
    oB0 = __builtin_amdgcn_mfma_f32_16x16x32_bf16(vf10, pfB1.v, oB0, 0, 0, 0);
    oB1 = __builtin_amdgcn_mfma_f32_16x16x32_bf16(vf11, pfB1.v, oB1, 0, 0, 0);
  }
  lsA += __shfl_xor(lsA, 16, 64);
  lsA += __shfl_xor(lsA, 32, 64);
  lsB += __shfl_xor(lsB, 16, 64);
  lsB += __shfl_xor(lsB, 32, 64);
  int qA = q0 + c, qB = q0 + 16 + c;
  size_t obase = ((size_t)(ks * 4 + b) * 256 + h * 32) * S;
  if (qA < S) {
#pragma unroll
    for (int r = 0; r < 4; ++r) {
      opart[obase + (size_t)(4 * g + r) * S + qA]      = oA0[r];
      opart[obase + (size_t)(16 + 4 * g + r) * S + qA] = oA1[r];
    }
  }
  if (qB < S) {
#pragma unroll
    for (int r = 0; r < 4; ++r) {
      opart[obase + (size_t)(4 * g + r) * S + qB]      = oB0[r];
      opart[obase + (size_t)(16 + 4 * g + r) * S + qB] = oB1[r];
    }
  }
  if (lane < 16) {
    size_t lb = ((size_t)(ks * 4 + b) * 8 + h) * S;
    if (q0 + lane < S)      lpart[lb + q0 + lane] = lsA;
    if (q0 + 16 + lane < S) lpart[lb + q0 + 16 + lane] = lsB;
  }
}

// ---------------------------------------------------------------------------
// Combine K-split partials: att[b][ch][s] = sum_ks O / sum_ks lsum.
// ---------------------------------------------------------------------------
template<int KS>
__global__ __launch_bounds__(256)
void att_combine_kernel(const float* __restrict__ opart,
                        const float* __restrict__ lpart,
                        float* __restrict__ att, int S, int N) {
  int idx = blockIdx.x * 256 + threadIdx.x;
  if (idx >= N) return;
  int S4 = S >> 2;
  int sq = idx % S4; int t = idx / S4;
  int ch = t & 255; int b = t >> 8;
  int s = sq * 4;
  float4 num = {0.f, 0.f, 0.f, 0.f};
  float4 den = {0.f, 0.f, 0.f, 0.f};
#pragma unroll
  for (int ks = 0; ks < KS; ++ks) {
    float4 o4 = *(const float4*)(opart + ((size_t)(ks * 4 + b) * 256 + ch) * S + s);
    float4 l4 = *(const float4*)(lpart + ((size_t)(ks * 4 + b) * 8 + (ch >> 5)) * S + s);
    num.x += o4.x; num.y += o4.y; num.z += o4.z; num.w += o4.w;
    den.x += l4.x; den.y += l4.y; den.z += l4.z; den.w += l4.w;
  }
  float4 r;
  r.x = num.x / den.x; r.y = num.y / den.y; r.z = num.z / den.z; r.w = num.w / den.w;
  *(float4*)(att + ((size_t)b * 256 + ch) * S + s) = r;
}

// ---------------------------------------------------------------------------
__global__ __launch_bounds__(256)
void pool_kernel(const float* __restrict__ x, float* __restrict__ xg) {
  int idx = blockIdx.x * 256 + threadIdx.x;
  if (idx >= 4 * 256 * 144) return;
  int wc = idx % 12;
  int t = idx / 12;
  int hc = t % 12;
  int bc = t / 12;
  const float* p = x + ((size_t)bc * 48 + hc * 4) * 48 + wc * 4;
  float s = 0.f;
#pragma unroll
  for (int dy = 0; dy < 4; ++dy)
#pragma unroll
    for (int dx = 0; dx < 4; ++dx) s += p[dy * 48 + dx];
  xg[idx] = s * (1.0f / 16.0f);
}

__global__ __launch_bounds__(256)
void upsample_kernel(const float* __restrict__ g, float* __restrict__ cat) {
  int idx = blockIdx.x * 256 + threadIdx.x;
  if (idx >= 4 * 256 * 2304) return;
  int xo = idx % 48;
  int t = idx / 48;
  int yo = t % 48;
  int bc = t / 48;
  int b = bc >> 8, c = bc & 255;
  float sy = 0.25f * yo - 0.375f;
  float sx = 0.25f * xo - 0.375f;
  int y0 = (int)floorf(sy); float fy = sy - (float)y0;
  int x0 = (int)floorf(sx); float fx = sx - (float)x0;
  int y0c = min(11, max(0, y0)), y1c = min(11, max(0, y0 + 1));
  int x0c = min(11, max(0, x0)), x1c = min(11, max(0, x0 + 1));
  const float* gb = g + (size_t)bc * 144;
  float v00 = gb[y0c * 12 + x0c], v01 = gb[y0c * 12 + x1c];
  float v10 = gb[y1c * 12 + x0c], v11 = gb[y1c * 12 + x1c];
  float v = (1.f - fy) * ((1.f - fx) * v00 + fx * v01) + fy * ((1.f - fx) * v10 + fx * v11);
  cat[((size_t)b * 512 + 256 + c) * 2304 + yo * 48 + xo] = v;
}

// ---------------------------------------------------------------------------
extern "C" void kernel_launch(void* const* d_in, const int* in_sizes, int n_in,
                              void* d_out, int out_size, void* d_ws, size_t ws_size,
                              hipStream_t stream) {
  const float* x        = (const float*)d_in[0];
  const float* w_qkv_l  = (const float*)d_in[1];
  const float* w_proj_l = (const float*)d_in[2];
  const float* b_proj_l = (const float*)d_in[3];
  const float* w_qkv_g  = (const float*)d_in[4];
  const float* w_proj_g = (const float*)d_in[5];
  const float* b_proj_g = (const float*)d_in[6];
  const float* w_f1     = (const float*)d_in[7];
  const float* b_f1     = (const float*)d_in[8];
  const float* w_f2     = (const float*)d_in[9];
  const float* b_f2     = (const float*)d_in[10];
  float* out = (float*)d_out;

  const int S = 2304, Sg = 144, B = 4;
  const int Sp = 2304, Sgp = 256;  // padded row counts (multiple of 128)
  const int KS = 3;

  char* wsp = (char*)d_ws;
  size_t off = 0;
  auto alloc = [&](size_t bytes) { char* p = wsp + off; off = (off + bytes + 255) & ~(size_t)255; return p; };
  float* qkv_l = (float*)alloc((size_t)B * 768 * S * 4);   // reused as opart_l
  float* att_l = (float*)alloc((size_t)B * 256 * S * 4);
  float* cat   = (float*)alloc((size_t)B * 512 * S * 4);
  float* hbuf  = (float*)alloc((size_t)B * 256 * S * 4);
  float* xg    = (float*)alloc((size_t)B * 256 * Sg * 4);
  float* qkv_g = (float*)alloc((size_t)B * 768 * Sg * 4);  // reused as opart_g
  float* att_g = (float*)alloc((size_t)B * 256 * Sg * 4);
  float* gsm   = (float*)alloc((size_t)B * 256 * Sg * 4);
  unsigned short* qr_l = (unsigned short*)alloc((size_t)B * 8 * Sp * 32 * 2);
  unsigned short* kr_l = (unsigned short*)alloc((size_t)B * 8 * Sp * 32 * 2);
  unsigned short* vt_l = (unsigned short*)alloc((size_t)B * 8 * Sp * 32 * 2);
  unsigned short* qr_g = (unsigned short*)alloc((size_t)B * 8 * Sgp * 32 * 2);
  unsigned short* kr_g = (unsigned short*)alloc((size_t)B * 8 * Sgp * 32 * 2);
  unsigned short* vt_g = (unsigned short*)alloc((size_t)B * 8 * Sgp * 32 * 2);
  unsigned short* whl_qkv_l  = (unsigned short*)alloc((size_t)768 * 256 * 2 * 2);
  unsigned short* whl_proj_l = (unsigned short*)alloc((size_t)256 * 256 * 2 * 2);
  unsigned short* whl_qkv_g  = (unsigned short*)alloc((size_t)768 * 256 * 2 * 2);
  unsigned short* whl_proj_g = (unsigned short*)alloc((size_t)256 * 256 * 2 * 2);
  unsigned short* whl_f1     = (unsigned short*)alloc((size_t)256 * 512 * 2 * 2);
  unsigned short* whl_f2     = (unsigned short*)alloc((size_t)256 * 256 * 2 * 2);
  float* lpart_l = (float*)alloc((size_t)KS * B * 8 * S * 4);
  float* lpart_g = (float*)alloc((size_t)KS * B * 8 * Sg * 4);
  float* opart_l = qkv_l;  // qkv_l dead after l2ncvt/vcvt consume it
  float* opart_g = qkv_g;

  dim3 blk(256);

  wsplit_kernel<<<dim3(88), blk, 0, stream>>>(
      w_qkv_l, w_proj_l, w_qkv_g, w_proj_g, w_f1, w_f2,
      whl_qkv_l, whl_proj_l, whl_qkv_g, whl_proj_g, whl_f1, whl_f2);

  // ----- local branch -----
  conv_mfma_kernel<0, 128><<<dim3(36, 6, B), blk, 0, stream>>>(
      whl_qkv_l, x, nullptr, qkv_l, 256, S, (size_t)768 * S);
  l2ncvt_kernel<<<dim3((B * 2 * 8 * Sp) / 256), blk, 0, stream>>>(qkv_l, qr_l, kr_l, S, Sp);
  vcvt_kernel<<<dim3((B * 8 * 32 * (Sp / 2)) / 256), blk, 0, stream>>>(qkv_l, vt_l, S, Sp);
  attn_mfma_kernel<KS><<<dim3(8, (Sp / 128) * KS, B), blk, 0, stream>>>(
      qr_l, kr_l, vt_l, opart_l, lpart_l, S, Sp);
  att_combine_kernel<KS><<<dim3((B * 256 * (S / 4) + 255) / 256), blk, 0, stream>>>(
      opart_l, lpart_l, att_l, S, B * 256 * (S / 4));
  conv_mfma_kernel<0, 64><<<dim3(36, 4, B), blk, 0, stream>>>(
      whl_proj_l, att_l, b_proj_l, cat, 256, S, (size_t)512 * S);

  // ----- global branch -----
  pool_kernel<<<dim3(576), blk, 0, stream>>>(x, xg);
  conv_mfma_kernel<0, 64><<<dim3(3, 12, B), blk, 0, stream>>>(
      whl_qkv_g, xg, nullptr, qkv_g, 256, Sg, (size_t)768 * Sg);
  l2ncvt_kernel<<<dim3((B * 2 * 8 * Sgp) / 256), blk, 0, stream>>>(qkv_g, qr_g, kr_g, Sg, Sgp);
  vcvt_kernel<<<dim3((B * 8 * 32 * (Sgp / 2)) / 256), blk, 0, stream>>>(qkv_g, vt_g, Sg, Sgp);
  attn_mfma_kernel<KS><<<dim3(8, (Sgp / 128) * KS, B), blk, 0, stream>>>(
      qr_g, kr_g, vt_g, opart_g, lpart_g, Sg, Sgp);
  att_combine_kernel<KS><<<dim3((B * 256 * (Sg / 4) + 255) / 256), blk, 0, stream>>>(
      opart_g, lpart_g, att_g, Sg, B * 256 * (Sg / 4));
  conv_mfma_kernel<0, 64><<<dim3(3, 4, B), blk, 0, stream>>>(
      whl_proj_g, att_g, b_proj_g, gsm, 256, Sg, (size_t)256 * Sg);
  upsample_kernel<<<dim3(9216), blk, 0, stream>>>(gsm, cat);

  // ----- fuse: f1 (GELU) then f2 -----
  conv_mfma_kernel<1, 64><<<dim3(36, 4, B), blk, 0, stream>>>(
      whl_f1, cat, b_f1, hbuf, 512, S, (size_t)256 * S);
  conv_mfma_kernel<0, 64><<<dim3(36, 4, B), blk, 0, stream>>>(
      whl_f2, hbuf, b_f2, out, 256, S, (size_t)256 * S);
}

// Round 9
// 188.545 us; speedup vs baseline: 8.9420x; 1.0831x over previous
//
#include <hip/hip_runtime.h>
#include <hip/hip_bf16.h>
#include <math.h>

typedef __attribute__((ext_vector_type(8))) short bf16x8;
typedef __attribute__((ext_vector_type(4))) float f32x4;

__device__ inline unsigned short f2bf(float x) {
  __hip_bfloat16 h = __float2bfloat16(x);
  return __builtin_bit_cast(unsigned short, h);
}
__device__ inline float bf2f(unsigned short u) {
  unsigned v = ((unsigned)u) << 16;
  return __builtin_bit_cast(float, v);
}
// One-instruction RNE pack of two f32 -> packed bf16x2 (low = a, high = b).
__device__ inline unsigned cvtpk(float a, float b) {
  unsigned r;
  asm("v_cvt_pk_bf16_f32 %0, %1, %2" : "=v"(r) : "v"(a), "v"(b));
  return r;
}
__device__ inline float bf2f_lo(unsigned p) {
  return __builtin_bit_cast(float, p << 16);
}
__device__ inline float bf2f_hi(unsigned p) {
  return __builtin_bit_cast(float, p & 0xffff0000u);
}

// ---------------------------------------------------------------------------
// Weight split: W[O][Cin] f32 -> Whl rows of 128B: [o][kb][32 hi bf16 | 32 lo].
// ---------------------------------------------------------------------------
__global__ __launch_bounds__(256)
void wsplit_kernel(const float* __restrict__ w0, const float* __restrict__ w1,
                   const float* __restrict__ w2, const float* __restrict__ w3,
                   const float* __restrict__ w4, const float* __restrict__ w5,
                   unsigned short* __restrict__ d0, unsigned short* __restrict__ d1,
                   unsigned short* __restrict__ d2, unsigned short* __restrict__ d3,
                   unsigned short* __restrict__ d4, unsigned short* __restrict__ d5) {
  int r = blockIdx.x * 256 + threadIdx.x;
  const float* src; unsigned short* dst;
  if (r < 6144) { src = w0; dst = d0; }
  else if (r < 8192) { src = w1; dst = d1; r -= 6144; }
  else if (r < 14336) { src = w2; dst = d2; r -= 8192; }
  else if (r < 16384) { src = w3; dst = d3; r -= 14336; }
  else if (r < 20480) { src = w4; dst = d4; r -= 16384; }
  else if (r < 22528) { src = w5; dst = d5; r -= 20480; }
  else return;
  const float* in = src + (size_t)r * 32;
  union { unsigned short u[32]; uint4 q[4]; } H, L;
#pragma unroll
  for (int i = 0; i < 32; ++i) {
    float x = in[i];
    unsigned short h = f2bf(x);
    H.u[i] = h;
    L.u[i] = f2bf(x - bf2f(h));
  }
  uint4* op = (uint4*)(dst + (size_t)r * 64);
#pragma unroll
  for (int q = 0; q < 4; ++q) { op[q] = H.q[q]; op[4 + q] = L.q[q]; }
}

// ---------------------------------------------------------------------------
// conv1x1 as split-precision MFMA GEMM. Tile OT(o) x 64(s), K-step 32.
// ---------------------------------------------------------------------------
template<int ACT, int OT>
__global__ __launch_bounds__(256)
void conv_mfma_kernel(const unsigned short* __restrict__ Whl,
                      const float* __restrict__ X,
                      const float* __restrict__ bias,
                      float* __restrict__ Y,
                      int Cin, int S, size_t YbS) {
  constexpr int OI = OT / 64;  // o-frags per wave
  __shared__ __align__(16) unsigned short Bs[64 * 64];  // 8 KB
  const int tid = threadIdx.x;
  const int w = tid >> 6, lane = tid & 63;
  const int g = lane >> 4, c = lane & 15;
  const int s0 = blockIdx.x * 64;
  const int o0 = blockIdx.y * OT;
  const int b = blockIdx.z;
  const int KB = Cin >> 5;
  const float* Xb = X + (size_t)b * Cin * S;
  const int sRow = tid & 63;
  const int jS = tid >> 6;
  const int ss = s0 + sRow;
  const bool sIn = (ss < S);
  unsigned short* BsRow = Bs + sRow * 64;
  const int hiOff = (jS ^ (sRow & 7)) * 8;
  const int loOff = ((4 + jS) ^ (sRow & 7)) * 8;

  f32x4 acc[OI][4];
#pragma unroll
  for (int oi = 0; oi < OI; ++oi)
#pragma unroll
    for (int si = 0; si < 4; ++si) acc[oi][si] = (f32x4){0.f, 0.f, 0.f, 0.f};

  for (int kb = 0; kb < KB; ++kb) {
    union { unsigned u[4]; bf16x8 v; } hu, lu;
    if (sIn) {
      const float* xp = Xb + (size_t)(kb * 32 + 8 * jS) * S + ss;
#pragma unroll
      for (int i = 0; i < 4; ++i) {
        float x0 = xp[(size_t)(2 * i) * S];
        float x1 = xp[(size_t)(2 * i + 1) * S];
        unsigned hp = cvtpk(x0, x1);
        unsigned lp = cvtpk(x0 - bf2f_lo(hp), x1 - bf2f_hi(hp));
        hu.u[i] = hp; lu.u[i] = lp;
      }
    } else {
#pragma unroll
      for (int i = 0; i < 4; ++i) { hu.u[i] = 0; lu.u[i] = 0; }
    }
    bf16x8 ahi[OI], alo[OI];
#pragma unroll
    for (int oi = 0; oi < OI; ++oi) {
      const unsigned short* ap =
          Whl + ((size_t)(o0 + 16 * OI * w + 16 * oi + c) * KB + kb) * 64;
      ahi[oi] = *(const bf16x8*)(ap + 8 * g);
      alo[oi] = *(const bf16x8*)(ap + 32 + 8 * g);
    }
    __syncthreads();
    *(bf16x8*)(BsRow + hiOff) = hu.v;
    *(bf16x8*)(BsRow + loOff) = lu.v;
    __syncthreads();
    bf16x8 bhi[4], blo[4];
#pragma unroll
    for (int si = 0; si < 4; ++si) {
      int row = 16 * si + c;
      const unsigned short* bp = Bs + row * 64;
      bhi[si] = *(const bf16x8*)(bp + (g ^ (row & 7)) * 8);
      blo[si] = *(const bf16x8*)(bp + (((4 + g) ^ (row & 7))) * 8);
    }
#pragma unroll
    for (int oi = 0; oi < OI; ++oi)
#pragma unroll
      for (int si = 0; si < 4; ++si) {
        acc[oi][si] = __builtin_amdgcn_mfma_f32_16x16x32_bf16(ahi[oi], bhi[si], acc[oi][si], 0, 0, 0);
        acc[oi][si] = __builtin_amdgcn_mfma_f32_16x16x32_bf16(ahi[oi], blo[si], acc[oi][si], 0, 0, 0);
        acc[oi][si] = __builtin_amdgcn_mfma_f32_16x16x32_bf16(alo[oi], bhi[si], acc[oi][si], 0, 0, 0);
      }
  }
#pragma unroll
  for (int oi = 0; oi < OI; ++oi) {
#pragma unroll
    for (int r = 0; r < 4; ++r) {
      int o = o0 + 16 * OI * w + 16 * oi + 4 * g + r;
      float bv = bias ? bias[o] : 0.f;
#pragma unroll
      for (int si = 0; si < 4; ++si) {
        int s = s0 + 16 * si + c;
        if (s < S) {
          float v = acc[oi][si][r] + bv;
          if (ACT == 1) v = v * 0.5f * (1.0f + erff(v * 0.70710678118654752f));
          Y[(size_t)b * YbS + (size_t)o * S + s] = v;
        }
      }
    }
  }
}

// ---------------------------------------------------------------------------
// L2-normalize q,k head-vectors, convert to bf16 row-major [b][h][s][32].
// q additionally pre-scaled by hd^-0.5 * log2(e) so attention can use exp2.
// K rows stored permuted within 64-row blocks (QK^T acc == PV B-frag layout).
// ---------------------------------------------------------------------------
__global__ __launch_bounds__(256)
void l2ncvt_kernel(const float* __restrict__ qkv, unsigned short* __restrict__ qd,
                   unsigned short* __restrict__ kd, int S, int Sp) {
  int idx = blockIdx.x * 256 + threadIdx.x;
  int s = idx % Sp; int t = idx / Sp;
  int h = t & 7; t >>= 3;
  int qk = t & 1; int b = t >> 1;
  if (b >= 4) return;
  unsigned short* dst;
  int srow;
  if (qk == 0) { dst = qd; srow = s; }
  else {
    dst = kd;
    int blk = s >> 6, j = s & 63;
    srow = (blk << 6) + 32 * ((j >> 2) & 1) + 16 * (j >> 5) + 4 * ((j >> 3) & 3) + (j & 3);
  }
  unsigned wbuf[16];
  if (s < S) {
    const float* base = qkv + ((size_t)b * 768 + qk * 256 + h * 32) * S + s;
    float v[32]; float ss = 0.f;
#pragma unroll
    for (int d = 0; d < 32; ++d) { v[d] = base[(size_t)d * S]; ss += v[d] * v[d]; }
    float inv = 1.0f / fmaxf(sqrtf(ss), 1e-12f);
    if (qk == 0) inv *= 0.25506607138105343f;  // 32^-0.5 * log2(e)
#pragma unroll
    for (int i = 0; i < 16; ++i) wbuf[i] = cvtpk(v[2 * i] * inv, v[2 * i + 1] * inv);
  } else {
#pragma unroll
    for (int i = 0; i < 16; ++i) wbuf[i] = 0u;
  }
  uint4* o = (uint4*)(dst + ((size_t)(b * 8 + h) * Sp + srow) * 32);
#pragma unroll
  for (int i = 0; i < 4; ++i)
    o[i] = make_uint4(wbuf[4 * i], wbuf[4 * i + 1], wbuf[4 * i + 2], wbuf[4 * i + 3]);
}

// ---------------------------------------------------------------------------
// v -> bf16 d-major layout vt[b][h][32][Sp], zero-padded past S.
// ---------------------------------------------------------------------------
__global__ __launch_bounds__(256)
void vcvt_kernel(const float* __restrict__ qkv, unsigned short* __restrict__ vt,
                 int S, int Sp) {
  int idx = blockIdx.x * 256 + threadIdx.x;
  int SpH = Sp >> 1;
  int sp = idx % SpH; int t = idx / SpH;
  int d = t & 31; t >>= 5;
  int h = t & 7; int b = t >> 3;
  if (b >= 4) return;
  const float* src = qkv + ((size_t)b * 768 + 512 + h * 32 + d) * S;
  int s2 = 2 * sp;
  float a = (s2 < S) ? src[s2] : 0.f;
  float c = (s2 + 1 < S) ? src[s2 + 1] : 0.f;
  *(unsigned*)(vt + ((size_t)(b * 8 + h) * 32 + d) * Sp + s2) = cvtpk(a, c);
}

// ---------------------------------------------------------------------------
// MFMA flash attention, K-split into KS partials. No online max (logits
// bounded: q,k L2-normalized). 64 q-rows per wave (four Q frags share each
// K/V fragment load -> 32 MFMA per 8 loads). Softmax phase-paired per 32-key
// half (kb) to cap live registers; K prefetched one chunk ahead.
// GRID (8=h, qblk*KS, b): lin%8==h pins each head's K/V to one XCD's L2.
// ---------------------------------------------------------------------------
template<int KS>
__global__ __launch_bounds__(256)
void attn_mfma_kernel(const unsigned short* __restrict__ qr,
                      const unsigned short* __restrict__ kr,
                      const unsigned short* __restrict__ vt,
                      float* __restrict__ opart, float* __restrict__ lpart,
                      int S, int Sp) {
  int h = blockIdx.x, b = blockIdx.z;
  int qblk = blockIdx.y / KS;
  int ks = blockIdx.y - qblk * KS;
  int w = threadIdx.x >> 6, lane = threadIdx.x & 63;
  int g = lane >> 4, c = lane & 15;
  int q0 = qblk * 256 + w * 64;
  const int chunks = Sp >> 6;
  const int c0 = (ks * chunks) / KS, c1 = ((ks + 1) * chunks) / KS;
  const unsigned short* qbh = qr + (size_t)(b * 8 + h) * Sp * 32;
  const unsigned short* kbh = kr + (size_t)(b * 8 + h) * Sp * 32;
  const unsigned short* vbh = vt + (size_t)(b * 8 + h) * 32 * Sp;

  bf16x8 qf[4];
#pragma unroll
  for (int f = 0; f < 4; ++f)
    qf[f] = *(const bf16x8*)(qbh + (size_t)(q0 + 16 * f + c) * 32 + 8 * g);

  f32x4 oacc[4][2];
#pragma unroll
  for (int f = 0; f < 4; ++f) {
    oacc[f][0] = (f32x4){0.f, 0.f, 0.f, 0.f};
    oacc[f][1] = (f32x4){0.f, 0.f, 0.f, 0.f};
  }
  float ls[4] = {0.f, 0.f, 0.f, 0.f};

  bf16x8 kf[4];
  {
    int k0 = c0 * 64;
#pragma unroll
    for (int t = 0; t < 4; ++t)
      kf[t] = *(const bf16x8*)(kbh + (size_t)(k0 + 16 * t + c) * 32 + 8 * g);
  }

  for (int ch = c0; ch < c1; ++ch) {
    int k0 = ch * 64;
    const f32x4 z = {0.f, 0.f, 0.f, 0.f};
    bool full = (k0 + 64 <= S);
    // V fragments for this chunk (latency hidden under softmax work below)
    bf16x8 vf00 = *(const bf16x8*)(vbh + (size_t)c * Sp + k0 + 8 * g);
    bf16x8 vf01 = *(const bf16x8*)(vbh + (size_t)(16 + c) * Sp + k0 + 8 * g);
    bf16x8 vf10 = *(const bf16x8*)(vbh + (size_t)c * Sp + k0 + 32 + 8 * g);
    bf16x8 vf11 = *(const bf16x8*)(vbh + (size_t)(16 + c) * Sp + k0 + 32 + 8 * g);

    // ---- phase kb=0: K-subtiles t=0 (k-slots 0-3) and t=2 (k-slots 4-7) ----
    f32x4 sL[4], sH[4];
    __builtin_amdgcn_s_setprio(1);
#pragma unroll
    for (int f = 0; f < 4; ++f) {
      sL[f] = __builtin_amdgcn_mfma_f32_16x16x32_bf16(kf[0], qf[f], z, 0, 0, 0);
      sH[f] = __builtin_amdgcn_mfma_f32_16x16x32_bf16(kf[2], qf[f], z, 0, 0, 0);
    }
    __builtin_amdgcn_s_setprio(0);
    union { bf16x8 v; unsigned u[4]; } pf[4];
    if (full) {
#pragma unroll
      for (int f = 0; f < 4; ++f) {
        float e0 = __builtin_amdgcn_exp2f(sL[f][0]);
        float e1 = __builtin_amdgcn_exp2f(sL[f][1]);
        float e2 = __builtin_amdgcn_exp2f(sL[f][2]);
        float e3 = __builtin_amdgcn_exp2f(sL[f][3]);
        float e4 = __builtin_amdgcn_exp2f(sH[f][0]);
        float e5 = __builtin_amdgcn_exp2f(sH[f][1]);
        float e6 = __builtin_amdgcn_exp2f(sH[f][2]);
        float e7 = __builtin_amdgcn_exp2f(sH[f][3]);
        ls[f] += ((e0 + e1) + (e2 + e3)) + ((e4 + e5) + (e6 + e7));
        pf[f].u[0] = cvtpk(e0, e1); pf[f].u[1] = cvtpk(e2, e3);
        pf[f].u[2] = cvtpk(e4, e5); pf[f].u[3] = cvtpk(e6, e7);
      }
    } else {
#pragma unroll
      for (int f = 0; f < 4; ++f) {
        float e[8];
#pragma unroll
        for (int r = 0; r < 4; ++r) {
          int keyL = k0 + 8 * g + r;          // t=0
          int keyH = k0 + 8 * g + 4 + r;      // t=2
          e[r]     = (keyL < S) ? __builtin_amdgcn_exp2f(sL[f][r]) : 0.f;
          e[4 + r] = (keyH < S) ? __builtin_amdgcn_exp2f(sH[f][r]) : 0.f;
        }
        ls[f] += ((e[0] + e[1]) + (e[2] + e[3])) + ((e[4] + e[5]) + (e[6] + e[7]));
        pf[f].u[0] = cvtpk(e[0], e[1]); pf[f].u[1] = cvtpk(e[2], e[3]);
        pf[f].u[2] = cvtpk(e[4], e[5]); pf[f].u[3] = cvtpk(e[6], e[7]);
      }
    }
    __builtin_amdgcn_s_setprio(1);
#pragma unroll
    for (int f = 0; f < 4; ++f) {
      oacc[f][0] = __builtin_amdgcn_mfma_f32_16x16x32_bf16(vf00, pf[f].v, oacc[f][0], 0, 0, 0);
      oacc[f][1] = __builtin_amdgcn_mfma_f32_16x16x32_bf16(vf01, pf[f].v, oacc[f][1], 0, 0, 0);
    }
    // ---- phase kb=1: K-subtiles t=1, t=3 ----
#pragma unroll
    for (int f = 0; f < 4; ++f) {
      sL[f] = __builtin_amdgcn_mfma_f32_16x16x32_bf16(kf[1], qf[f], z, 0, 0, 0);
      sH[f] = __builtin_amdgcn_mfma_f32_16x16x32_bf16(kf[3], qf[f], z, 0, 0, 0);
    }
    __builtin_amdgcn_s_setprio(0);
    // K prefetch for next chunk (kf free now)
    if (ch + 1 < c1) {
      int kn = (ch + 1) * 64;
#pragma unroll
      for (int t = 0; t < 4; ++t)
        kf[t] = *(const bf16x8*)(kbh + (size_t)(kn + 16 * t + c) * 32 + 8 * g);
    }
    if (full) {
#pragma unroll
      for (int f = 0; f < 4; ++f) {
        float e0 = __builtin_amdgcn_exp2f(sL[f][0]);
        float e1 = __builtin_amdgcn_exp2f(sL[f][1]);
        float e2 = __builtin_amdgcn_exp2f(sL[f][2]);
        float e3 = __builtin_amdgcn_exp2f(sL[f][3]);
        float e4 = __builtin_amdgcn_exp2f(sH[f][0]);
        float e5 = __builtin_amdgcn_exp2f(sH[f][1]);
        float e6 = __builtin_amdgcn_exp2f(sH[f][2]);
        float e7 = __builtin_amdgcn_exp2f(sH[f][3]);
        ls[f] += ((e0 + e1) + (e2 + e3)) + ((e4 + e5) + (e6 + e7));
        pf[f].u[0] = cvtpk(e0, e1); pf[f].u[1] = cvtpk(e2, e3);
        pf[f].u[2] = cvtpk(e4, e5); pf[f].u[3] = cvtpk(e6, e7);
      }
    } else {
#pragma unroll
      for (int f = 0; f < 4; ++f) {
        float e[8];
#pragma unroll
        for (int r = 0; r < 4; ++r) {
          int keyL = k0 + 32 + 8 * g + r;      // t=1
          int keyH = k0 + 32 + 8 * g + 4 + r;  // t=3
          e[r]     = (keyL < S) ? __builtin_amdgcn_exp2f(sL[f][r]) : 0.f;
          e[4 + r] = (keyH < S) ? __builtin_amdgcn_exp2f(sH[f][r]) : 0.f;
        }
        ls[f] += ((e[0] + e[1]) + (e[2] + e[3])) + ((e[4] + e[5]) + (e[6] + e[7]));
        pf[f].u[0] = cvtpk(e[0], e[1]); pf[f].u[1] = cvtpk(e[2], e[3]);
        pf[f].u[2] = cvtpk(e[4], e[5]); pf[f].u[3] = cvtpk(e[6], e[7]);
      }
    }
    __builtin_amdgcn_s_setprio(1);
#pragma unroll
    for (int f = 0; f < 4; ++f) {
      oacc[f][0] = __builtin_amdgcn_mfma_f32_16x16x32_bf16(vf10, pf[f].v, oacc[f][0], 0, 0, 0);
      oacc[f][1] = __builtin_amdgcn_mfma_f32_16x16x32_bf16(vf11, pf[f].v, oacc[f][1], 0, 0, 0);
    }
    __builtin_amdgcn_s_setprio(0);
  }
#pragma unroll
  for (int f = 0; f < 4; ++f) {
    ls[f] += __shfl_xor(ls[f], 16, 64);
    ls[f] += __shfl_xor(ls[f], 32, 64);
  }
  size_t obase = ((size_t)(ks * 4 + b) * 256 + h * 32) * S;
#pragma unroll
  for (int f = 0; f < 4; ++f) {
    int q = q0 + 16 * f + c;
    if (q < S) {
#pragma unroll
      for (int r = 0; r < 4; ++r) {
        opart[obase + (size_t)(4 * g + r) * S + q]      = oacc[f][0][r];
        opart[obase + (size_t)(16 + 4 * g + r) * S + q] = oacc[f][1][r];
      }
    }
  }
  if (lane < 16) {
    size_t lb = ((size_t)(ks * 4 + b) * 8 + h) * S;
#pragma unroll
    for (int f = 0; f < 4; ++f)
      if (q0 + 16 * f + lane < S) lpart[lb + q0 + 16 * f + lane] = ls[f];
  }
}

// ---------------------------------------------------------------------------
// Combine K-split partials: att[b][ch][s] = sum_ks O / sum_ks lsum.
// ---------------------------------------------------------------------------
template<int KS>
__global__ __launch_bounds__(256)
void att_combine_kernel(const float* __restrict__ opart,
                        const float* __restrict__ lpart,
                        float* __restrict__ att, int S, int N) {
  int idx = blockIdx.x * 256 + threadIdx.x;
  if (idx >= N) return;
  int S4 = S >> 2;
  int sq = idx % S4; int t = idx / S4;
  int ch = t & 255; int b = t >> 8;
  int s = sq * 4;
  float4 num = {0.f, 0.f, 0.f, 0.f};
  float4 den = {0.f, 0.f, 0.f, 0.f};
#pragma unroll
  for (int ks = 0; ks < KS; ++ks) {
    float4 o4 = *(const float4*)(opart + ((size_t)(ks * 4 + b) * 256 + ch) * S + s);
    float4 l4 = *(const float4*)(lpart + ((size_t)(ks * 4 + b) * 8 + (ch >> 5)) * S + s);
    num.x += o4.x; num.y += o4.y; num.z += o4.z; num.w += o4.w;
    den.x += l4.x; den.y += l4.y; den.z += l4.z; den.w += l4.w;
  }
  float4 r;
  r.x = num.x / den.x; r.y = num.y / den.y; r.z = num.z / den.z; r.w = num.w / den.w;
  *(float4*)(att + ((size_t)b * 256 + ch) * S + s) = r;
}

// ---------------------------------------------------------------------------
__global__ __launch_bounds__(256)
void pool_kernel(const float* __restrict__ x, float* __restrict__ xg) {
  int idx = blockIdx.x * 256 + threadIdx.x;
  if (idx >= 4 * 256 * 144) return;
  int wc = idx % 12;
  int t = idx / 12;
  int hc = t % 12;
  int bc = t / 12;
  const float* p = x + ((size_t)bc * 48 + hc * 4) * 48 + wc * 4;
  float s = 0.f;
#pragma unroll
  for (int dy = 0; dy < 4; ++dy)
#pragma unroll
    for (int dx = 0; dx < 4; ++dx) s += p[dy * 48 + dx];
  xg[idx] = s * (1.0f / 16.0f);
}

__global__ __launch_bounds__(256)
void upsample_kernel(const float* __restrict__ g, float* __restrict__ cat) {
  int idx = blockIdx.x * 256 + threadIdx.x;
  if (idx >= 4 * 256 * 2304) return;
  int xo = idx % 48;
  int t = idx / 48;
  int yo = t % 48;
  int bc = t / 48;
  int b = bc >> 8, c = bc & 255;
  float sy = 0.25f * yo - 0.375f;
  float sx = 0.25f * xo - 0.375f;
  int y0 = (int)floorf(sy); float fy = sy - (float)y0;
  int x0 = (int)floorf(sx); float fx = sx - (float)x0;
  int y0c = min(11, max(0, y0)), y1c = min(11, max(0, y0 + 1));
  int x0c = min(11, max(0, x0)), x1c = min(11, max(0, x0 + 1));
  const float* gb = g + (size_t)bc * 144;
  float v00 = gb[y0c * 12 + x0c], v01 = gb[y0c * 12 + x1c];
  float v10 = gb[y1c * 12 + x0c], v11 = gb[y1c * 12 + x1c];
  float v = (1.f - fy) * ((1.f - fx) * v00 + fx * v01) + fy * ((1.f - fx) * v10 + fx * v11);
  cat[((size_t)b * 512 + 256 + c) * 2304 + yo * 48 + xo] = v;
}

// ---------------------------------------------------------------------------
extern "C" void kernel_launch(void* const* d_in, const int* in_sizes, int n_in,
                              void* d_out, int out_size, void* d_ws, size_t ws_size,
                              hipStream_t stream) {
  const float* x        = (const float*)d_in[0];
  const float* w_qkv_l  = (const float*)d_in[1];
  const float* w_proj_l = (const float*)d_in[2];
  const float* b_proj_l = (const float*)d_in[3];
  const float* w_qkv_g  = (const float*)d_in[4];
  const float* w_proj_g = (const float*)d_in[5];
  const float* b_proj_g = (const float*)d_in[6];
  const float* w_f1     = (const float*)d_in[7];
  const float* b_f1     = (const float*)d_in[8];
  const float* w_f2     = (const float*)d_in[9];
  const float* b_f2     = (const float*)d_in[10];
  float* out = (float*)d_out;

  const int S = 2304, Sg = 144, B = 4;
  const int Sp = 2304, Sgp = 256;  // padded row counts (multiple of 256)
  const int KS = 3;

  char* wsp = (char*)d_ws;
  size_t off = 0;
  auto alloc = [&](size_t bytes) { char* p = wsp + off; off = (off + bytes + 255) & ~(size_t)255; return p; };
  float* qkv_l = (float*)alloc((size_t)B * 768 * S * 4);   // reused as opart_l
  float* att_l = (float*)alloc((size_t)B * 256 * S * 4);
  float* cat   = (float*)alloc((size_t)B * 512 * S * 4);
  float* hbuf  = (float*)alloc((size_t)B * 256 * S * 4);
  float* xg    = (float*)alloc((size_t)B * 256 * Sg * 4);
  float* qkv_g = (float*)alloc((size_t)B * 768 * Sg * 4);  // reused as opart_g
  float* att_g = (float*)alloc((size_t)B * 256 * Sg * 4);
  float* gsm   = (float*)alloc((size_t)B * 256 * Sg * 4);
  unsigned short* qr_l = (unsigned short*)alloc((size_t)B * 8 * Sp * 32 * 2);
  unsigned short* kr_l = (unsigned short*)alloc((size_t)B * 8 * Sp * 32 * 2);
  unsigned short* vt_l = (unsigned short*)alloc((size_t)B * 8 * Sp * 32 * 2);
  unsigned short* qr_g = (unsigned short*)alloc((size_t)B * 8 * Sgp * 32 * 2);
  unsigned short* kr_g = (unsigned short*)alloc((size_t)B * 8 * Sgp * 32 * 2);
  unsigned short* vt_g = (unsigned short*)alloc((size_t)B * 8 * Sgp * 32 * 2);
  unsigned short* whl_qkv_l  = (unsigned short*)alloc((size_t)768 * 256 * 2 * 2);
  unsigned short* whl_proj_l = (unsigned short*)alloc((size_t)256 * 256 * 2 * 2);
  unsigned short* whl_qkv_g  = (unsigned short*)alloc((size_t)768 * 256 * 2 * 2);
  unsigned short* whl_proj_g = (unsigned short*)alloc((size_t)256 * 256 * 2 * 2);
  unsigned short* whl_f1     = (unsigned short*)alloc((size_t)256 * 512 * 2 * 2);
  unsigned short* whl_f2     = (unsigned short*)alloc((size_t)256 * 256 * 2 * 2);
  float* lpart_l = (float*)alloc((size_t)KS * B * 8 * S * 4);
  float* lpart_g = (float*)alloc((size_t)KS * B * 8 * Sg * 4);
  float* opart_l = qkv_l;  // qkv_l dead after l2ncvt/vcvt consume it
  float* opart_g = qkv_g;

  dim3 blk(256);

  wsplit_kernel<<<dim3(88), blk, 0, stream>>>(
      w_qkv_l, w_proj_l, w_qkv_g, w_proj_g, w_f1, w_f2,
      whl_qkv_l, whl_proj_l, whl_qkv_g, whl_proj_g, whl_f1, whl_f2);

  // ----- local branch -----
  conv_mfma_kernel<0, 128><<<dim3(36, 6, B), blk, 0, stream>>>(
      whl_qkv_l, x, nullptr, qkv_l, 256, S, (size_t)768 * S);
  l2ncvt_kernel<<<dim3((B * 2 * 8 * Sp) / 256), blk, 0, stream>>>(qkv_l, qr_l, kr_l, S, Sp);
  vcvt_kernel<<<dim3((B * 8 * 32 * (Sp / 2)) / 256), blk, 0, stream>>>(qkv_l, vt_l, S, Sp);
  attn_mfma_kernel<KS><<<dim3(8, (Sp / 256) * KS, B), blk, 0, stream>>>(
      qr_l, kr_l, vt_l, opart_l, lpart_l, S, Sp);
  att_combine_kernel<KS><<<dim3((B * 256 * (S / 4) + 255) / 256), blk, 0, stream>>>(
      opart_l, lpart_l, att_l, S, B * 256 * (S / 4));
  conv_mfma_kernel<0, 64><<<dim3(36, 4, B), blk, 0, stream>>>(
      whl_proj_l, att_l, b_proj_l, cat, 256, S, (size_t)512 * S);

  // ----- global branch -----
  pool_kernel<<<dim3(576), blk, 0, stream>>>(x, xg);
  conv_mfma_kernel<0, 64><<<dim3(3, 12, B), blk, 0, stream>>>(
      whl_qkv_g, xg, nullptr, qkv_g, 256, Sg, (size_t)768 * Sg);
  l2ncvt_kernel<<<dim3((B * 2 * 8 * Sgp) / 256), blk, 0, stream>>>(qkv_g, qr_g, kr_g, Sg, Sgp);
  vcvt_kernel<<<dim3((B * 8 * 32 * (Sgp / 2)) / 256), blk, 0, stream>>>(qkv_g, vt_g, Sg, Sgp);
  attn_mfma_kernel<KS><<<dim3(8, (Sgp / 256) * KS, B), blk, 0, stream>>>(
      qr_g, kr_g, vt_g, opart_g, lpart_g, Sg, Sgp);
  att_combine_kernel<KS><<<dim3((B * 256 * (Sg / 4) + 255) / 256), blk, 0, stream>>>(
      opart_g, lpart_g, att_g, Sg, B * 256 * (Sg / 4));
  conv_mfma_kernel<0, 64><<<dim3(3, 4, B), blk, 0, stream>>>(
      whl_proj_g, att_g, b_proj_g, gsm, 256, Sg, (size_t)256 * Sg);
  upsample_kernel<<<dim3(9216), blk, 0, stream>>>(gsm, cat);

  // ----- fuse: f1 (GELU) then f2 -----
  conv_mfma_kernel<1, 64><<<dim3(36, 4, B), blk, 0, stream>>>(
      whl_f1, cat, b_f1, hbuf, 512, S, (size_t)256 * S);
  conv_mfma_kernel<0, 64><<<dim3(36, 4, B), blk, 0, stream>>>(
      whl_f2, hbuf, b_f2, out, 256, S, (size_t)256 * S);
}

// Round 10
// 181.984 us; speedup vs baseline: 9.2644x; 1.0361x over previous
//
#include <hip/hip_runtime.h>
#include <hip/hip_bf16.h>
#include <math.h>

typedef __attribute__((ext_vector_type(8))) short bf16x8;
typedef __attribute__((ext_vector_type(4))) float f32x4;

__device__ inline unsigned short f2bf(float x) {
  __hip_bfloat16 h = __float2bfloat16(x);
  return __builtin_bit_cast(unsigned short, h);
}
__device__ inline float bf2f(unsigned short u) {
  unsigned v = ((unsigned)u) << 16;
  return __builtin_bit_cast(float, v);
}
// One-instruction RNE pack of two f32 -> packed bf16x2 (low = a, high = b).
__device__ inline unsigned cvtpk(float a, float b) {
  unsigned r;
  asm("v_cvt_pk_bf16_f32 %0, %1, %2" : "=v"(r) : "v"(a), "v"(b));
  return r;
}
__device__ inline float bf2f_lo(unsigned p) {
  return __builtin_bit_cast(float, p << 16);
}
__device__ inline float bf2f_hi(unsigned p) {
  return __builtin_bit_cast(float, p & 0xffff0000u);
}

// ---------------------------------------------------------------------------
// Weight split: W[O][Cin] f32 -> Whl rows of 128B: [o][kb][32 hi bf16 | 32 lo].
// ---------------------------------------------------------------------------
__global__ __launch_bounds__(256)
void wsplit_kernel(const float* __restrict__ w0, const float* __restrict__ w1,
                   const float* __restrict__ w2, const float* __restrict__ w3,
                   const float* __restrict__ w4, const float* __restrict__ w5,
                   unsigned short* __restrict__ d0, unsigned short* __restrict__ d1,
                   unsigned short* __restrict__ d2, unsigned short* __restrict__ d3,
                   unsigned short* __restrict__ d4, unsigned short* __restrict__ d5) {
  int r = blockIdx.x * 256 + threadIdx.x;
  const float* src; unsigned short* dst;
  if (r < 6144) { src = w0; dst = d0; }
  else if (r < 8192) { src = w1; dst = d1; r -= 6144; }
  else if (r < 14336) { src = w2; dst = d2; r -= 8192; }
  else if (r < 16384) { src = w3; dst = d3; r -= 14336; }
  else if (r < 20480) { src = w4; dst = d4; r -= 16384; }
  else if (r < 22528) { src = w5; dst = d5; r -= 20480; }
  else return;
  const float* in = src + (size_t)r * 32;
  union { unsigned short u[32]; uint4 q[4]; } H, L;
#pragma unroll
  for (int i = 0; i < 32; ++i) {
    float x = in[i];
    unsigned short h = f2bf(x);
    H.u[i] = h;
    L.u[i] = f2bf(x - bf2f(h));
  }
  uint4* op = (uint4*)(dst + (size_t)r * 64);
#pragma unroll
  for (int q = 0; q < 4; ++q) { op[q] = H.q[q]; op[4 + q] = L.q[q]; }
}

// ---------------------------------------------------------------------------
// conv1x1 as 2-term MFMA GEMM:  Y = (Whi + Wlo) . Xhi  (+bias, +act).
// W precision ~2^-17 (pre-split hi/lo); X truncated to bf16 (its f32 tail is
// quantized away downstream anyway). Tile OT(o) x 64(s), K-step 32.
// LDS: Bs[64 s][4 slots x 16B], slot = octet ^ ((row>>1)&3) -> 2-way (free).
// ---------------------------------------------------------------------------
template<int ACT, int OT>
__global__ __launch_bounds__(256)
void conv_mfma_kernel(const unsigned short* __restrict__ Whl,
                      const float* __restrict__ X,
                      const float* __restrict__ bias,
                      float* __restrict__ Y,
                      int Cin, int S, size_t YbS) {
  constexpr int OI = OT / 64;  // o-frags per wave
  __shared__ __align__(16) unsigned short Bs[64 * 32];  // 4 KB
  const int tid = threadIdx.x;
  const int w = tid >> 6, lane = tid & 63;
  const int g = lane >> 4, c = lane & 15;
  const int s0 = blockIdx.x * 64;
  const int o0 = blockIdx.y * OT;
  const int b = blockIdx.z;
  const int KB = Cin >> 5;
  const float* Xb = X + (size_t)b * Cin * S;
  const int sRow = tid & 63;
  const int jS = tid >> 6;
  const int ss = s0 + sRow;
  const bool sIn = (ss < S);
  unsigned short* BsRow = Bs + sRow * 32;
  const int hiOff = (jS ^ ((sRow >> 1) & 3)) * 8;

  f32x4 acc[OI][4];
#pragma unroll
  for (int oi = 0; oi < OI; ++oi)
#pragma unroll
    for (int si = 0; si < 4; ++si) acc[oi][si] = (f32x4){0.f, 0.f, 0.f, 0.f};

  for (int kb = 0; kb < KB; ++kb) {
    union { unsigned u[4]; bf16x8 v; } hu;
    if (sIn) {
      const float* xp = Xb + (size_t)(kb * 32 + 8 * jS) * S + ss;
#pragma unroll
      for (int i = 0; i < 4; ++i) {
        float x0 = xp[(size_t)(2 * i) * S];
        float x1 = xp[(size_t)(2 * i + 1) * S];
        hu.u[i] = cvtpk(x0, x1);
      }
    } else {
#pragma unroll
      for (int i = 0; i < 4; ++i) hu.u[i] = 0;
    }
    bf16x8 ahi[OI], alo[OI];
#pragma unroll
    for (int oi = 0; oi < OI; ++oi) {
      const unsigned short* ap =
          Whl + ((size_t)(o0 + 16 * OI * w + 16 * oi + c) * KB + kb) * 64;
      ahi[oi] = *(const bf16x8*)(ap + 8 * g);
      alo[oi] = *(const bf16x8*)(ap + 32 + 8 * g);
    }
    __syncthreads();
    *(bf16x8*)(BsRow + hiOff) = hu.v;
    __syncthreads();
    bf16x8 bhi[4];
#pragma unroll
    for (int si = 0; si < 4; ++si) {
      int row = 16 * si + c;
      const unsigned short* bp = Bs + row * 32;
      bhi[si] = *(const bf16x8*)(bp + ((g ^ ((row >> 1) & 3)) * 8));
    }
#pragma unroll
    for (int oi = 0; oi < OI; ++oi)
#pragma unroll
      for (int si = 0; si < 4; ++si) {
        acc[oi][si] = __builtin_amdgcn_mfma_f32_16x16x32_bf16(ahi[oi], bhi[si], acc[oi][si], 0, 0, 0);
        acc[oi][si] = __builtin_amdgcn_mfma_f32_16x16x32_bf16(alo[oi], bhi[si], acc[oi][si], 0, 0, 0);
      }
  }
#pragma unroll
  for (int oi = 0; oi < OI; ++oi) {
#pragma unroll
    for (int r = 0; r < 4; ++r) {
      int o = o0 + 16 * OI * w + 16 * oi + 4 * g + r;
      float bv = bias ? bias[o] : 0.f;
#pragma unroll
      for (int si = 0; si < 4; ++si) {
        int s = s0 + 16 * si + c;
        if (s < S) {
          float v = acc[oi][si][r] + bv;
          if (ACT == 1) v = v * 0.5f * (1.0f + erff(v * 0.70710678118654752f));
          Y[(size_t)b * YbS + (size_t)o * S + s] = v;
        }
      }
    }
  }
}

// ---------------------------------------------------------------------------
// L2-normalize q,k head-vectors, convert to bf16 row-major [b][h][s][32].
// q additionally pre-scaled by hd^-0.5 * log2(e) so attention can use exp2.
// K rows stored permuted within 64-row blocks (QK^T acc == PV B-frag layout).
// ---------------------------------------------------------------------------
__global__ __launch_bounds__(256)
void l2ncvt_kernel(const float* __restrict__ qkv, unsigned short* __restrict__ qd,
                   unsigned short* __restrict__ kd, int S, int Sp) {
  int idx = blockIdx.x * 256 + threadIdx.x;
  int s = idx % Sp; int t = idx / Sp;
  int h = t & 7; t >>= 3;
  int qk = t & 1; int b = t >> 1;
  if (b >= 4) return;
  unsigned short* dst;
  int srow;
  if (qk == 0) { dst = qd; srow = s; }
  else {
    dst = kd;
    int blk = s >> 6, j = s & 63;
    srow = (blk << 6) + 32 * ((j >> 2) & 1) + 16 * (j >> 5) + 4 * ((j >> 3) & 3) + (j & 3);
  }
  unsigned wbuf[16];
  if (s < S) {
    const float* base = qkv + ((size_t)b * 768 + qk * 256 + h * 32) * S + s;
    float v[32]; float ss = 0.f;
#pragma unroll
    for (int d = 0; d < 32; ++d) { v[d] = base[(size_t)d * S]; ss += v[d] * v[d]; }
    float inv = 1.0f / fmaxf(sqrtf(ss), 1e-12f);
    if (qk == 0) inv *= 0.25506607138105343f;  // 32^-0.5 * log2(e)
#pragma unroll
    for (int i = 0; i < 16; ++i) wbuf[i] = cvtpk(v[2 * i] * inv, v[2 * i + 1] * inv);
  } else {
#pragma unroll
    for (int i = 0; i < 16; ++i) wbuf[i] = 0u;
  }
  uint4* o = (uint4*)(dst + ((size_t)(b * 8 + h) * Sp + srow) * 32);
#pragma unroll
  for (int i = 0; i < 4; ++i)
    o[i] = make_uint4(wbuf[4 * i], wbuf[4 * i + 1], wbuf[4 * i + 2], wbuf[4 * i + 3]);
}

// ---------------------------------------------------------------------------
// v -> bf16 d-major layout vt[b][h][32][Sp], zero-padded past S.
// ---------------------------------------------------------------------------
__global__ __launch_bounds__(256)
void vcvt_kernel(const float* __restrict__ qkv, unsigned short* __restrict__ vt,
                 int S, int Sp) {
  int idx = blockIdx.x * 256 + threadIdx.x;
  int SpH = Sp >> 1;
  int sp = idx % SpH; int t = idx / SpH;
  int d = t & 31; t >>= 5;
  int h = t & 7; int b = t >> 3;
  if (b >= 4) return;
  const float* src = qkv + ((size_t)b * 768 + 512 + h * 32 + d) * S;
  int s2 = 2 * sp;
  float a = (s2 < S) ? src[s2] : 0.f;
  float c = (s2 + 1 < S) ? src[s2 + 1] : 0.f;
  *(unsigned*)(vt + ((size_t)(b * 8 + h) * 32 + d) * Sp + s2) = cvtpk(a, c);
}

// ---------------------------------------------------------------------------
// MFMA flash attention, K-split into KS partials. No online max (logits
// bounded: q,k L2-normalized). 64 q-rows per wave (four Q frags share each
// K/V fragment load -> 32 MFMA per 8 loads). Softmax phase-paired per 32-key
// half (kb) to cap live registers; K prefetched one chunk ahead.
// GRID (8=h, qblk*KS, b): lin%8==h pins each head's K/V to one XCD's L2.
// ---------------------------------------------------------------------------
template<int KS>
__global__ __launch_bounds__(256)
void attn_mfma_kernel(const unsigned short* __restrict__ qr,
                      const unsigned short* __restrict__ kr,
                      const unsigned short* __restrict__ vt,
                      float* __restrict__ opart, float* __restrict__ lpart,
                      int S, int Sp) {
  int h = blockIdx.x, b = blockIdx.z;
  int qblk = blockIdx.y / KS;
  int ks = blockIdx.y - qblk * KS;
  int w = threadIdx.x >> 6, lane = threadIdx.x & 63;
  int g = lane >> 4, c = lane & 15;
  int q0 = qblk * 256 + w * 64;
  const int chunks = Sp >> 6;
  const int c0 = (ks * chunks) / KS, c1 = ((ks + 1) * chunks) / KS;
  const unsigned short* qbh = qr + (size_t)(b * 8 + h) * Sp * 32;
  const unsigned short* kbh = kr + (size_t)(b * 8 + h) * Sp * 32;
  const unsigned short* vbh = vt + (size_t)(b * 8 + h) * 32 * Sp;

  bf16x8 qf[4];
#pragma unroll
  for (int f = 0; f < 4; ++f)
    qf[f] = *(const bf16x8*)(qbh + (size_t)(q0 + 16 * f + c) * 32 + 8 * g);

  f32x4 oacc[4][2];
#pragma unroll
  for (int f = 0; f < 4; ++f) {
    oacc[f][0] = (f32x4){0.f, 0.f, 0.f, 0.f};
    oacc[f][1] = (f32x4){0.f, 0.f, 0.f, 0.f};
  }
  float ls[4] = {0.f, 0.f, 0.f, 0.f};

  bf16x8 kf[4];
  {
    int k0 = c0 * 64;
#pragma unroll
    for (int t = 0; t < 4; ++t)
      kf[t] = *(const bf16x8*)(kbh + (size_t)(k0 + 16 * t + c) * 32 + 8 * g);
  }

  for (int ch = c0; ch < c1; ++ch) {
    int k0 = ch * 64;
    const f32x4 z = {0.f, 0.f, 0.f, 0.f};
    bool full = (k0 + 64 <= S);
    // V fragments for this chunk (latency hidden under softmax work below)
    bf16x8 vf00 = *(const bf16x8*)(vbh + (size_t)c * Sp + k0 + 8 * g);
    bf16x8 vf01 = *(const bf16x8*)(vbh + (size_t)(16 + c) * Sp + k0 + 8 * g);
    bf16x8 vf10 = *(const bf16x8*)(vbh + (size_t)c * Sp + k0 + 32 + 8 * g);
    bf16x8 vf11 = *(const bf16x8*)(vbh + (size_t)(16 + c) * Sp + k0 + 32 + 8 * g);

    // ---- phase kb=0: K-subtiles t=0 (k-slots 0-3) and t=2 (k-slots 4-7) ----
    f32x4 sL[4], sH[4];
    __builtin_amdgcn_s_setprio(1);
#pragma unroll
    for (int f = 0; f < 4; ++f) {
      sL[f] = __builtin_amdgcn_mfma_f32_16x16x32_bf16(kf[0], qf[f], z, 0, 0, 0);
      sH[f] = __builtin_amdgcn_mfma_f32_16x16x32_bf16(kf[2], qf[f], z, 0, 0, 0);
    }
    __builtin_amdgcn_s_setprio(0);
    union { bf16x8 v; unsigned u[4]; } pf[4];
    if (full) {
#pragma unroll
      for (int f = 0; f < 4; ++f) {
        float e0 = __builtin_amdgcn_exp2f(sL[f][0]);
        float e1 = __builtin_amdgcn_exp2f(sL[f][1]);
        float e2 = __builtin_amdgcn_exp2f(sL[f][2]);
        float e3 = __builtin_amdgcn_exp2f(sL[f][3]);
        float e4 = __builtin_amdgcn_exp2f(sH[f][0]);
        float e5 = __builtin_amdgcn_exp2f(sH[f][1]);
        float e6 = __builtin_amdgcn_exp2f(sH[f][2]);
        float e7 = __builtin_amdgcn_exp2f(sH[f][3]);
        ls[f] += ((e0 + e1) + (e2 + e3)) + ((e4 + e5) + (e6 + e7));
        pf[f].u[0] = cvtpk(e0, e1); pf[f].u[1] = cvtpk(e2, e3);
        pf[f].u[2] = cvtpk(e4, e5); pf[f].u[3] = cvtpk(e6, e7);
      }
    } else {
#pragma unroll
      for (int f = 0; f < 4; ++f) {
        float e[8];
#pragma unroll
        for (int r = 0; r < 4; ++r) {
          int keyL = k0 + 8 * g + r;          // t=0
          int keyH = k0 + 8 * g + 4 + r;      // t=2
          e[r]     = (keyL < S) ? __builtin_amdgcn_exp2f(sL[f][r]) : 0.f;
          e[4 + r] = (keyH < S) ? __builtin_amdgcn_exp2f(sH[f][r]) : 0.f;
        }
        ls[f] += ((e[0] + e[1]) + (e[2] + e[3])) + ((e[4] + e[5]) + (e[6] + e[7]));
        pf[f].u[0] = cvtpk(e[0], e[1]); pf[f].u[1] = cvtpk(e[2], e[3]);
        pf[f].u[2] = cvtpk(e[4], e[5]); pf[f].u[3] = cvtpk(e[6], e[7]);
      }
    }
    __builtin_amdgcn_s_setprio(1);
#pragma unroll
    for (int f = 0; f < 4; ++f) {
      oacc[f][0] = __builtin_amdgcn_mfma_f32_16x16x32_bf16(vf00, pf[f].v, oacc[f][0], 0, 0, 0);
      oacc[f][1] = __builtin_amdgcn_mfma_f32_16x16x32_bf16(vf01, pf[f].v, oacc[f][1], 0, 0, 0);
    }
    // ---- phase kb=1: K-subtiles t=1, t=3 ----
#pragma unroll
    for (int f = 0; f < 4; ++f) {
      sL[f] = __builtin_amdgcn_mfma_f32_16x16x32_bf16(kf[1], qf[f], z, 0, 0, 0);
      sH[f] = __builtin_amdgcn_mfma_f32_16x16x32_bf16(kf[3], qf[f], z, 0, 0, 0);
    }
    __builtin_amdgcn_s_setprio(0);
    // K prefetch for next chunk (kf free now)
    if (ch + 1 < c1) {
      int kn = (ch + 1) * 64;
#pragma unroll
      for (int t = 0; t < 4; ++t)
        kf[t] = *(const bf16x8*)(kbh + (size_t)(kn + 16 * t + c) * 32 + 8 * g);
    }
    if (full) {
#pragma unroll
      for (int f = 0; f < 4; ++f) {
        float e0 = __builtin_amdgcn_exp2f(sL[f][0]);
        float e1 = __builtin_amdgcn_exp2f(sL[f][1]);
        float e2 = __builtin_amdgcn_exp2f(sL[f][2]);
        float e3 = __builtin_amdgcn_exp2f(sL[f][3]);
        float e4 = __builtin_amdgcn_exp2f(sH[f][0]);
        float e5 = __builtin_amdgcn_exp2f(sH[f][1]);
        float e6 = __builtin_amdgcn_exp2f(sH[f][2]);
        float e7 = __builtin_amdgcn_exp2f(sH[f][3]);
        ls[f] += ((e0 + e1) + (e2 + e3)) + ((e4 + e5) + (e6 + e7));
        pf[f].u[0] = cvtpk(e0, e1); pf[f].u[1] = cvtpk(e2, e3);
        pf[f].u[2] = cvtpk(e4, e5); pf[f].u[3] = cvtpk(e6, e7);
      }
    } else {
#pragma unroll
      for (int f = 0; f < 4; ++f) {
        float e[8];
#pragma unroll
        for (int r = 0; r < 4; ++r) {
          int keyL = k0 + 32 + 8 * g + r;      // t=1
          int keyH = k0 + 32 + 8 * g + 4 + r;  // t=3
          e[r]     = (keyL < S) ? __builtin_amdgcn_exp2f(sL[f][r]) : 0.f;
          e[4 + r] = (keyH < S) ? __builtin_amdgcn_exp2f(sH[f][r]) : 0.f;
        }
        ls[f] += ((e[0] + e[1]) + (e[2] + e[3])) + ((e[4] + e[5]) + (e[6] + e[7]));
        pf[f].u[0] = cvtpk(e[0], e[1]); pf[f].u[1] = cvtpk(e[2], e[3]);
        pf[f].u[2] = cvtpk(e[4], e[5]); pf[f].u[3] = cvtpk(e[6], e[7]);
      }
    }
    __builtin_amdgcn_s_setprio(1);
#pragma unroll
    for (int f = 0; f < 4; ++f) {
      oacc[f][0] = __builtin_amdgcn_mfma_f32_16x16x32_bf16(vf10, pf[f].v, oacc[f][0], 0, 0, 0);
      oacc[f][1] = __builtin_amdgcn_mfma_f32_16x16x32_bf16(vf11, pf[f].v, oacc[f][1], 0, 0, 0);
    }
    __builtin_amdgcn_s_setprio(0);
  }
#pragma unroll
  for (int f = 0; f < 4; ++f) {
    ls[f] += __shfl_xor(ls[f], 16, 64);
    ls[f] += __shfl_xor(ls[f], 32, 64);
  }
  size_t obase = ((size_t)(ks * 4 + b) * 256 + h * 32) * S;
#pragma unroll
  for (int f = 0; f < 4; ++f) {
    int q = q0 + 16 * f + c;
    if (q < S) {
#pragma unroll
      for (int r = 0; r < 4; ++r) {
        opart[obase + (size_t)(4 * g + r) * S + q]      = oacc[f][0][r];
        opart[obase + (size_t)(16 + 4 * g + r) * S + q] = oacc[f][1][r];
      }
    }
  }
  if (lane < 16) {
    size_t lb = ((size_t)(ks * 4 + b) * 8 + h) * S;
#pragma unroll
    for (int f = 0; f < 4; ++f)
      if (q0 + 16 * f + lane < S) lpart[lb + q0 + 16 * f + lane] = ls[f];
  }
}

// ---------------------------------------------------------------------------
// Combine K-split partials: att[b][ch][s] = sum_ks O / sum_ks lsum.
// ---------------------------------------------------------------------------
template<int KS>
__global__ __launch_bounds__(256)
void att_combine_kernel(const float* __restrict__ opart,
                        const float* __restrict__ lpart,
                        float* __restrict__ att, int S, int N) {
  int idx = blockIdx.x * 256 + threadIdx.x;
  if (idx >= N) return;
  int S4 = S >> 2;
  int sq = idx % S4; int t = idx / S4;
  int ch = t & 255; int b = t >> 8;
  int s = sq * 4;
  float4 num = {0.f, 0.f, 0.f, 0.f};
  float4 den = {0.f, 0.f, 0.f, 0.f};
#pragma unroll
  for (int ks = 0; ks < KS; ++ks) {
    float4 o4 = *(const float4*)(opart + ((size_t)(ks * 4 + b) * 256 + ch) * S + s);
    float4 l4 = *(const float4*)(lpart + ((size_t)(ks * 4 + b) * 8 + (ch >> 5)) * S + s);
    num.x += o4.x; num.y += o4.y; num.z += o4.z; num.w += o4.w;
    den.x += l4.x; den.y += l4.y; den.z += l4.z; den.w += l4.w;
  }
  float4 r;
  r.x = num.x / den.x; r.y = num.y / den.y; r.z = num.z / den.z; r.w = num.w / den.w;
  *(float4*)(att + ((size_t)b * 256 + ch) * S + s) = r;
}

// ---------------------------------------------------------------------------
__global__ __launch_bounds__(256)
void pool_kernel(const float* __restrict__ x, float* __restrict__ xg) {
  int idx = blockIdx.x * 256 + threadIdx.x;
  if (idx >= 4 * 256 * 144) return;
  int wc = idx % 12;
  int t = idx / 12;
  int hc = t % 12;
  int bc = t / 12;
  const float* p = x + ((size_t)bc * 48 + hc * 4) * 48 + wc * 4;
  float s = 0.f;
#pragma unroll
  for (int dy = 0; dy < 4; ++dy)
#pragma unroll
    for (int dx = 0; dx < 4; ++dx) s += p[dy * 48 + dx];
  xg[idx] = s * (1.0f / 16.0f);
}

__global__ __launch_bounds__(256)
void upsample_kernel(const float* __restrict__ g, float* __restrict__ cat) {
  int idx = blockIdx.x * 256 + threadIdx.x;
  if (idx >= 4 * 256 * 2304) return;
  int xo = idx % 48;
  int t = idx / 48;
  int yo = t % 48;
  int bc = t / 48;
  int b = bc >> 8, c = bc & 255;
  float sy = 0.25f * yo - 0.375f;
  float sx = 0.25f * xo - 0.375f;
  int y0 = (int)floorf(sy); float fy = sy - (float)y0;
  int x0 = (int)floorf(sx); float fx = sx - (float)x0;
  int y0c = min(11, max(0, y0)), y1c = min(11, max(0, y0 + 1));
  int x0c = min(11, max(0, x0)), x1c = min(11, max(0, x0 + 1));
  const float* gb = g + (size_t)bc * 144;
  float v00 = gb[y0c * 12 + x0c], v01 = gb[y0c * 12 + x1c];
  float v10 = gb[y1c * 12 + x0c], v11 = gb[y1c * 12 + x1c];
  float v = (1.f - fy) * ((1.f - fx) * v00 + fx * v01) + fy * ((1.f - fx) * v10 + fx * v11);
  cat[((size_t)b * 512 + 256 + c) * 2304 + yo * 48 + xo] = v;
}

// ---------------------------------------------------------------------------
extern "C" void kernel_launch(void* const* d_in, const int* in_sizes, int n_in,
                              void* d_out, int out_size, void* d_ws, size_t ws_size,
                              hipStream_t stream) {
  const float* x        = (const float*)d_in[0];
  const float* w_qkv_l  = (const float*)d_in[1];
  const float* w_proj_l = (const float*)d_in[2];
  const float* b_proj_l = (const float*)d_in[3];
  const float* w_qkv_g  = (const float*)d_in[4];
  const float* w_proj_g = (const float*)d_in[5];
  const float* b_proj_g = (const float*)d_in[6];
  const float* w_f1     = (const float*)d_in[7];
  const float* b_f1     = (const float*)d_in[8];
  const float* w_f2     = (const float*)d_in[9];
  const float* b_f2     = (const float*)d_in[10];
  float* out = (float*)d_out;

  const int S = 2304, Sg = 144, B = 4;
  const int Sp = 2304, Sgp = 256;  // padded row counts (multiple of 256)
  const int KS = 3;

  char* wsp = (char*)d_ws;
  size_t off = 0;
  auto alloc = [&](size_t bytes) { char* p = wsp + off; off = (off + bytes + 255) & ~(size_t)255; return p; };
  float* qkv_l = (float*)alloc((size_t)B * 768 * S * 4);   // reused as opart_l
  float* att_l = (float*)alloc((size_t)B * 256 * S * 4);
  float* cat   = (float*)alloc((size_t)B * 512 * S * 4);
  float* hbuf  = (float*)alloc((size_t)B * 256 * S * 4);
  float* xg    = (float*)alloc((size_t)B * 256 * Sg * 4);
  float* qkv_g = (float*)alloc((size_t)B * 768 * Sg * 4);  // reused as opart_g
  float* att_g = (float*)alloc((size_t)B * 256 * Sg * 4);
  float* gsm   = (float*)alloc((size_t)B * 256 * Sg * 4);
  unsigned short* qr_l = (unsigned short*)alloc((size_t)B * 8 * Sp * 32 * 2);
  unsigned short* kr_l = (unsigned short*)alloc((size_t)B * 8 * Sp * 32 * 2);
  unsigned short* vt_l = (unsigned short*)alloc((size_t)B * 8 * Sp * 32 * 2);
  unsigned short* qr_g = (unsigned short*)alloc((size_t)B * 8 * Sgp * 32 * 2);
  unsigned short* kr_g = (unsigned short*)alloc((size_t)B * 8 * Sgp * 32 * 2);
  unsigned short* vt_g = (unsigned short*)alloc((size_t)B * 8 * Sgp * 32 * 2);
  unsigned short* whl_qkv_l  = (unsigned short*)alloc((size_t)768 * 256 * 2 * 2);
  unsigned short* whl_proj_l = (unsigned short*)alloc((size_t)256 * 256 * 2 * 2);
  unsigned short* whl_qkv_g  = (unsigned short*)alloc((size_t)768 * 256 * 2 * 2);
  unsigned short* whl_proj_g = (unsigned short*)alloc((size_t)256 * 256 * 2 * 2);
  unsigned short* whl_f1     = (unsigned short*)alloc((size_t)256 * 512 * 2 * 2);
  unsigned short* whl_f2     = (unsigned short*)alloc((size_t)256 * 256 * 2 * 2);
  float* lpart_l = (float*)alloc((size_t)KS * B * 8 * S * 4);
  float* lpart_g = (float*)alloc((size_t)KS * B * 8 * Sg * 4);
  float* opart_l = qkv_l;  // qkv_l dead after l2ncvt/vcvt consume it
  float* opart_g = qkv_g;

  dim3 blk(256);

  wsplit_kernel<<<dim3(88), blk, 0, stream>>>(
      w_qkv_l, w_proj_l, w_qkv_g, w_proj_g, w_f1, w_f2,
      whl_qkv_l, whl_proj_l, whl_qkv_g, whl_proj_g, whl_f1, whl_f2);

  // ----- local branch -----
  conv_mfma_kernel<0, 128><<<dim3(36, 6, B), blk, 0, stream>>>(
      whl_qkv_l, x, nullptr, qkv_l, 256, S, (size_t)768 * S);
  l2ncvt_kernel<<<dim3((B * 2 * 8 * Sp) / 256), blk, 0, stream>>>(qkv_l, qr_l, kr_l, S, Sp);
  vcvt_kernel<<<dim3((B * 8 * 32 * (Sp / 2)) / 256), blk, 0, stream>>>(qkv_l, vt_l, S, Sp);
  attn_mfma_kernel<KS><<<dim3(8, (Sp / 256) * KS, B), blk, 0, stream>>>(
      qr_l, kr_l, vt_l, opart_l, lpart_l, S, Sp);
  att_combine_kernel<KS><<<dim3((B * 256 * (S / 4) + 255) / 256), blk, 0, stream>>>(
      opart_l, lpart_l, att_l, S, B * 256 * (S / 4));
  conv_mfma_kernel<0, 64><<<dim3(36, 4, B), blk, 0, stream>>>(
      whl_proj_l, att_l, b_proj_l, cat, 256, S, (size_t)512 * S);

  // ----- global branch -----
  pool_kernel<<<dim3(576), blk, 0, stream>>>(x, xg);
  conv_mfma_kernel<0, 64><<<dim3(3, 12, B), blk, 0, stream>>>(
      whl_qkv_g, xg, nullptr, qkv_g, 256, Sg, (size_t)768 * Sg);
  l2ncvt_kernel<<<dim3((B * 2 * 8 * Sgp) / 256), blk, 0, stream>>>(qkv_g, qr_g, kr_g, Sg, Sgp);
  vcvt_kernel<<<dim3((B * 8 * 32 * (Sgp / 2)) / 256), blk, 0, stream>>>(qkv_g, vt_g, Sg, Sgp);
  attn_mfma_kernel<KS><<<dim3(8, (Sgp / 256) * KS, B), blk, 0, stream>>>(
      qr_g, kr_g, vt_g, opart_g, lpart_g, Sg, Sgp);
  att_combine_kernel<KS><<<dim3((B * 256 * (Sg / 4) + 255) / 256), blk, 0, stream>>>(
      opart_g, lpart_g, att_g, Sg, B * 256 * (Sg / 4));
  conv_mfma_kernel<0, 64><<<dim3(3, 4, B), blk, 0, stream>>>(
      whl_proj_g, att_g, b_proj_g, gsm, 256, Sg, (size_t)256 * Sg);
  upsample_kernel<<<dim3(9216), blk, 0, stream>>>(gsm, cat);

  // ----- fuse: f1 (GELU) then f2 -----
  conv_mfma_kernel<1, 64><<<dim3(36, 4, B), blk, 0, stream>>>(
      whl_f1, cat, b_f1, hbuf, 512, S, (size_t)256 * S);
  conv_mfma_kernel<0, 64><<<dim3(36, 4, B), blk, 0, stream>>>(
      whl_f2, hbuf, b_f2, out, 256, S, (size_t)256 * S);
}